// Round 1
// baseline (537.187 us; speedup 1.0000x reference)
//
#include <hip/hip_runtime.h>
#include <hip/hip_bf16.h>
#include <stdint.h>

#define D_MODEL 1024
#define D_STATE 16
#define D_CONV  4
#define D_INNER 2048
#define BATCH   2
#define SEQLEN  2048
#define NROWS   (BATCH*SEQLEN)     // 4096
#define BCD_LD  36                 // padded leading dim for bcd (33 used)
#define NCHUNK  8
#define CHUNKLEN (SEQLEN/NCHUNK)   // 256
#define L2E 1.44269504088896340f

typedef __attribute__((ext_vector_type(8))) short   short8;
typedef __attribute__((ext_vector_type(4))) float   f32x4;

__device__ __forceinline__ uint16_t f2bf(float f) {        // RNE f32->bf16
    uint32_t u = __float_as_uint(f);
    return (uint16_t)((u + 0x7FFFu + ((u >> 16) & 1u)) >> 16);
}
__device__ __forceinline__ float bf2f(uint16_t h) {
    return __uint_as_float(((uint32_t)h) << 16);
}
__device__ __forceinline__ void gload16(const uint16_t* g, uint16_t* l) {
    // async global->LDS, 16B/lane; LDS dest = wave-uniform base + lane*16
    __builtin_amdgcn_global_load_lds(
        (const __attribute__((address_space(1))) void*)g,
        (__attribute__((address_space(3))) void*)l, 16, 0, 0);
}
__device__ __forceinline__ float softplus_f(float v) {
    return fmaxf(v, 0.f) + __logf(1.f + __expf(-fabsf(v)));
}
__device__ __forceinline__ float silu_f(float v) {
    return v / (1.f + __expf(-v));
}

// ---------- f32 -> bf16 elementwise (x) ----------
__global__ void kcvt(const float* __restrict__ in, uint16_t* __restrict__ out, int n4) {
    int T = blockIdx.x * 256 + threadIdx.x;
    if (T >= n4) return;
    const float4 v = *(const float4*)&in[(size_t)T * 4];
    ushort4 o;
    o.x = f2bf(v.x); o.y = f2bf(v.y); o.z = f2bf(v.z); o.w = f2bf(v.w);
    *(ushort4*)&out[(size_t)T * 4] = o;
}

// ---------- transpose+convert: in[Kd][Nd] f32 -> out[Nd][Kd] bf16 ----------
__global__ void ktrans(const float* __restrict__ in, uint16_t* __restrict__ out,
                       int Kd, int Nd) {
    __shared__ float tile[32][33];
    const int n0 = blockIdx.x * 32, k0 = blockIdx.y * 32;
    const int tx = threadIdx.x & 31, ty = threadIdx.x >> 5;   // ty 0..7
#pragma unroll
    for (int i = 0; i < 4; ++i)
        tile[ty + i * 8][tx] = in[(size_t)(k0 + ty + i * 8) * Nd + n0 + tx];
    __syncthreads();
#pragma unroll
    for (int i = 0; i < 4; ++i)
        out[(size_t)(n0 + ty + i * 8) * Kd + k0 + tx] = f2bf(tile[tx][ty + i * 8]);
}

// ---------- TN bf16 MFMA GEMM: C[M][ldc] = A[M][KDIM] * B[ldc-cols][KDIM]^T ----------
template<int KDIM>
__global__ __launch_bounds__(256) void kgemm(const uint16_t* __restrict__ A,
                                             const uint16_t* __restrict__ B,
                                             float* __restrict__ C, const int ldc) {
    __shared__ uint16_t As[128 * 32];
    __shared__ uint16_t Bs[128 * 32];
    const int t = threadIdx.x;
    const int w = t >> 6, lane = t & 63;
    const int m0 = blockIdx.y * 128, n0 = blockIdx.x * 128;
    const int wm = (w >> 1) * 64, wn = (w & 1) * 64;
    f32x4 acc[4][4] = {};

    // staging: round r covers rows r*64 + t/4, k-bytes (t%4)*16
    const int srow = t >> 2;
    const int scol = (t & 3) * 8;
    const uint16_t* ga0 = A + (size_t)(m0 + srow) * KDIM + scol;
    const uint16_t* ga1 = A + (size_t)(m0 + 64 + srow) * KDIM + scol;
    const uint16_t* gb0 = B + (size_t)(n0 + srow) * KDIM + scol;
    const uint16_t* gb1 = B + (size_t)(n0 + 64 + srow) * KDIM + scol;
    uint16_t* lA0 = &As[w * 512];
    uint16_t* lA1 = &As[2048 + w * 512];
    uint16_t* lB0 = &Bs[w * 512];
    uint16_t* lB1 = &Bs[2048 + w * 512];

    const int fr = lane & 15, fg = (lane >> 4) * 8;

    for (int kt = 0; kt < KDIM / 32; ++kt) {
        const int ko = kt * 32;
        gload16(ga0 + ko, lA0);
        gload16(ga1 + ko, lA1);
        gload16(gb0 + ko, lB0);
        gload16(gb1 + ko, lB1);
        __syncthreads();              // compiler drains vmcnt before s_barrier
        short8 a[4], b[4];
#pragma unroll
        for (int i = 0; i < 4; ++i) {
            a[i] = *(const short8*)&As[(wm + i * 16 + fr) * 32 + fg];
            b[i] = *(const short8*)&Bs[(wn + i * 16 + fr) * 32 + fg];
        }
#pragma unroll
        for (int i = 0; i < 4; ++i)
#pragma unroll
            for (int j = 0; j < 4; ++j)
                acc[i][j] = __builtin_amdgcn_mfma_f32_16x16x32_bf16(a[i], b[j], acc[i][j], 0, 0, 0);
        __syncthreads();
    }
    // C/D layout: col = lane&15, row = (lane>>4)*4 + reg  [guide m89]
    const int cr = (lane >> 4) * 4, cc = lane & 15;
#pragma unroll
    for (int i = 0; i < 4; ++i)
#pragma unroll
        for (int j = 0; j < 4; ++j)
#pragma unroll
            for (int r = 0; r < 4; ++r)
                C[(size_t)(m0 + wm + i * 16 + cr + r) * ldc + (n0 + wn + j * 16 + cc)] = acc[i][j][r];
}

// ---------- causal depthwise conv (k=4) + bias + SiLU ----------
__global__ void kconv(const float* __restrict__ xz, const float* __restrict__ cw,
                      const float* __restrict__ cb, float* __restrict__ xs) {
    size_t T = (size_t)blockIdx.x * 256 + threadIdx.x;   // over NROWS*D_INNER
    int d = (int)(T & (D_INNER - 1));
    int row = (int)(T >> 11);
    int l = row & (SEQLEN - 1), b = row >> 11;
    const float4 w4 = *(const float4*)&cw[d * 4];
    float acc = cb[d];
    const size_t base = (size_t)b * SEQLEN;
    if (l >= 3) {
        acc += w4.x * xz[(base + l - 3) * 4096 + d];
        acc += w4.y * xz[(base + l - 2) * 4096 + d];
        acc += w4.z * xz[(base + l - 1) * 4096 + d];
        acc += w4.w * xz[(base + l    ) * 4096 + d];
    } else {
        if (l >= 3) acc += w4.x * xz[(base + l - 3) * 4096 + d];
        if (l >= 2) acc += w4.y * xz[(base + l - 2) * 4096 + d];
        if (l >= 1) acc += w4.z * xz[(base + l - 1) * 4096 + d];
        acc += w4.w * xz[(base + l) * 4096 + d];
    }
    xs[T] = silu_f(acc);
}

// ---------- bcd = xs @ W_x  (K=2048, N=33, padded to 36) ----------
__global__ __launch_bounds__(256) void kgemm2(const float* __restrict__ xs,
                                              const float* __restrict__ Wx,
                                              float* __restrict__ bcd) {
    __shared__ float Ws[256 * 36];
    __shared__ float Xs[32 * 257];
    const int t = threadIdx.x;
    const int r = t >> 3, jg = t & 7;
    const int m0 = blockIdx.x * 32;
    float a0 = 0, a1 = 0, a2 = 0, a3 = 0, a4 = 0;
    for (int kc = 0; kc < D_INNER; kc += 256) {
        __syncthreads();
        for (int i = t; i < 256 * 33; i += 256)
            Ws[(i / 33) * 36 + (i % 33)] = Wx[(size_t)(kc + i / 33) * 33 + (i % 33)];
        for (int i = t; i < 32 * 256; i += 256)
            Xs[(i >> 8) * 257 + (i & 255)] = xs[(size_t)(m0 + (i >> 8)) * D_INNER + kc + (i & 255)];
        __syncthreads();
#pragma unroll 4
        for (int k = 0; k < 256; ++k) {
            float x = Xs[r * 257 + k];
            const float4 w4 = *(const float4*)&Ws[k * 36 + jg * 4];
            a0 += x * w4.x; a1 += x * w4.y; a2 += x * w4.z; a3 += x * w4.w;
            if (jg == 7) a4 += x * Ws[k * 36 + 32];
        }
    }
    float* out = &bcd[(size_t)(m0 + r) * BCD_LD + jg * 4];
    out[0] = a0; out[1] = a1; out[2] = a2; out[3] = a3;
    if (jg == 7) out[4] = a4;   // column 32 (dt raw)
}

// ---------- scan phase 1: per (chunk, channel): sum(dt), h_local (h0=0) ----------
__global__ __launch_bounds__(256) void kscan1(const float* __restrict__ xs,
        const float* __restrict__ bcd, const float* __restrict__ wdt,
        const float* __restrict__ bdt, const float* __restrict__ Alog,
        float* __restrict__ hloc, float* __restrict__ sumdt) {
    const int T = blockIdx.x * 256 + threadIdx.x;
    const int sub = T & 3;
    const int ch = (T >> 2) & 4095;
    const int chunk = T >> 14;
    const int b = ch >> 11, d = ch & 2047;
    float Ae[4];
#pragma unroll
    for (int i = 0; i < 4; ++i) Ae[i] = -__expf(Alog[d * 16 + sub * 4 + i]) * L2E;
    const float w = wdt[d], bb = bdt[d];
    float h0 = 0, h1 = 0, h2 = 0, h3 = 0, sdt = 0;
    const int row0 = b * SEQLEN + chunk * CHUNKLEN;
    for (int l = 0; l < CHUNKLEN; ++l) {
        const int row = row0 + l;
        const float raw = bcd[(size_t)row * BCD_LD + 32];
        const float dtv = softplus_f(raw * w + bb);
        sdt += dtv;
        const float x = xs[(size_t)row * D_INNER + d];
        const float dtx = dtv * x;
        const float4 B4 = *(const float4*)&bcd[(size_t)row * BCD_LD + sub * 4];
        h0 = __builtin_amdgcn_exp2f(dtv * Ae[0]) * h0 + dtx * B4.x;
        h1 = __builtin_amdgcn_exp2f(dtv * Ae[1]) * h1 + dtx * B4.y;
        h2 = __builtin_amdgcn_exp2f(dtv * Ae[2]) * h2 + dtx * B4.z;
        h3 = __builtin_amdgcn_exp2f(dtv * Ae[3]) * h3 + dtx * B4.w;
    }
    const int cc = chunk * 4096 + ch;
    *(float4*)&hloc[(size_t)cc * 16 + sub * 4] = make_float4(h0, h1, h2, h3);
    if (sub == 0) sumdt[cc] = sdt;
}

// ---------- scan phase 2: sequential chunk combine -> h at chunk starts ----------
__global__ void kscan2(const float* __restrict__ hloc, const float* __restrict__ sumdt,
                       const float* __restrict__ Alog, float* __restrict__ h0buf) {
    const int T = blockIdx.x * 256 + threadIdx.x;   // 65536
    const int n = T & 15, ch = T >> 4;
    const int d = ch & 2047;
    const float Ae = -__expf(Alog[d * 16 + n]) * L2E;
    float h = 0.f;
    for (int c = 0; c < NCHUNK; ++c) {
        const int cc = c * 4096 + ch;
        h0buf[(size_t)cc * 16 + n] = h;
        h = __builtin_amdgcn_exp2f(Ae * sumdt[cc]) * h + hloc[(size_t)cc * 16 + n];
    }
}

// ---------- scan phase 3: replay with h0, emit u = (y + x*Dp)*silu(z) bf16 ----------
__global__ __launch_bounds__(256) void kscan3(const float* __restrict__ xs,
        const float* __restrict__ bcd, const float* __restrict__ wdt,
        const float* __restrict__ bdt, const float* __restrict__ Alog,
        const float* __restrict__ Dp, const float* __restrict__ xz,
        const float* __restrict__ h0buf, uint16_t* __restrict__ u) {
    const int T = blockIdx.x * 256 + threadIdx.x;
    const int sub = T & 3;
    const int ch = (T >> 2) & 4095;
    const int chunk = T >> 14;
    const int b = ch >> 11, d = ch & 2047;
    float Ae[4];
#pragma unroll
    for (int i = 0; i < 4; ++i) Ae[i] = -__expf(Alog[d * 16 + sub * 4 + i]) * L2E;
    const float w = wdt[d], bb = bdt[d];
    const float Dpd = Dp[d];
    const float4 hh = *(const float4*)&h0buf[(size_t)(chunk * 4096 + ch) * 16 + sub * 4];
    float h0 = hh.x, h1 = hh.y, h2 = hh.z, h3 = hh.w;
    const int row0 = b * SEQLEN + chunk * CHUNKLEN;
    for (int l = 0; l < CHUNKLEN; ++l) {
        const int row = row0 + l;
        const float raw = bcd[(size_t)row * BCD_LD + 32];
        const float dtv = softplus_f(raw * w + bb);
        const float x = xs[(size_t)row * D_INNER + d];
        const float dtx = dtv * x;
        const float4 B4 = *(const float4*)&bcd[(size_t)row * BCD_LD + sub * 4];
        const float4 C4 = *(const float4*)&bcd[(size_t)row * BCD_LD + 16 + sub * 4];
        h0 = __builtin_amdgcn_exp2f(dtv * Ae[0]) * h0 + dtx * B4.x;
        h1 = __builtin_amdgcn_exp2f(dtv * Ae[1]) * h1 + dtx * B4.y;
        h2 = __builtin_amdgcn_exp2f(dtv * Ae[2]) * h2 + dtx * B4.z;
        h3 = __builtin_amdgcn_exp2f(dtv * Ae[3]) * h3 + dtx * B4.w;
        float yp = h0 * C4.x + h1 * C4.y + h2 * C4.z + h3 * C4.w;
        yp += __shfl_xor(yp, 1);
        yp += __shfl_xor(yp, 2);
        if (sub == 0) {
            const float z = xz[(size_t)row * 4096 + 2048 + d];
            const float uu = (yp + x * Dpd) * silu_f(z);
            u[(size_t)row * D_INNER + d] = f2bf(uu);
        }
    }
}

extern "C" void kernel_launch(void* const* d_in, const int* in_sizes, int n_in,
                              void* d_out, int out_size, void* d_ws, size_t ws_size,
                              hipStream_t stream) {
    const float* x      = (const float*)d_in[0];
    const float* W_in   = (const float*)d_in[1];
    const float* conv_w = (const float*)d_in[2];
    const float* conv_b = (const float*)d_in[3];
    const float* W_x    = (const float*)d_in[4];
    const float* w_dt   = (const float*)d_in[5];
    const float* b_dt   = (const float*)d_in[6];
    const float* A_log  = (const float*)d_in[7];
    const float* Dp     = (const float*)d_in[8];
    const float* W_out  = (const float*)d_in[9];
    float* out = (float*)d_out;

    char* p = (char*)d_ws;
    uint16_t* xb  = (uint16_t*)p;  p += (size_t)NROWS * D_MODEL * 2;      // 8 MB
    uint16_t* Wb  = (uint16_t*)p;  p += (size_t)4096 * 1024 * 2;          // 8 MB  (W_in^T)
    uint16_t* Wob = (uint16_t*)p;  p += (size_t)1024 * 2048 * 2;          // 4 MB  (W_out^T)
    float* xz     = (float*)p;     p += (size_t)NROWS * 4096 * 4;         // 64 MB
    float* xs     = (float*)p;     p += (size_t)NROWS * D_INNER * 4;      // 32 MB
    float* bcd    = (float*)p;     p += (size_t)NROWS * BCD_LD * 4;       // 576 KB
    float* sumdt  = (float*)p;     p += (size_t)NCHUNK * 4096 * 4;        // 128 KB
    float* hloc   = (float*)p;     p += (size_t)NCHUNK * 4096 * 16 * 4;   // 2 MB
    float* h0b    = (float*)p;     p += (size_t)NCHUNK * 4096 * 16 * 4;   // 2 MB
    uint16_t* ub  = (uint16_t*)p;  p += (size_t)NROWS * D_INNER * 2;      // 16 MB

    // 1) dtype prep
    kcvt<<<(NROWS * D_MODEL / 4 + 255) / 256, 256, 0, stream>>>(x, xb, NROWS * D_MODEL / 4);
    ktrans<<<dim3(4096 / 32, 1024 / 32), 256, 0, stream>>>(W_in, Wb, 1024, 4096);
    ktrans<<<dim3(1024 / 32, 2048 / 32), 256, 0, stream>>>(W_out, Wob, 2048, 1024);
    // 2) xz = x @ W_in   (M=4096, N=4096, K=1024)
    kgemm<1024><<<dim3(32, 32), 256, 0, stream>>>(xb, Wb, xz, 4096);
    // 3) conv + silu
    kconv<<<NROWS * D_INNER / 256, 256, 0, stream>>>(xz, conv_w, conv_b, xs);
    // 4) bcd = xs @ W_x
    kgemm2<<<NROWS / 32, 256, 0, stream>>>(xs, W_x, bcd);
    // 5) selective scan (3 phases)
    kscan1<<<(4096 * 4 * NCHUNK) / 256, 256, 0, stream>>>(xs, bcd, w_dt, b_dt, A_log, hloc, sumdt);
    kscan2<<<(4096 * 16) / 256, 256, 0, stream>>>(hloc, sumdt, A_log, h0b);
    kscan3<<<(4096 * 4 * NCHUNK) / 256, 256, 0, stream>>>(xs, bcd, w_dt, b_dt, A_log, Dp, xz, h0b, ub);
    // 6) out = u @ W_out (M=4096, N=1024, K=2048)
    kgemm<2048><<<dim3(1024 / 128, 32), 256, 0, stream>>>(ub, Wob, out, 1024);
}

// Round 2
// 394.353 us; speedup vs baseline: 1.3622x; 1.3622x over previous
//
#include <hip/hip_runtime.h>
#include <hip/hip_bf16.h>
#include <stdint.h>

#define D_MODEL 1024
#define D_STATE 16
#define D_CONV  4
#define D_INNER 2048
#define BATCH   2
#define SEQLEN  2048
#define NROWS   (BATCH*SEQLEN)     // 4096
#define BCD_LD  36                 // padded leading dim for bcd (33 used)
#define NCHUNK  32
#define CHUNKLEN (SEQLEN/NCHUNK)   // 64
#define L2E 1.44269504088896340f

typedef __attribute__((ext_vector_type(8))) short   short8;
typedef __attribute__((ext_vector_type(4))) float   f32x4;

__device__ __forceinline__ uint16_t f2bf(float f) {        // RNE f32->bf16
    uint32_t u = __float_as_uint(f);
    return (uint16_t)((u + 0x7FFFu + ((u >> 16) & 1u)) >> 16);
}
__device__ __forceinline__ void gload16(const uint16_t* g, uint16_t* l) {
    // async global->LDS, 16B/lane; LDS dest = wave-uniform base + lane*16
    __builtin_amdgcn_global_load_lds(
        (const __attribute__((address_space(1))) void*)g,
        (__attribute__((address_space(3))) void*)l, 16, 0, 0);
}
__device__ __forceinline__ float softplus_f(float v) {
    return fmaxf(v, 0.f) + __logf(1.f + __expf(-fabsf(v)));
}
__device__ __forceinline__ float silu_f(float v) {
    return v / (1.f + __expf(-v));
}

// ---------- f32 -> bf16 elementwise (x) ----------
__global__ void kcvt(const float* __restrict__ in, uint16_t* __restrict__ out, int n4) {
    int T = blockIdx.x * 256 + threadIdx.x;
    if (T >= n4) return;
    const float4 v = *(const float4*)&in[(size_t)T * 4];
    ushort4 o;
    o.x = f2bf(v.x); o.y = f2bf(v.y); o.z = f2bf(v.z); o.w = f2bf(v.w);
    *(ushort4*)&out[(size_t)T * 4] = o;
}

// ---------- transpose+convert: in[Kd][Nd] f32 -> out[Nd][Kd] bf16 ----------
__global__ void ktrans(const float* __restrict__ in, uint16_t* __restrict__ out,
                       int Kd, int Nd) {
    __shared__ float tile[32][33];
    const int n0 = blockIdx.x * 32, k0 = blockIdx.y * 32;
    const int tx = threadIdx.x & 31, ty = threadIdx.x >> 5;   // ty 0..7
#pragma unroll
    for (int i = 0; i < 4; ++i)
        tile[ty + i * 8][tx] = in[(size_t)(k0 + ty + i * 8) * Nd + n0 + tx];
    __syncthreads();
#pragma unroll
    for (int i = 0; i < 4; ++i)
        out[(size_t)(n0 + ty + i * 8) * Kd + k0 + tx] = f2bf(tile[tx][ty + i * 8]);
}

// ---------- TN bf16 MFMA GEMM: C[M][ldc] = A[M][KDIM] * B[ldc-cols][KDIM]^T ----------
template<int KDIM>
__global__ __launch_bounds__(256) void kgemm(const uint16_t* __restrict__ A,
                                             const uint16_t* __restrict__ B,
                                             float* __restrict__ C, const int ldc) {
    __shared__ uint16_t As[128 * 32];
    __shared__ uint16_t Bs[128 * 32];
    const int t = threadIdx.x;
    const int w = t >> 6, lane = t & 63;
    const int m0 = blockIdx.y * 128, n0 = blockIdx.x * 128;
    const int wm = (w >> 1) * 64, wn = (w & 1) * 64;
    f32x4 acc[4][4] = {};

    const int srow = t >> 2;
    const int scol = (t & 3) * 8;
    const uint16_t* ga0 = A + (size_t)(m0 + srow) * KDIM + scol;
    const uint16_t* ga1 = A + (size_t)(m0 + 64 + srow) * KDIM + scol;
    const uint16_t* gb0 = B + (size_t)(n0 + srow) * KDIM + scol;
    const uint16_t* gb1 = B + (size_t)(n0 + 64 + srow) * KDIM + scol;
    uint16_t* lA0 = &As[w * 512];
    uint16_t* lA1 = &As[2048 + w * 512];
    uint16_t* lB0 = &Bs[w * 512];
    uint16_t* lB1 = &Bs[2048 + w * 512];

    const int fr = lane & 15, fg = (lane >> 4) * 8;

    for (int kt = 0; kt < KDIM / 32; ++kt) {
        const int ko = kt * 32;
        gload16(ga0 + ko, lA0);
        gload16(ga1 + ko, lA1);
        gload16(gb0 + ko, lB0);
        gload16(gb1 + ko, lB1);
        __syncthreads();
        short8 a[4], b[4];
#pragma unroll
        for (int i = 0; i < 4; ++i) {
            a[i] = *(const short8*)&As[(wm + i * 16 + fr) * 32 + fg];
            b[i] = *(const short8*)&Bs[(wn + i * 16 + fr) * 32 + fg];
        }
#pragma unroll
        for (int i = 0; i < 4; ++i)
#pragma unroll
            for (int j = 0; j < 4; ++j)
                acc[i][j] = __builtin_amdgcn_mfma_f32_16x16x32_bf16(a[i], b[j], acc[i][j], 0, 0, 0);
        __syncthreads();
    }
    const int cr = (lane >> 4) * 4, cc = lane & 15;
#pragma unroll
    for (int i = 0; i < 4; ++i)
#pragma unroll
        for (int j = 0; j < 4; ++j)
#pragma unroll
            for (int r = 0; r < 4; ++r)
                C[(size_t)(m0 + wm + i * 16 + cr + r) * ldc + (n0 + wn + j * 16 + cc)] = acc[i][j][r];
}

// ---------- causal depthwise conv (k=4) + bias + SiLU ----------
__global__ void kconv(const float* __restrict__ xz, const float* __restrict__ cw,
                      const float* __restrict__ cb, float* __restrict__ xs) {
    size_t T = (size_t)blockIdx.x * 256 + threadIdx.x;   // over NROWS*D_INNER
    int d = (int)(T & (D_INNER - 1));
    int row = (int)(T >> 11);
    int l = row & (SEQLEN - 1), b = row >> 11;
    const float4 w4 = *(const float4*)&cw[d * 4];
    float acc = cb[d];
    const size_t base = (size_t)b * SEQLEN;
    if (l >= 3) {
        acc += w4.x * xz[(base + l - 3) * 4096 + d];
        acc += w4.y * xz[(base + l - 2) * 4096 + d];
        acc += w4.z * xz[(base + l - 1) * 4096 + d];
        acc += w4.w * xz[(base + l    ) * 4096 + d];
    } else {
        if (l >= 2) acc += w4.y * xz[(base + l - 2) * 4096 + d];
        if (l >= 1) acc += w4.z * xz[(base + l - 1) * 4096 + d];
        acc += w4.w * xz[(base + l) * 4096 + d];
    }
    xs[T] = silu_f(acc);
}

// ---------- bcd = xs @ W_x  (K=2048, N=33, padded to 36) ----------
__global__ __launch_bounds__(256) void kgemm2(const float* __restrict__ xs,
                                              const float* __restrict__ Wx,
                                              float* __restrict__ bcd) {
    __shared__ float Ws[256 * 36];
    __shared__ float Xs[32 * 257];
    const int t = threadIdx.x;
    const int r = t >> 3, jg = t & 7;
    const int m0 = blockIdx.x * 32;
    float a0 = 0, a1 = 0, a2 = 0, a3 = 0, a4 = 0;
    for (int kc = 0; kc < D_INNER; kc += 256) {
        __syncthreads();
        for (int i = t; i < 256 * 33; i += 256)
            Ws[(i / 33) * 36 + (i % 33)] = Wx[(size_t)(kc + i / 33) * 33 + (i % 33)];
        for (int i = t; i < 32 * 256; i += 256)
            Xs[(i >> 8) * 257 + (i & 255)] = xs[(size_t)(m0 + (i >> 8)) * D_INNER + kc + (i & 255)];
        __syncthreads();
#pragma unroll 4
        for (int k = 0; k < 256; ++k) {
            float x = Xs[r * 257 + k];
            const float4 w4 = *(const float4*)&Ws[k * 36 + jg * 4];
            a0 += x * w4.x; a1 += x * w4.y; a2 += x * w4.z; a3 += x * w4.w;
            if (jg == 7) a4 += x * Ws[k * 36 + 32];
        }
    }
    float* out = &bcd[(size_t)(m0 + r) * BCD_LD + jg * 4];
    out[0] = a0; out[1] = a1; out[2] = a2; out[3] = a3;
    if (jg == 7) out[4] = a4;   // column 32 (dt raw)
}

// ---------- scan phase 1: per (chunk, channel): sum(dt), h_local (h0=0) ----------
// thread map: sub = T&3 (4 states each), ch = (T>>2)&4095, chunk = T>>14
__global__ __launch_bounds__(256) void kscan1(const float* __restrict__ xs,
        const float* __restrict__ bcd, const float* __restrict__ wdt,
        const float* __restrict__ bdt, const float* __restrict__ Alog,
        float* __restrict__ hloc, float* __restrict__ sumdt) {
    const int T = blockIdx.x * 256 + threadIdx.x;
    const int sub = T & 3;
    const int ch = (T >> 2) & 4095;
    const int chunk = T >> 14;
    const int b = ch >> 11, d = ch & 2047;
    float Ae[4];
#pragma unroll
    for (int i = 0; i < 4; ++i) Ae[i] = -__expf(Alog[d * 16 + sub * 4 + i]) * L2E;
    const float w = wdt[d], bb = bdt[d];
    float h0 = 0, h1 = 0, h2 = 0, h3 = 0, sdt = 0;
    const int row0 = b * SEQLEN + chunk * CHUNKLEN;
    for (int l0 = 0; l0 < CHUNKLEN; l0 += 4) {
        float raw[4], xv[4]; float4 B4[4];
#pragma unroll
        for (int s = 0; s < 4; ++s) {          // batch all loads: ~12 in flight
            const int row = row0 + l0 + s;
            raw[s] = bcd[(size_t)row * BCD_LD + 32];
            xv[s]  = xs[(size_t)row * D_INNER + d];
            B4[s]  = *(const float4*)&bcd[(size_t)row * BCD_LD + sub * 4];
        }
#pragma unroll
        for (int s = 0; s < 4; ++s) {
            const float dtv = softplus_f(raw[s] * w + bb);
            sdt += dtv;
            const float dtx = dtv * xv[s];
            h0 = __builtin_amdgcn_exp2f(dtv * Ae[0]) * h0 + dtx * B4[s].x;
            h1 = __builtin_amdgcn_exp2f(dtv * Ae[1]) * h1 + dtx * B4[s].y;
            h2 = __builtin_amdgcn_exp2f(dtv * Ae[2]) * h2 + dtx * B4[s].z;
            h3 = __builtin_amdgcn_exp2f(dtv * Ae[3]) * h3 + dtx * B4[s].w;
        }
    }
    const int cc = chunk * 4096 + ch;
    *(float4*)&hloc[(size_t)cc * 16 + sub * 4] = make_float4(h0, h1, h2, h3);
    if (sub == 0) sumdt[cc] = sdt;
}

// ---------- scan phase 2: sequential chunk combine -> h at chunk starts ----------
__global__ void kscan2(const float* __restrict__ hloc, const float* __restrict__ sumdt,
                       const float* __restrict__ Alog, float* __restrict__ h0buf) {
    const int T = blockIdx.x * 256 + threadIdx.x;   // 65536
    const int n = T & 15, ch = T >> 4;
    const int d = ch & 2047;
    const float Ae = -__expf(Alog[d * 16 + n]) * L2E;
    float h = 0.f;
    for (int c = 0; c < NCHUNK; ++c) {
        const int cc = c * 4096 + ch;
        h0buf[(size_t)cc * 16 + n] = h;
        h = __builtin_amdgcn_exp2f(Ae * sumdt[cc]) * h + hloc[(size_t)cc * 16 + n];
    }
}

// ---------- scan phase 3: replay with h0, emit u = (y + x*Dp)*silu(z) bf16 ----------
__global__ __launch_bounds__(256) void kscan3(const float* __restrict__ xs,
        const float* __restrict__ bcd, const float* __restrict__ wdt,
        const float* __restrict__ bdt, const float* __restrict__ Alog,
        const float* __restrict__ Dp, const float* __restrict__ xz,
        const float* __restrict__ h0buf, uint16_t* __restrict__ u) {
    const int T = blockIdx.x * 256 + threadIdx.x;
    const int sub = T & 3;
    const int ch = (T >> 2) & 4095;
    const int chunk = T >> 14;
    const int b = ch >> 11, d = ch & 2047;
    float Ae[4];
#pragma unroll
    for (int i = 0; i < 4; ++i) Ae[i] = -__expf(Alog[d * 16 + sub * 4 + i]) * L2E;
    const float w = wdt[d], bb = bdt[d];
    const float Dpd = Dp[d];
    const float4 hh = *(const float4*)&h0buf[(size_t)(chunk * 4096 + ch) * 16 + sub * 4];
    float h0 = hh.x, h1 = hh.y, h2 = hh.z, h3 = hh.w;
    const int row0 = b * SEQLEN + chunk * CHUNKLEN;
    for (int l0 = 0; l0 < CHUNKLEN; l0 += 4) {
        float raw[4], xv[4], zv[4]; float4 B4[4], C4[4];
#pragma unroll
        for (int s = 0; s < 4; ++s) {          // batch all loads
            const int row = row0 + l0 + s;
            raw[s] = bcd[(size_t)row * BCD_LD + 32];
            xv[s]  = xs[(size_t)row * D_INNER + d];
            B4[s]  = *(const float4*)&bcd[(size_t)row * BCD_LD + sub * 4];
            C4[s]  = *(const float4*)&bcd[(size_t)row * BCD_LD + 16 + sub * 4];
            if (sub == 0) zv[s] = xz[(size_t)row * 4096 + 2048 + d];
        }
#pragma unroll
        for (int s = 0; s < 4; ++s) {
            const int row = row0 + l0 + s;
            const float dtv = softplus_f(raw[s] * w + bb);
            const float dtx = dtv * xv[s];
            h0 = __builtin_amdgcn_exp2f(dtv * Ae[0]) * h0 + dtx * B4[s].x;
            h1 = __builtin_amdgcn_exp2f(dtv * Ae[1]) * h1 + dtx * B4[s].y;
            h2 = __builtin_amdgcn_exp2f(dtv * Ae[2]) * h2 + dtx * B4[s].z;
            h3 = __builtin_amdgcn_exp2f(dtv * Ae[3]) * h3 + dtx * B4[s].w;
            float yp = h0 * C4[s].x + h1 * C4[s].y + h2 * C4[s].z + h3 * C4[s].w;
            yp += __shfl_xor(yp, 1);
            yp += __shfl_xor(yp, 2);
            if (sub == 0) {
                const float uu = (yp + xv[s] * Dpd) * silu_f(zv[s]);
                u[(size_t)row * D_INNER + d] = f2bf(uu);
            }
        }
    }
}

extern "C" void kernel_launch(void* const* d_in, const int* in_sizes, int n_in,
                              void* d_out, int out_size, void* d_ws, size_t ws_size,
                              hipStream_t stream) {
    const float* x      = (const float*)d_in[0];
    const float* W_in   = (const float*)d_in[1];
    const float* conv_w = (const float*)d_in[2];
    const float* conv_b = (const float*)d_in[3];
    const float* W_x    = (const float*)d_in[4];
    const float* w_dt   = (const float*)d_in[5];
    const float* b_dt   = (const float*)d_in[6];
    const float* A_log  = (const float*)d_in[7];
    const float* Dp     = (const float*)d_in[8];
    const float* W_out  = (const float*)d_in[9];
    float* out = (float*)d_out;

    char* p = (char*)d_ws;
    uint16_t* xb  = (uint16_t*)p;  p += (size_t)NROWS * D_MODEL * 2;      // 8 MB (dead after gemm1)
    uint16_t* Wb  = (uint16_t*)p;  p += (size_t)4096 * 1024 * 2;          // 8 MB (dead after gemm1)
    uint16_t* Wob = (uint16_t*)p;  p += (size_t)1024 * 2048 * 2;          // 4 MB  (W_out^T)
    float* xz     = (float*)p;     p += (size_t)NROWS * 4096 * 4;         // 64 MB
    float* xs     = (float*)p;     p += (size_t)NROWS * D_INNER * 4;      // 32 MB
    float* bcd    = (float*)p;     p += (size_t)NROWS * BCD_LD * 4;       // 576 KB
    float* sumdt  = (float*)p;     p += (size_t)NCHUNK * 4096 * 4;        // 512 KB
    uint16_t* ub  = (uint16_t*)p;  p += (size_t)NROWS * D_INNER * 2;      // 16 MB
    // overlay scan buffers on xb/Wb (dead after kgemm<1024>): 8 MB each
    float* hloc   = (float*)xb;    // NCHUNK*4096*16*4 = 8 MB
    float* h0b    = (float*)Wb;    // NCHUNK*4096*16*4 = 8 MB

    // 1) dtype prep
    kcvt<<<(NROWS * D_MODEL / 4 + 255) / 256, 256, 0, stream>>>(x, xb, NROWS * D_MODEL / 4);
    ktrans<<<dim3(4096 / 32, 1024 / 32), 256, 0, stream>>>(W_in, Wb, 1024, 4096);
    ktrans<<<dim3(1024 / 32, 2048 / 32), 256, 0, stream>>>(W_out, Wob, 2048, 1024);
    // 2) xz = x @ W_in   (M=4096, N=4096, K=1024)
    kgemm<1024><<<dim3(32, 32), 256, 0, stream>>>(xb, Wb, xz, 4096);
    // 3) conv + silu
    kconv<<<NROWS * D_INNER / 256, 256, 0, stream>>>(xz, conv_w, conv_b, xs);
    // 4) bcd = xs @ W_x
    kgemm2<<<NROWS / 32, 256, 0, stream>>>(xs, W_x, bcd);
    // 5) selective scan (3 phases)
    kscan1<<<(4096 * 4 * NCHUNK) / 256, 256, 0, stream>>>(xs, bcd, w_dt, b_dt, A_log, hloc, sumdt);
    kscan2<<<(4096 * 16) / 256, 256, 0, stream>>>(hloc, sumdt, A_log, h0b);
    kscan3<<<(4096 * 4 * NCHUNK) / 256, 256, 0, stream>>>(xs, bcd, w_dt, b_dt, A_log, Dp, xz, h0b, ub);
    // 6) out = u @ W_out (M=4096, N=1024, K=2048)
    kgemm<2048><<<dim3(1024 / 128, 32), 256, 0, stream>>>(ub, Wob, out, 1024);
}

// Round 3
// 259.572 us; speedup vs baseline: 2.0695x; 1.5192x over previous
//
#include <hip/hip_runtime.h>
#include <hip/hip_bf16.h>
#include <stdint.h>

#define D_MODEL 1024
#define D_STATE 16
#define D_CONV  4
#define D_INNER 2048
#define BATCH   2
#define SEQLEN  2048
#define NROWS   (BATCH*SEQLEN)     // 4096
#define BCD_LD  36                 // padded leading dim for bcd (33 used)
#define NCHUNK  32
#define CHUNKLEN (SEQLEN/NCHUNK)   // 64
#define KS2     16                 // K-splits for GEMM2 (chunk = 128)
#define L2E 1.44269504088896340f

typedef __attribute__((ext_vector_type(8))) short   short8;
typedef __attribute__((ext_vector_type(4))) float   f32x4;

__device__ __forceinline__ uint16_t f2bf(float f) {        // RNE f32->bf16
    uint32_t u = __float_as_uint(f);
    return (uint16_t)((u + 0x7FFFu + ((u >> 16) & 1u)) >> 16);
}
__device__ __forceinline__ void gload16(const uint16_t* g, uint16_t* l) {
    __builtin_amdgcn_global_load_lds(
        (const __attribute__((address_space(1))) void*)g,
        (__attribute__((address_space(3))) void*)l, 16, 0, 0);
}
__device__ __forceinline__ void gload16f(const float* g, float* l) {
    __builtin_amdgcn_global_load_lds(
        (const __attribute__((address_space(1))) void*)g,
        (__attribute__((address_space(3))) void*)l, 16, 0, 0);
}
__device__ __forceinline__ float softplus_f(float v) {
    return fmaxf(v, 0.f) + __logf(1.f + __expf(-fabsf(v)));
}
__device__ __forceinline__ float silu_f(float v) {
    return v / (1.f + __expf(-v));
}
__device__ __forceinline__ short8 pack8(const float4 lo, const float4 hi) {
    short8 r;
    r[0] = (short)f2bf(lo.x); r[1] = (short)f2bf(lo.y);
    r[2] = (short)f2bf(lo.z); r[3] = (short)f2bf(lo.w);
    r[4] = (short)f2bf(hi.x); r[5] = (short)f2bf(hi.y);
    r[6] = (short)f2bf(hi.z); r[7] = (short)f2bf(hi.w);
    return r;
}

// ---------- f32 -> bf16 elementwise (x) ----------
__global__ void kcvt(const float* __restrict__ in, uint16_t* __restrict__ out, int n4) {
    int T = blockIdx.x * 256 + threadIdx.x;
    if (T >= n4) return;
    const float4 v = *(const float4*)&in[(size_t)T * 4];
    ushort4 o;
    o.x = f2bf(v.x); o.y = f2bf(v.y); o.z = f2bf(v.z); o.w = f2bf(v.w);
    *(ushort4*)&out[(size_t)T * 4] = o;
}

// ---------- transpose+convert: in[Kd][Nd] f32 -> out[Nd][Kd] bf16 ----------
__global__ void ktrans(const float* __restrict__ in, uint16_t* __restrict__ out,
                       int Kd, int Nd) {
    __shared__ float tile[32][33];
    const int n0 = blockIdx.x * 32, k0 = blockIdx.y * 32;
    const int tx = threadIdx.x & 31, ty = threadIdx.x >> 5;   // ty 0..7
#pragma unroll
    for (int i = 0; i < 4; ++i)
        tile[ty + i * 8][tx] = in[(size_t)(k0 + ty + i * 8) * Nd + n0 + tx];
    __syncthreads();
#pragma unroll
    for (int i = 0; i < 4; ++i)
        out[(size_t)(n0 + ty + i * 8) * Kd + k0 + tx] = f2bf(tile[tx][ty + i * 8]);
}

// ---------- Wxt[64][2048] f32 = W_x^T zero-padded (33 -> 64 rows) ----------
__global__ void kwxt(const float* __restrict__ Wx, float* __restrict__ Wxt) {
    const int T = blockIdx.x * 256 + threadIdx.x;   // 64*2048
    const int j = T >> 11, k = T & 2047;
    Wxt[T] = (j < 33) ? Wx[(size_t)k * 33 + j] : 0.f;
}

// ---------- TN bf16 MFMA GEMM: C[M][ldc] = A[M][KDIM] * B[ldc-cols][KDIM]^T ----------
// LDS tiles [128][32] bf16, 16B-slot XOR swizzle: phys_slot = log_slot ^ ((row>>1)&3)
template<int KDIM>
__global__ __launch_bounds__(256) void kgemm(const uint16_t* __restrict__ A,
                                             const uint16_t* __restrict__ B,
                                             float* __restrict__ C, const int ldc) {
    __shared__ uint16_t As[128 * 32];
    __shared__ uint16_t Bs[128 * 32];
    const int t = threadIdx.x;
    const int w = t >> 6, lane = t & 63;
    const int m0 = blockIdx.y * 128, n0 = blockIdx.x * 128;
    const int wm = (w >> 1) * 64, wn = (w & 1) * 64;
    f32x4 acc[4][4] = {};

    const int srow = t >> 2;                              // 0..63
    const int scol = ((t & 3) ^ ((t >> 3) & 3)) * 8;      // pre-swizzled source slot
    const uint16_t* ga0 = A + (size_t)(m0 + srow) * KDIM + scol;
    const uint16_t* ga1 = A + (size_t)(m0 + 64 + srow) * KDIM + scol;
    const uint16_t* gb0 = B + (size_t)(n0 + srow) * KDIM + scol;
    const uint16_t* gb1 = B + (size_t)(n0 + 64 + srow) * KDIM + scol;
    uint16_t* lA0 = &As[w * 512];
    uint16_t* lA1 = &As[2048 + w * 512];
    uint16_t* lB0 = &Bs[w * 512];
    uint16_t* lB1 = &Bs[2048 + w * 512];

    const int fr = lane & 15, fg = (lane >> 4) * 8;
    const int psl = (((fg >> 3) ^ ((fr >> 1) & 3)) << 3); // swizzled read slot (elems)

    for (int kt = 0; kt < KDIM / 32; ++kt) {
        const int ko = kt * 32;
        gload16(ga0 + ko, lA0);
        gload16(ga1 + ko, lA1);
        gload16(gb0 + ko, lB0);
        gload16(gb1 + ko, lB1);
        __syncthreads();
        short8 a[4], b[4];
#pragma unroll
        for (int i = 0; i < 4; ++i) {
            a[i] = *(const short8*)&As[(wm + i * 16 + fr) * 32 + psl];
            b[i] = *(const short8*)&Bs[(wn + i * 16 + fr) * 32 + psl];
        }
#pragma unroll
        for (int i = 0; i < 4; ++i)
#pragma unroll
            for (int j = 0; j < 4; ++j)
                acc[i][j] = __builtin_amdgcn_mfma_f32_16x16x32_bf16(a[i], b[j], acc[i][j], 0, 0, 0);
        __syncthreads();
    }
    const int cr = (lane >> 4) * 4, cc = lane & 15;
#pragma unroll
    for (int i = 0; i < 4; ++i)
#pragma unroll
        for (int j = 0; j < 4; ++j)
#pragma unroll
            for (int r = 0; r < 4; ++r)
                C[(size_t)(m0 + wm + i * 16 + cr + r) * ldc + (n0 + wn + j * 16 + cc)] = acc[i][j][r];
}

// ---------- GEMM2 MFMA K-split: part[kb][4096][48] = xs(chunk) @ Wxt^T ----------
// A = xs f32 [4096][2048], B = Wxt f32 [64][2048]; f32 staged, bf16 fragments.
// f32 LDS tiles, 16B-slot swizzle: phys = log ^ (row&7)
__global__ __launch_bounds__(256) void kgemm2m(const float* __restrict__ xs,
        const float* __restrict__ Wxt, float* __restrict__ part) {
    __shared__ float As[128 * 32];   // 16 KB
    __shared__ float Bs[64 * 32];    // 8 KB
    const int t = threadIdx.x;
    const int w = t >> 6, lane = t & 63;
    const int kb = blockIdx.x;              // 0..15
    const int m0 = blockIdx.y * 128;
    const int kc = kb * 128;
    f32x4 acc[2][3] = {};

    const int srow = t >> 3;                            // 0..31
    const int scol = ((t & 7) ^ ((t >> 3) & 7)) * 4;    // pre-swizzled source (floats)
    float* lA[4]; float* lB[2];
#pragma unroll
    for (int r = 0; r < 4; ++r) lA[r] = &As[(r * 32 + w * 8) * 32];
#pragma unroll
    for (int r = 0; r < 2; ++r) lB[r] = &Bs[(r * 32 + w * 8) * 32];

    const int wm = w * 32;
    const int fr = lane & 15, fg = (lane >> 4) * 8;
    const int plo = (((fg >> 2) ^ (fr & 7))) * 4;       // float idx of swizzled lo slot
    const int phi = ((((fg >> 2) + 1) ^ (fr & 7))) * 4;

    for (int kt = 0; kt < 4; ++kt) {
        const int ko = kc + kt * 32;
#pragma unroll
        for (int r = 0; r < 4; ++r)
            gload16f(xs + (size_t)(m0 + r * 32 + srow) * 2048 + ko + scol, lA[r]);
#pragma unroll
        for (int r = 0; r < 2; ++r)
            gload16f(Wxt + (size_t)(r * 32 + srow) * 2048 + ko + scol, lB[r]);
        __syncthreads();
        short8 a[2], b[3];
#pragma unroll
        for (int i = 0; i < 2; ++i) {
            const float* base = &As[(wm + i * 16 + fr) * 32];
            a[i] = pack8(*(const float4*)&base[plo], *(const float4*)&base[phi]);
        }
#pragma unroll
        for (int j = 0; j < 3; ++j) {
            const float* base = &Bs[(j * 16 + fr) * 32];
            b[j] = pack8(*(const float4*)&base[plo], *(const float4*)&base[phi]);
        }
#pragma unroll
        for (int i = 0; i < 2; ++i)
#pragma unroll
            for (int j = 0; j < 3; ++j)
                acc[i][j] = __builtin_amdgcn_mfma_f32_16x16x32_bf16(a[i], b[j], acc[i][j], 0, 0, 0);
        __syncthreads();
    }
    const int cr = (lane >> 4) * 4, cc = lane & 15;
    float* pb = part + (size_t)kb * 4096 * 48;
#pragma unroll
    for (int i = 0; i < 2; ++i)
#pragma unroll
        for (int j = 0; j < 3; ++j)
#pragma unroll
            for (int r = 0; r < 4; ++r)
                pb[(size_t)(m0 + wm + i * 16 + cr + r) * 48 + j * 16 + cc] = acc[i][j][r];
}

// ---------- reduce K-split partials -> bcd ----------
__global__ void kred2(const float* __restrict__ part, float* __restrict__ bcd) {
    const int T = blockIdx.x * 256 + threadIdx.x;   // 4096*48
    if (T >= 4096 * 48) return;
    const int row = T / 48, j = T - row * 48;
    if (j >= 33) return;
    float s = 0.f;
#pragma unroll
    for (int ks = 0; ks < KS2; ++ks) s += part[(size_t)ks * 4096 * 48 + T];
    bcd[(size_t)row * BCD_LD + j] = s;
}

// ---------- causal depthwise conv (k=4) + bias + SiLU ----------
__global__ void kconv(const float* __restrict__ xz, const float* __restrict__ cw,
                      const float* __restrict__ cb, float* __restrict__ xs) {
    size_t T = (size_t)blockIdx.x * 256 + threadIdx.x;   // over NROWS*D_INNER
    int d = (int)(T & (D_INNER - 1));
    int row = (int)(T >> 11);
    int l = row & (SEQLEN - 1), b = row >> 11;
    const float4 w4 = *(const float4*)&cw[d * 4];
    float acc = cb[d];
    const size_t base = (size_t)b * SEQLEN;
    if (l >= 3) {
        acc += w4.x * xz[(base + l - 3) * 4096 + d];
        acc += w4.y * xz[(base + l - 2) * 4096 + d];
        acc += w4.z * xz[(base + l - 1) * 4096 + d];
        acc += w4.w * xz[(base + l    ) * 4096 + d];
    } else {
        if (l >= 2) acc += w4.y * xz[(base + l - 2) * 4096 + d];
        if (l >= 1) acc += w4.z * xz[(base + l - 1) * 4096 + d];
        acc += w4.w * xz[(base + l) * 4096 + d];
    }
    xs[T] = silu_f(acc);
}

// ---------- scan phase 1: per (chunk, channel): sum(dt), h_local (h0=0) ----------
__global__ __launch_bounds__(256) void kscan1(const float* __restrict__ xs,
        const float* __restrict__ bcd, const float* __restrict__ wdt,
        const float* __restrict__ bdt, const float* __restrict__ Alog,
        float* __restrict__ hloc, float* __restrict__ sumdt) {
    const int T = blockIdx.x * 256 + threadIdx.x;
    const int sub = T & 3;
    const int ch = (T >> 2) & 4095;
    const int chunk = T >> 14;
    const int b = ch >> 11, d = ch & 2047;
    float Ae[4];
#pragma unroll
    for (int i = 0; i < 4; ++i) Ae[i] = -__expf(Alog[d * 16 + sub * 4 + i]) * L2E;
    const float w = wdt[d], bb = bdt[d];
    float h0 = 0, h1 = 0, h2 = 0, h3 = 0, sdt = 0;
    const int row0 = b * SEQLEN + chunk * CHUNKLEN;
    for (int l0 = 0; l0 < CHUNKLEN; l0 += 4) {
        float raw[4], xv[4]; float4 B4[4];
#pragma unroll
        for (int s = 0; s < 4; ++s) {
            const int row = row0 + l0 + s;
            raw[s] = bcd[(size_t)row * BCD_LD + 32];
            xv[s]  = xs[(size_t)row * D_INNER + d];
            B4[s]  = *(const float4*)&bcd[(size_t)row * BCD_LD + sub * 4];
        }
#pragma unroll
        for (int s = 0; s < 4; ++s) {
            const float dtv = softplus_f(raw[s] * w + bb);
            sdt += dtv;
            const float dtx = dtv * xv[s];
            h0 = __builtin_amdgcn_exp2f(dtv * Ae[0]) * h0 + dtx * B4[s].x;
            h1 = __builtin_amdgcn_exp2f(dtv * Ae[1]) * h1 + dtx * B4[s].y;
            h2 = __builtin_amdgcn_exp2f(dtv * Ae[2]) * h2 + dtx * B4[s].z;
            h3 = __builtin_amdgcn_exp2f(dtv * Ae[3]) * h3 + dtx * B4[s].w;
        }
    }
    const int cc = chunk * 4096 + ch;
    *(float4*)&hloc[(size_t)cc * 16 + sub * 4] = make_float4(h0, h1, h2, h3);
    if (sub == 0) sumdt[cc] = sdt;
}

// ---------- scan phase 2: sequential chunk combine -> h at chunk starts ----------
__global__ void kscan2(const float* __restrict__ hloc, const float* __restrict__ sumdt,
                       const float* __restrict__ Alog, float* __restrict__ h0buf) {
    const int T = blockIdx.x * 256 + threadIdx.x;   // 65536
    const int n = T & 15, ch = T >> 4;
    const int d = ch & 2047;
    const float Ae = -__expf(Alog[d * 16 + n]) * L2E;
    float h = 0.f;
    for (int c = 0; c < NCHUNK; ++c) {
        const int cc = c * 4096 + ch;
        h0buf[(size_t)cc * 16 + n] = h;
        h = __builtin_amdgcn_exp2f(Ae * sumdt[cc]) * h + hloc[(size_t)cc * 16 + n];
    }
}

// ---------- scan phase 3: replay with h0, emit u = (y + x*Dp)*silu(z) bf16 ----------
__global__ __launch_bounds__(256) void kscan3(const float* __restrict__ xs,
        const float* __restrict__ bcd, const float* __restrict__ wdt,
        const float* __restrict__ bdt, const float* __restrict__ Alog,
        const float* __restrict__ Dp, const float* __restrict__ xz,
        const float* __restrict__ h0buf, uint16_t* __restrict__ u) {
    const int T = blockIdx.x * 256 + threadIdx.x;
    const int sub = T & 3;
    const int ch = (T >> 2) & 4095;
    const int chunk = T >> 14;
    const int b = ch >> 11, d = ch & 2047;
    float Ae[4];
#pragma unroll
    for (int i = 0; i < 4; ++i) Ae[i] = -__expf(Alog[d * 16 + sub * 4 + i]) * L2E;
    const float w = wdt[d], bb = bdt[d];
    const float Dpd = Dp[d];
    const float4 hh = *(const float4*)&h0buf[(size_t)(chunk * 4096 + ch) * 16 + sub * 4];
    float h0 = hh.x, h1 = hh.y, h2 = hh.z, h3 = hh.w;
    const int row0 = b * SEQLEN + chunk * CHUNKLEN;
    for (int l0 = 0; l0 < CHUNKLEN; l0 += 4) {
        float raw[4], xv[4], zv[4]; float4 B4[4], C4[4];
#pragma unroll
        for (int s = 0; s < 4; ++s) {
            const int row = row0 + l0 + s;
            raw[s] = bcd[(size_t)row * BCD_LD + 32];
            xv[s]  = xs[(size_t)row * D_INNER + d];
            B4[s]  = *(const float4*)&bcd[(size_t)row * BCD_LD + sub * 4];
            C4[s]  = *(const float4*)&bcd[(size_t)row * BCD_LD + 16 + sub * 4];
            if (sub == 0) zv[s] = xz[(size_t)row * 4096 + 2048 + d];
        }
#pragma unroll
        for (int s = 0; s < 4; ++s) {
            const int row = row0 + l0 + s;
            const float dtv = softplus_f(raw[s] * w + bb);
            const float dtx = dtv * xv[s];
            h0 = __builtin_amdgcn_exp2f(dtv * Ae[0]) * h0 + dtx * B4[s].x;
            h1 = __builtin_amdgcn_exp2f(dtv * Ae[1]) * h1 + dtx * B4[s].y;
            h2 = __builtin_amdgcn_exp2f(dtv * Ae[2]) * h2 + dtx * B4[s].z;
            h3 = __builtin_amdgcn_exp2f(dtv * Ae[3]) * h3 + dtx * B4[s].w;
            float yp = h0 * C4[s].x + h1 * C4[s].y + h2 * C4[s].z + h3 * C4[s].w;
            yp += __shfl_xor(yp, 1);
            yp += __shfl_xor(yp, 2);
            if (sub == 0) {
                const float uu = (yp + xv[s] * Dpd) * silu_f(zv[s]);
                u[(size_t)row * D_INNER + d] = f2bf(uu);
            }
        }
    }
}

extern "C" void kernel_launch(void* const* d_in, const int* in_sizes, int n_in,
                              void* d_out, int out_size, void* d_ws, size_t ws_size,
                              hipStream_t stream) {
    const float* x      = (const float*)d_in[0];
    const float* W_in   = (const float*)d_in[1];
    const float* conv_w = (const float*)d_in[2];
    const float* conv_b = (const float*)d_in[3];
    const float* W_x    = (const float*)d_in[4];
    const float* w_dt   = (const float*)d_in[5];
    const float* b_dt   = (const float*)d_in[6];
    const float* A_log  = (const float*)d_in[7];
    const float* Dp     = (const float*)d_in[8];
    const float* W_out  = (const float*)d_in[9];
    float* out = (float*)d_out;

    char* p = (char*)d_ws;
    uint16_t* xb  = (uint16_t*)p;  p += (size_t)NROWS * D_MODEL * 2;      // 8 MB (dead after gemm1)
    uint16_t* Wb  = (uint16_t*)p;  p += (size_t)4096 * 1024 * 2;          // 8 MB (dead after gemm1)
    uint16_t* Wob = (uint16_t*)p;  p += (size_t)1024 * 2048 * 2;          // 4 MB  (W_out^T)
    float* xz     = (float*)p;     p += (size_t)NROWS * 4096 * 4;         // 64 MB
    float* xs     = (float*)p;     p += (size_t)NROWS * D_INNER * 4;      // 32 MB
    float* bcd    = (float*)p;     p += (size_t)NROWS * BCD_LD * 4;       // 576 KB
    float* sumdt  = (float*)p;     p += (size_t)NCHUNK * 4096 * 4;        // 512 KB
    float* Wxt    = (float*)p;     p += (size_t)64 * 2048 * 4;            // 512 KB
    uint16_t* ub  = (uint16_t*)p;  p += (size_t)NROWS * D_INNER * 2;      // 16 MB
    // overlays (regions dead during their use):
    float* hloc   = (float*)xb;    // 8 MB  (xb dead after gemm1)
    float* h0b    = (float*)Wb;    // 8 MB  (Wb dead after gemm1)
    float* part   = (float*)ub;    // 12.6 MB (ub written only by kscan3, later)

    // 1) dtype prep
    kcvt<<<(NROWS * D_MODEL / 4 + 255) / 256, 256, 0, stream>>>(x, xb, NROWS * D_MODEL / 4);
    ktrans<<<dim3(4096 / 32, 1024 / 32), 256, 0, stream>>>(W_in, Wb, 1024, 4096);
    ktrans<<<dim3(1024 / 32, 2048 / 32), 256, 0, stream>>>(W_out, Wob, 2048, 1024);
    kwxt<<<(64 * 2048) / 256, 256, 0, stream>>>(W_x, Wxt);
    // 2) xz = x @ W_in   (M=4096, N=4096, K=1024)
    kgemm<1024><<<dim3(32, 32), 256, 0, stream>>>(xb, Wb, xz, 4096);
    // 3) conv + silu
    kconv<<<NROWS * D_INNER / 256, 256, 0, stream>>>(xz, conv_w, conv_b, xs);
    // 4) bcd = xs @ W_x  (MFMA, K-split 16 + reduce)
    kgemm2m<<<dim3(KS2, 32), 256, 0, stream>>>(xs, Wxt, part);
    kred2<<<(4096 * 48 + 255) / 256, 256, 0, stream>>>(part, bcd);
    // 5) selective scan (3 phases)
    kscan1<<<(4096 * 4 * NCHUNK) / 256, 256, 0, stream>>>(xs, bcd, w_dt, b_dt, A_log, hloc, sumdt);
    kscan2<<<(4096 * 16) / 256, 256, 0, stream>>>(hloc, sumdt, A_log, h0b);
    kscan3<<<(4096 * 4 * NCHUNK) / 256, 256, 0, stream>>>(xs, bcd, w_dt, b_dt, A_log, Dp, xz, h0b, ub);
    // 6) out = u @ W_out (M=4096, N=1024, K=2048)
    kgemm<2048><<<dim3(1024 / 128, 32), 256, 0, stream>>>(ub, Wob, out, 1024);
}

// Round 4
// 240.988 us; speedup vs baseline: 2.2291x; 1.0771x over previous
//
#include <hip/hip_runtime.h>
#include <hip/hip_bf16.h>
#include <stdint.h>

#define D_MODEL 1024
#define D_STATE 16
#define D_CONV  4
#define D_INNER 2048
#define BATCH   2
#define SEQLEN  2048
#define NROWS   (BATCH*SEQLEN)     // 4096
#define BCD_LD  36                 // padded leading dim for bcd (33 used)
#define NCHUNK  32
#define CHUNKLEN (SEQLEN/NCHUNK)   // 64
#define KS2     16                 // K-splits for GEMM2 (chunk = 128)
#define L2E 1.44269504088896340f

typedef __attribute__((ext_vector_type(8))) short   short8;
typedef __attribute__((ext_vector_type(4))) float   f32x4;

__device__ __forceinline__ uint16_t f2bf(float f) {        // RNE f32->bf16
    uint32_t u = __float_as_uint(f);
    return (uint16_t)((u + 0x7FFFu + ((u >> 16) & 1u)) >> 16);
}
__device__ __forceinline__ void gload16(const uint16_t* g, uint16_t* l) {
    __builtin_amdgcn_global_load_lds(
        (const __attribute__((address_space(1))) void*)g,
        (__attribute__((address_space(3))) void*)l, 16, 0, 0);
}
__device__ __forceinline__ void gload16f(const float* g, float* l) {
    __builtin_amdgcn_global_load_lds(
        (const __attribute__((address_space(1))) void*)g,
        (__attribute__((address_space(3))) void*)l, 16, 0, 0);
}
__device__ __forceinline__ float softplus_f(float v) {
    return fmaxf(v, 0.f) + __logf(1.f + __expf(-fabsf(v)));
}
__device__ __forceinline__ float silu_f(float v) {
    return v / (1.f + __expf(-v));
}
__device__ __forceinline__ short8 pack8(const float4 lo, const float4 hi) {
    short8 r;
    r[0] = (short)f2bf(lo.x); r[1] = (short)f2bf(lo.y);
    r[2] = (short)f2bf(lo.z); r[3] = (short)f2bf(lo.w);
    r[4] = (short)f2bf(hi.x); r[5] = (short)f2bf(hi.y);
    r[6] = (short)f2bf(hi.z); r[7] = (short)f2bf(hi.w);
    return r;
}

// ---------- f32 -> bf16 elementwise (x) ----------
__global__ void kcvt(const float* __restrict__ in, uint16_t* __restrict__ out, int n4) {
    int T = blockIdx.x * 256 + threadIdx.x;
    if (T >= n4) return;
    const float4 v = *(const float4*)&in[(size_t)T * 4];
    ushort4 o;
    o.x = f2bf(v.x); o.y = f2bf(v.y); o.z = f2bf(v.z); o.w = f2bf(v.w);
    *(ushort4*)&out[(size_t)T * 4] = o;
}

// ---------- transpose+convert: in[Kd][Nd] f32 -> out[Nd][Kd] bf16 ----------
__global__ void ktrans(const float* __restrict__ in, uint16_t* __restrict__ out,
                       int Kd, int Nd) {
    __shared__ float tile[32][33];
    const int n0 = blockIdx.x * 32, k0 = blockIdx.y * 32;
    const int tx = threadIdx.x & 31, ty = threadIdx.x >> 5;   // ty 0..7
#pragma unroll
    for (int i = 0; i < 4; ++i)
        tile[ty + i * 8][tx] = in[(size_t)(k0 + ty + i * 8) * Nd + n0 + tx];
    __syncthreads();
#pragma unroll
    for (int i = 0; i < 4; ++i)
        out[(size_t)(n0 + ty + i * 8) * Kd + k0 + tx] = f2bf(tile[tx][ty + i * 8]);
}

// ---------- Wxt[64][2048] f32 = W_x^T zero-padded (33 -> 64 rows) ----------
__global__ void kwxt(const float* __restrict__ Wx, float* __restrict__ Wxt) {
    const int T = blockIdx.x * 256 + threadIdx.x;   // 64*2048
    const int j = T >> 11, k = T & 2047;
    Wxt[T] = (j < 33) ? Wx[(size_t)k * 33 + j] : 0.f;
}

// ---------- TN bf16 MFMA GEMM 128x128: C = A * B^T ----------
template<int KDIM>
__global__ __launch_bounds__(256) void kgemm(const uint16_t* __restrict__ A,
                                             const uint16_t* __restrict__ B,
                                             float* __restrict__ C, const int ldc) {
    __shared__ uint16_t As[128 * 32];
    __shared__ uint16_t Bs[128 * 32];
    const int t = threadIdx.x;
    const int w = t >> 6, lane = t & 63;
    const int m0 = blockIdx.y * 128, n0 = blockIdx.x * 128;
    const int wm = (w >> 1) * 64, wn = (w & 1) * 64;
    f32x4 acc[4][4] = {};

    const int srow = t >> 2;                              // 0..63
    const int scol = ((t & 3) ^ ((t >> 3) & 3)) * 8;      // pre-swizzled source slot
    const uint16_t* ga0 = A + (size_t)(m0 + srow) * KDIM + scol;
    const uint16_t* ga1 = A + (size_t)(m0 + 64 + srow) * KDIM + scol;
    const uint16_t* gb0 = B + (size_t)(n0 + srow) * KDIM + scol;
    const uint16_t* gb1 = B + (size_t)(n0 + 64 + srow) * KDIM + scol;
    uint16_t* lA0 = &As[w * 512];
    uint16_t* lA1 = &As[2048 + w * 512];
    uint16_t* lB0 = &Bs[w * 512];
    uint16_t* lB1 = &Bs[2048 + w * 512];

    const int fr = lane & 15, fg = (lane >> 4) * 8;
    const int psl = (((fg >> 3) ^ ((fr >> 1) & 3)) << 3); // swizzled read slot (elems)

    for (int kt = 0; kt < KDIM / 32; ++kt) {
        const int ko = kt * 32;
        gload16(ga0 + ko, lA0);
        gload16(ga1 + ko, lA1);
        gload16(gb0 + ko, lB0);
        gload16(gb1 + ko, lB1);
        __syncthreads();
        short8 a[4], b[4];
#pragma unroll
        for (int i = 0; i < 4; ++i) {
            a[i] = *(const short8*)&As[(wm + i * 16 + fr) * 32 + psl];
            b[i] = *(const short8*)&Bs[(wn + i * 16 + fr) * 32 + psl];
        }
#pragma unroll
        for (int i = 0; i < 4; ++i)
#pragma unroll
            for (int j = 0; j < 4; ++j)
                acc[i][j] = __builtin_amdgcn_mfma_f32_16x16x32_bf16(a[i], b[j], acc[i][j], 0, 0, 0);
        __syncthreads();
    }
    const int cr = (lane >> 4) * 4, cc = lane & 15;
#pragma unroll
    for (int i = 0; i < 4; ++i)
#pragma unroll
        for (int j = 0; j < 4; ++j)
#pragma unroll
            for (int r = 0; r < 4; ++r)
                C[(size_t)(m0 + wm + i * 16 + cr + r) * ldc + (n0 + wn + j * 16 + cc)] = acc[i][j][r];
}

// ---------- TN bf16 MFMA GEMM 64x128 (more blocks for small-N GEMM3) ----------
template<int KDIM>
__global__ __launch_bounds__(256) void kgemm64(const uint16_t* __restrict__ A,
                                               const uint16_t* __restrict__ B,
                                               float* __restrict__ C, const int ldc) {
    __shared__ uint16_t As[64 * 32];     // 4 KB
    __shared__ uint16_t Bs[128 * 32];    // 8 KB
    const int t = threadIdx.x;
    const int w = t >> 6, lane = t & 63;
    const int m0 = blockIdx.y * 64, n0 = blockIdx.x * 128;
    const int wm = (w >> 1) * 32, wn = (w & 1) * 64;
    f32x4 acc[2][4] = {};

    const int srow = t >> 2;
    const int scol = ((t & 3) ^ ((t >> 3) & 3)) * 8;
    const uint16_t* ga0 = A + (size_t)(m0 + srow) * KDIM + scol;
    const uint16_t* gb0 = B + (size_t)(n0 + srow) * KDIM + scol;
    const uint16_t* gb1 = B + (size_t)(n0 + 64 + srow) * KDIM + scol;
    uint16_t* lA0 = &As[w * 512];
    uint16_t* lB0 = &Bs[w * 512];
    uint16_t* lB1 = &Bs[2048 + w * 512];

    const int fr = lane & 15, fg = (lane >> 4) * 8;
    const int psl = (((fg >> 3) ^ ((fr >> 1) & 3)) << 3);

    for (int kt = 0; kt < KDIM / 32; ++kt) {
        const int ko = kt * 32;
        gload16(ga0 + ko, lA0);
        gload16(gb0 + ko, lB0);
        gload16(gb1 + ko, lB1);
        __syncthreads();
        short8 a[2], b[4];
#pragma unroll
        for (int i = 0; i < 2; ++i)
            a[i] = *(const short8*)&As[(wm + i * 16 + fr) * 32 + psl];
#pragma unroll
        for (int j = 0; j < 4; ++j)
            b[j] = *(const short8*)&Bs[(wn + j * 16 + fr) * 32 + psl];
#pragma unroll
        for (int i = 0; i < 2; ++i)
#pragma unroll
            for (int j = 0; j < 4; ++j)
                acc[i][j] = __builtin_amdgcn_mfma_f32_16x16x32_bf16(a[i], b[j], acc[i][j], 0, 0, 0);
        __syncthreads();
    }
    const int cr = (lane >> 4) * 4, cc = lane & 15;
#pragma unroll
    for (int i = 0; i < 2; ++i)
#pragma unroll
        for (int j = 0; j < 4; ++j)
#pragma unroll
            for (int r = 0; r < 4; ++r)
                C[(size_t)(m0 + wm + i * 16 + cr + r) * ldc + (n0 + wn + j * 16 + cc)] = acc[i][j][r];
}

// ---------- GEMM2 MFMA K-split: part[kb][4096][48] = xs(chunk) @ Wxt^T ----------
__global__ __launch_bounds__(256) void kgemm2m(const float* __restrict__ xs,
        const float* __restrict__ Wxt, float* __restrict__ part) {
    __shared__ float As[128 * 32];   // 16 KB
    __shared__ float Bs[64 * 32];    // 8 KB
    const int t = threadIdx.x;
    const int w = t >> 6, lane = t & 63;
    const int kb = blockIdx.x;              // 0..15
    const int m0 = blockIdx.y * 128;
    const int kc = kb * 128;
    f32x4 acc[2][3] = {};

    const int srow = t >> 3;                            // 0..31
    const int scol = ((t & 7) ^ ((t >> 3) & 7)) * 4;    // pre-swizzled source (floats)
    float* lA[4]; float* lB[2];
#pragma unroll
    for (int r = 0; r < 4; ++r) lA[r] = &As[(r * 32 + w * 8) * 32];
#pragma unroll
    for (int r = 0; r < 2; ++r) lB[r] = &Bs[(r * 32 + w * 8) * 32];

    const int wm = w * 32;
    const int fr = lane & 15, fg = (lane >> 4) * 8;
    const int plo = (((fg >> 2) ^ (fr & 7))) * 4;
    const int phi = ((((fg >> 2) + 1) ^ (fr & 7))) * 4;

    for (int kt = 0; kt < 4; ++kt) {
        const int ko = kc + kt * 32;
#pragma unroll
        for (int r = 0; r < 4; ++r)
            gload16f(xs + (size_t)(m0 + r * 32 + srow) * 2048 + ko + scol, lA[r]);
#pragma unroll
        for (int r = 0; r < 2; ++r)
            gload16f(Wxt + (size_t)(r * 32 + srow) * 2048 + ko + scol, lB[r]);
        __syncthreads();
        short8 a[2], b[3];
#pragma unroll
        for (int i = 0; i < 2; ++i) {
            const float* base = &As[(wm + i * 16 + fr) * 32];
            a[i] = pack8(*(const float4*)&base[plo], *(const float4*)&base[phi]);
        }
#pragma unroll
        for (int j = 0; j < 3; ++j) {
            const float* base = &Bs[(j * 16 + fr) * 32];
            b[j] = pack8(*(const float4*)&base[plo], *(const float4*)&base[phi]);
        }
#pragma unroll
        for (int i = 0; i < 2; ++i)
#pragma unroll
            for (int j = 0; j < 3; ++j)
                acc[i][j] = __builtin_amdgcn_mfma_f32_16x16x32_bf16(a[i], b[j], acc[i][j], 0, 0, 0);
        __syncthreads();
    }
    const int cr = (lane >> 4) * 4, cc = lane & 15;
    float* pb = part + (size_t)kb * 4096 * 48;
#pragma unroll
    for (int i = 0; i < 2; ++i)
#pragma unroll
        for (int j = 0; j < 3; ++j)
#pragma unroll
            for (int r = 0; r < 4; ++r)
                pb[(size_t)(m0 + wm + i * 16 + cr + r) * 48 + j * 16 + cc] = acc[i][j][r];
}

// ---------- reduce K-split partials -> bcd ----------
__global__ void kred2(const float* __restrict__ part, float* __restrict__ bcd) {
    const int T = blockIdx.x * 256 + threadIdx.x;   // 4096*48
    if (T >= 4096 * 48) return;
    const int row = T / 48, j = T - row * 48;
    if (j >= 33) return;
    float s = 0.f;
#pragma unroll
    for (int ks = 0; ks < KS2; ++ks) s += part[(size_t)ks * 4096 * 48 + T];
    bcd[(size_t)row * BCD_LD + j] = s;
}

// ---------- dt precompute: dt[row][d] = softplus(raw[row]*w_dt[d]+b_dt[d]) ----------
// stored at stride 4096 into the dead x_-half of xz
__global__ void kdt(const float* __restrict__ bcd, const float* __restrict__ wdt,
                    const float* __restrict__ bdt, float* __restrict__ dtb) {
    const int T = blockIdx.x * 256 + threadIdx.x;   // 4096*512
    const int row = T >> 9, dg = (T & 511) * 4;
    const float raw = bcd[(size_t)row * BCD_LD + 32];
    const float4 w = *(const float4*)&wdt[dg];
    const float4 b = *(const float4*)&bdt[dg];
    float4 o;
    o.x = softplus_f(raw * w.x + b.x);
    o.y = softplus_f(raw * w.y + b.y);
    o.z = softplus_f(raw * w.z + b.z);
    o.w = softplus_f(raw * w.w + b.w);
    *(float4*)&dtb[(size_t)row * 4096 + dg] = o;
}

// ---------- scan phase 1: per (chunk, channel): sum(dt), h_local (h0=0) ----------
__global__ __launch_bounds__(256) void kscan1(const float* __restrict__ xs,
        const float* __restrict__ bcd, const float* __restrict__ dtb,
        const float* __restrict__ Alog,
        float* __restrict__ hloc, float* __restrict__ sumdt) {
    const int T = blockIdx.x * 256 + threadIdx.x;
    const int sub = T & 3;
    const int ch = (T >> 2) & 4095;
    const int chunk = T >> 14;
    const int b = ch >> 11, d = ch & 2047;
    float Ae[4]; bool structured = true;
#pragma unroll
    for (int i = 0; i < 4; ++i) {
        const float a = __expf(Alog[d * 16 + sub * 4 + i]);
        Ae[i] = -a * L2E;
        structured = structured && (fabsf(a - (float)(sub * 4 + i + 1)) < 1e-3f);
    }
    float h0 = 0, h1 = 0, h2 = 0, h3 = 0, sdt = 0;
    const int row0 = b * SEQLEN + chunk * CHUNKLEN;
    if (structured) {   // A[n] = -(n+1): dA[n] = exp(-dt)^(n+1), 1 trans + mul chain
        for (int l0 = 0; l0 < CHUNKLEN; l0 += 4) {
            float dtv[4], xv[4]; float4 B4[4];
#pragma unroll
            for (int s = 0; s < 4; ++s) {
                const int row = row0 + l0 + s;
                dtv[s] = dtb[(size_t)row * 4096 + d];
                xv[s]  = xs[(size_t)row * D_INNER + d];
                B4[s]  = *(const float4*)&bcd[(size_t)row * BCD_LD + sub * 4];
            }
#pragma unroll
            for (int s = 0; s < 4; ++s) {
                const float e0 = __builtin_amdgcn_exp2f(dtv[s] * (-L2E));
                const float e2 = e0 * e0, e4 = e2 * e2, e8 = e4 * e4;
                const float bs = ((sub & 1) ? e4 : 1.f) * ((sub & 2) ? e8 : 1.f);
                const float d0 = bs * e0, d1 = d0 * e0, d2 = d1 * e0, d3 = d2 * e0;
                sdt += dtv[s];
                const float dtx = dtv[s] * xv[s];
                h0 = d0 * h0 + dtx * B4[s].x;
                h1 = d1 * h1 + dtx * B4[s].y;
                h2 = d2 * h2 + dtx * B4[s].z;
                h3 = d3 * h3 + dtx * B4[s].w;
            }
        }
    } else {
        for (int l0 = 0; l0 < CHUNKLEN; l0 += 4) {
            float dtv[4], xv[4]; float4 B4[4];
#pragma unroll
            for (int s = 0; s < 4; ++s) {
                const int row = row0 + l0 + s;
                dtv[s] = dtb[(size_t)row * 4096 + d];
                xv[s]  = xs[(size_t)row * D_INNER + d];
                B4[s]  = *(const float4*)&bcd[(size_t)row * BCD_LD + sub * 4];
            }
#pragma unroll
            for (int s = 0; s < 4; ++s) {
                sdt += dtv[s];
                const float dtx = dtv[s] * xv[s];
                h0 = __builtin_amdgcn_exp2f(dtv[s] * Ae[0]) * h0 + dtx * B4[s].x;
                h1 = __builtin_amdgcn_exp2f(dtv[s] * Ae[1]) * h1 + dtx * B4[s].y;
                h2 = __builtin_amdgcn_exp2f(dtv[s] * Ae[2]) * h2 + dtx * B4[s].z;
                h3 = __builtin_amdgcn_exp2f(dtv[s] * Ae[3]) * h3 + dtx * B4[s].w;
            }
        }
    }
    const int cc = chunk * 4096 + ch;
    *(float4*)&hloc[(size_t)cc * 16 + sub * 4] = make_float4(h0, h1, h2, h3);
    if (sub == 0) sumdt[cc] = sdt;
}

// ---------- scan phase 2: sequential chunk combine -> h at chunk starts ----------
__global__ void kscan2(const float* __restrict__ hloc, const float* __restrict__ sumdt,
                       const float* __restrict__ Alog, float* __restrict__ h0buf) {
    const int T = blockIdx.x * 256 + threadIdx.x;   // 65536
    const int n = T & 15, ch = T >> 4;
    const int d = ch & 2047;
    const float Ae = -__expf(Alog[d * 16 + n]) * L2E;
    float h = 0.f;
    for (int c = 0; c < NCHUNK; ++c) {
        const int cc = c * 4096 + ch;
        h0buf[(size_t)cc * 16 + n] = h;
        h = __builtin_amdgcn_exp2f(Ae * sumdt[cc]) * h + hloc[(size_t)cc * 16 + n];
    }
}

// ---------- scan phase 3: replay with h0, emit u = (y + x*Dp)*silu(z) bf16 ----------
__global__ __launch_bounds__(256) void kscan3(const float* __restrict__ xs,
        const float* __restrict__ bcd, const float* __restrict__ dtb,
        const float* __restrict__ Alog,
        const float* __restrict__ Dp, const float* __restrict__ xz,
        const float* __restrict__ h0buf, uint16_t* __restrict__ u) {
    const int T = blockIdx.x * 256 + threadIdx.x;
    const int sub = T & 3;
    const int ch = (T >> 2) & 4095;
    const int chunk = T >> 14;
    const int b = ch >> 11, d = ch & 2047;
    float Ae[4]; bool structured = true;
#pragma unroll
    for (int i = 0; i < 4; ++i) {
        const float a = __expf(Alog[d * 16 + sub * 4 + i]);
        Ae[i] = -a * L2E;
        structured = structured && (fabsf(a - (float)(sub * 4 + i + 1)) < 1e-3f);
    }
    const float Dpd = Dp[d];
    const float4 hh = *(const float4*)&h0buf[(size_t)(chunk * 4096 + ch) * 16 + sub * 4];
    float h0 = hh.x, h1 = hh.y, h2 = hh.z, h3 = hh.w;
    const int row0 = b * SEQLEN + chunk * CHUNKLEN;
    if (structured) {
        for (int l0 = 0; l0 < CHUNKLEN; l0 += 4) {
            float dtv[4], xv[4], zv[4]; float4 B4[4], C4[4];
#pragma unroll
            for (int s = 0; s < 4; ++s) {
                const int row = row0 + l0 + s;
                dtv[s] = dtb[(size_t)row * 4096 + d];
                xv[s]  = xs[(size_t)row * D_INNER + d];
                B4[s]  = *(const float4*)&bcd[(size_t)row * BCD_LD + sub * 4];
                C4[s]  = *(const float4*)&bcd[(size_t)row * BCD_LD + 16 + sub * 4];
                if (sub == 0) zv[s] = xz[(size_t)row * 4096 + 2048 + d];
            }
#pragma unroll
            for (int s = 0; s < 4; ++s) {
                const int row = row0 + l0 + s;
                const float e0 = __builtin_amdgcn_exp2f(dtv[s] * (-L2E));
                const float e2 = e0 * e0, e4 = e2 * e2, e8 = e4 * e4;
                const float bs = ((sub & 1) ? e4 : 1.f) * ((sub & 2) ? e8 : 1.f);
                const float d0 = bs * e0, d1 = d0 * e0, d2 = d1 * e0, d3 = d2 * e0;
                const float dtx = dtv[s] * xv[s];
                h0 = d0 * h0 + dtx * B4[s].x;
                h1 = d1 * h1 + dtx * B4[s].y;
                h2 = d2 * h2 + dtx * B4[s].z;
                h3 = d3 * h3 + dtx * B4[s].w;
                float yp = h0 * C4[s].x + h1 * C4[s].y + h2 * C4[s].z + h3 * C4[s].w;
                yp += __shfl_xor(yp, 1);
                yp += __shfl_xor(yp, 2);
                if (sub == 0) {
                    const float uu = (yp + xv[s] * Dpd) * silu_f(zv[s]);
                    u[(size_t)row * D_INNER + d] = f2bf(uu);
                }
            }
        }
    } else {
        for (int l0 = 0; l0 < CHUNKLEN; l0 += 4) {
            float dtv[4], xv[4], zv[4]; float4 B4[4], C4[4];
#pragma unroll
            for (int s = 0; s < 4; ++s) {
                const int row = row0 + l0 + s;
                dtv[s] = dtb[(size_t)row * 4096 + d];
                xv[s]  = xs[(size_t)row * D_INNER + d];
                B4[s]  = *(const float4*)&bcd[(size_t)row * BCD_LD + sub * 4];
                C4[s]  = *(const float4*)&bcd[(size_t)row * BCD_LD + 16 + sub * 4];
                if (sub == 0) zv[s] = xz[(size_t)row * 4096 + 2048 + d];
            }
#pragma unroll
            for (int s = 0; s < 4; ++s) {
                const int row = row0 + l0 + s;
                const float dtx = dtv[s] * xv[s];
                h0 = __builtin_amdgcn_exp2f(dtv[s] * Ae[0]) * h0 + dtx * B4[s].x;
                h1 = __builtin_amdgcn_exp2f(dtv[s] * Ae[1]) * h1 + dtx * B4[s].y;
                h2 = __builtin_amdgcn_exp2f(dtv[s] * Ae[2]) * h2 + dtx * B4[s].z;
                h3 = __builtin_amdgcn_exp2f(dtv[s] * Ae[3]) * h3 + dtx * B4[s].w;
                float yp = h0 * C4[s].x + h1 * C4[s].y + h2 * C4[s].z + h3 * C4[s].w;
                yp += __shfl_xor(yp, 1);
                yp += __shfl_xor(yp, 2);
                if (sub == 0) {
                    const float uu = (yp + xv[s] * Dpd) * silu_f(zv[s]);
                    u[(size_t)row * D_INNER + d] = f2bf(uu);
                }
            }
        }
    }
}

// ---------- causal depthwise conv (k=4) + bias + SiLU ----------
__global__ void kconv(const float* __restrict__ xz, const float* __restrict__ cw,
                      const float* __restrict__ cb, float* __restrict__ xs) {
    size_t T = (size_t)blockIdx.x * 256 + threadIdx.x;   // over NROWS*D_INNER
    int d = (int)(T & (D_INNER - 1));
    int row = (int)(T >> 11);
    int l = row & (SEQLEN - 1), b = row >> 11;
    const float4 w4 = *(const float4*)&cw[d * 4];
    float acc = cb[d];
    const size_t base = (size_t)b * SEQLEN;
    if (l >= 3) {
        acc += w4.x * xz[(base + l - 3) * 4096 + d];
        acc += w4.y * xz[(base + l - 2) * 4096 + d];
        acc += w4.z * xz[(base + l - 1) * 4096 + d];
        acc += w4.w * xz[(base + l    ) * 4096 + d];
    } else {
        if (l >= 2) acc += w4.y * xz[(base + l - 2) * 4096 + d];
        if (l >= 1) acc += w4.z * xz[(base + l - 1) * 4096 + d];
        acc += w4.w * xz[(base + l) * 4096 + d];
    }
    xs[T] = silu_f(acc);
}

extern "C" void kernel_launch(void* const* d_in, const int* in_sizes, int n_in,
                              void* d_out, int out_size, void* d_ws, size_t ws_size,
                              hipStream_t stream) {
    const float* x      = (const float*)d_in[0];
    const float* W_in   = (const float*)d_in[1];
    const float* conv_w = (const float*)d_in[2];
    const float* conv_b = (const float*)d_in[3];
    const float* W_x    = (const float*)d_in[4];
    const float* w_dt   = (const float*)d_in[5];
    const float* b_dt   = (const float*)d_in[6];
    const float* A_log  = (const float*)d_in[7];
    const float* Dp     = (const float*)d_in[8];
    const float* W_out  = (const float*)d_in[9];
    float* out = (float*)d_out;

    char* p = (char*)d_ws;
    uint16_t* xb  = (uint16_t*)p;  p += (size_t)NROWS * D_MODEL * 2;      // 8 MB (dead after gemm1)
    uint16_t* Wb  = (uint16_t*)p;  p += (size_t)4096 * 1024 * 2;          // 8 MB (dead after gemm1)
    uint16_t* Wob = (uint16_t*)p;  p += (size_t)1024 * 2048 * 2;          // 4 MB  (W_out^T)
    float* xz     = (float*)p;     p += (size_t)NROWS * 4096 * 4;         // 64 MB
    float* xs     = (float*)p;     p += (size_t)NROWS * D_INNER * 4;      // 32 MB
    float* bcd    = (float*)p;     p += (size_t)NROWS * BCD_LD * 4;       // 576 KB
    float* sumdt  = (float*)p;     p += (size_t)NCHUNK * 4096 * 4;        // 512 KB
    float* Wxt    = (float*)p;     p += (size_t)64 * 2048 * 4;            // 512 KB
    uint16_t* ub  = (uint16_t*)p;  p += (size_t)NROWS * D_INNER * 2;      // 16 MB
    // overlays (regions dead during their use):
    float* hloc   = (float*)xb;    // 8 MB  (xb dead after gemm1)
    float* h0b    = (float*)Wb;    // 8 MB  (Wb dead after gemm1)
    float* part   = (float*)ub;    // 12.6 MB (ub written only by kscan3, later)
    float* dtb    = xz;            // dt at stride 4096 in xz's dead x_-half

    // 1) dtype prep
    kcvt<<<(NROWS * D_MODEL / 4 + 255) / 256, 256, 0, stream>>>(x, xb, NROWS * D_MODEL / 4);
    ktrans<<<dim3(4096 / 32, 1024 / 32), 256, 0, stream>>>(W_in, Wb, 1024, 4096);
    ktrans<<<dim3(1024 / 32, 2048 / 32), 256, 0, stream>>>(W_out, Wob, 2048, 1024);
    kwxt<<<(64 * 2048) / 256, 256, 0, stream>>>(W_x, Wxt);
    // 2) xz = x @ W_in   (M=4096, N=4096, K=1024)
    kgemm<1024><<<dim3(32, 32), 256, 0, stream>>>(xb, Wb, xz, 4096);
    // 3) conv + silu
    kconv<<<NROWS * D_INNER / 256, 256, 0, stream>>>(xz, conv_w, conv_b, xs);
    // 4) bcd = xs @ W_x  (MFMA, K-split 16 + reduce), then dt precompute
    kgemm2m<<<dim3(KS2, 32), 256, 0, stream>>>(xs, Wxt, part);
    kred2<<<(4096 * 48 + 255) / 256, 256, 0, stream>>>(part, bcd);
    kdt<<<(4096 * 512) / 256, 256, 0, stream>>>(bcd, w_dt, b_dt, dtb);
    // 5) selective scan (3 phases)
    kscan1<<<(4096 * 4 * NCHUNK) / 256, 256, 0, stream>>>(xs, bcd, dtb, A_log, hloc, sumdt);
    kscan2<<<(4096 * 16) / 256, 256, 0, stream>>>(hloc, sumdt, A_log, h0b);
    kscan3<<<(4096 * 4 * NCHUNK) / 256, 256, 0, stream>>>(xs, bcd, dtb, A_log, Dp, xz, h0b, ub);
    // 6) out = u @ W_out (M=4096, N=1024, K=2048)
    kgemm64<2048><<<dim3(1024 / 128, 4096 / 64), 256, 0, stream>>>(ub, Wob, out, 1024);
}

// Round 6
// 240.830 us; speedup vs baseline: 2.2306x; 1.0007x over previous
//
#include <hip/hip_runtime.h>
#include <hip/hip_bf16.h>
#include <stdint.h>

#define D_MODEL 1024
#define D_STATE 16
#define D_CONV  4
#define D_INNER 2048
#define BATCH   2
#define SEQLEN  2048
#define NROWS   (BATCH*SEQLEN)     // 4096
#define BCD_LD  36                 // padded leading dim for bcd (33 used)
#define NCHUNK  64
#define CHUNKLEN (SEQLEN/NCHUNK)   // 32
#define KS2     16                 // K-splits for GEMM2 (chunk = 128)
#define L2E 1.44269504088896340f

typedef __attribute__((ext_vector_type(8))) short   short8;
typedef __attribute__((ext_vector_type(4))) float   f32x4;

__device__ __forceinline__ uint16_t f2bf(float f) {        // RNE f32->bf16
    uint32_t u = __float_as_uint(f);
    return (uint16_t)((u + 0x7FFFu + ((u >> 16) & 1u)) >> 16);
}
__device__ __forceinline__ uint32_t pack2bf(float lo, float hi) {
    return (uint32_t)f2bf(lo) | ((uint32_t)f2bf(hi) << 16);
}
__device__ __forceinline__ void gload16(const uint16_t* g, uint16_t* l) {
    __builtin_amdgcn_global_load_lds(
        (const __attribute__((address_space(1))) void*)g,
        (__attribute__((address_space(3))) void*)l, 16, 0, 0);
}
__device__ __forceinline__ void gload16f(const float* g, float* l) {
    __builtin_amdgcn_global_load_lds(
        (const __attribute__((address_space(1))) void*)g,
        (__attribute__((address_space(3))) void*)l, 16, 0, 0);
}
__device__ __forceinline__ float softplus_f(float v) {
    return fmaxf(v, 0.f) + __logf(1.f + __expf(-fabsf(v)));
}
__device__ __forceinline__ float silu_f(float v) {
    return v / (1.f + __expf(-v));
}
__device__ __forceinline__ short8 pack8(const float4 lo, const float4 hi) {
    short8 r;
    r[0] = (short)f2bf(lo.x); r[1] = (short)f2bf(lo.y);
    r[2] = (short)f2bf(lo.z); r[3] = (short)f2bf(lo.w);
    r[4] = (short)f2bf(hi.x); r[5] = (short)f2bf(hi.y);
    r[6] = (short)f2bf(hi.z); r[7] = (short)f2bf(hi.w);
    return r;
}

// ---------- f32 -> bf16 elementwise (x) ----------
__global__ void kcvt(const float* __restrict__ in, uint16_t* __restrict__ out, int n4) {
    int T = blockIdx.x * 256 + threadIdx.x;
    if (T >= n4) return;
    const float4 v = *(const float4*)&in[(size_t)T * 4];
    ushort4 o;
    o.x = f2bf(v.x); o.y = f2bf(v.y); o.z = f2bf(v.z); o.w = f2bf(v.w);
    *(ushort4*)&out[(size_t)T * 4] = o;
}

// ---------- transpose+convert: in[Kd][Nd] f32 -> out[Nd][Kd] bf16 ----------
__global__ void ktrans(const float* __restrict__ in, uint16_t* __restrict__ out,
                       int Kd, int Nd) {
    __shared__ float tile[32][33];
    const int n0 = blockIdx.x * 32, k0 = blockIdx.y * 32;
    const int tx = threadIdx.x & 31, ty = threadIdx.x >> 5;   // ty 0..7
#pragma unroll
    for (int i = 0; i < 4; ++i)
        tile[ty + i * 8][tx] = in[(size_t)(k0 + ty + i * 8) * Nd + n0 + tx];
    __syncthreads();
#pragma unroll
    for (int i = 0; i < 4; ++i)
        out[(size_t)(n0 + ty + i * 8) * Kd + k0 + tx] = f2bf(tile[tx][ty + i * 8]);
}

// ---------- Wxt[64][2048] f32 = W_x^T zero-padded (33 -> 64 rows) ----------
__global__ void kwxt(const float* __restrict__ Wx, float* __restrict__ Wxt) {
    const int T = blockIdx.x * 256 + threadIdx.x;   // 64*2048
    const int j = T >> 11, k = T & 2047;
    Wxt[T] = (j < 33) ? Wx[(size_t)k * 33 + j] : 0.f;
}

// ---------- TN bf16 MFMA GEMM 128x128: C = A * B^T (XCD-swizzled grid) ----------
template<int KDIM, int GXL>
__global__ __launch_bounds__(256) void kgemm(const uint16_t* __restrict__ A,
                                             const uint16_t* __restrict__ B,
                                             float* __restrict__ C, const int ldc) {
    __shared__ uint16_t As[128 * 32];
    __shared__ uint16_t Bs[128 * 32];
    const int t = threadIdx.x;
    const int w = t >> 6, lane = t & 63;
    int wg = blockIdx.y * (1 << GXL) + blockIdx.x;
    wg = (wg & 7) * ((gridDim.x * gridDim.y) >> 3) + (wg >> 3);   // bijective XCD swizzle
    const int m0 = (wg >> GXL) * 128, n0 = (wg & ((1 << GXL) - 1)) * 128;
    const int wm = (w >> 1) * 64, wn = (w & 1) * 64;
    f32x4 acc[4][4] = {};

    const int srow = t >> 2;                              // 0..63
    const int scol = ((t & 3) ^ ((t >> 3) & 3)) * 8;      // pre-swizzled source slot
    const uint16_t* ga0 = A + (size_t)(m0 + srow) * KDIM + scol;
    const uint16_t* ga1 = A + (size_t)(m0 + 64 + srow) * KDIM + scol;
    const uint16_t* gb0 = B + (size_t)(n0 + srow) * KDIM + scol;
    const uint16_t* gb1 = B + (size_t)(n0 + 64 + srow) * KDIM + scol;
    uint16_t* lA0 = &As[w * 512];
    uint16_t* lA1 = &As[2048 + w * 512];
    uint16_t* lB0 = &Bs[w * 512];
    uint16_t* lB1 = &Bs[2048 + w * 512];

    const int fr = lane & 15, fg = (lane >> 4) * 8;
    const int psl = (((fg >> 3) ^ ((fr >> 1) & 3)) << 3); // swizzled read slot (elems)

    for (int kt = 0; kt < KDIM / 32; ++kt) {
        const int ko = kt * 32;
        gload16(ga0 + ko, lA0);
        gload16(ga1 + ko, lA1);
        gload16(gb0 + ko, lB0);
        gload16(gb1 + ko, lB1);
        __syncthreads();
        short8 a[4], b[4];
#pragma unroll
        for (int i = 0; i < 4; ++i) {
            a[i] = *(const short8*)&As[(wm + i * 16 + fr) * 32 + psl];
            b[i] = *(const short8*)&Bs[(wn + i * 16 + fr) * 32 + psl];
        }
#pragma unroll
        for (int i = 0; i < 4; ++i)
#pragma unroll
            for (int j = 0; j < 4; ++j)
                acc[i][j] = __builtin_amdgcn_mfma_f32_16x16x32_bf16(a[i], b[j], acc[i][j], 0, 0, 0);
        __syncthreads();
    }
    const int cr = (lane >> 4) * 4, cc = lane & 15;
#pragma unroll
    for (int i = 0; i < 4; ++i)
#pragma unroll
        for (int j = 0; j < 4; ++j)
#pragma unroll
            for (int r = 0; r < 4; ++r)
                C[(size_t)(m0 + wm + i * 16 + cr + r) * ldc + (n0 + wn + j * 16 + cc)] = acc[i][j][r];
}

// ---------- TN bf16 MFMA GEMM 64x128 (GEMM3), XCD-swizzled ----------
template<int KDIM, int GXL>
__global__ __launch_bounds__(256) void kgemm64(const uint16_t* __restrict__ A,
                                               const uint16_t* __restrict__ B,
                                               float* __restrict__ C, const int ldc) {
    __shared__ uint16_t As[64 * 32];     // 4 KB
    __shared__ uint16_t Bs[128 * 32];    // 8 KB
    const int t = threadIdx.x;
    const int w = t >> 6, lane = t & 63;
    int wg = blockIdx.y * (1 << GXL) + blockIdx.x;
    wg = (wg & 7) * ((gridDim.x * gridDim.y) >> 3) + (wg >> 3);
    const int m0 = (wg >> GXL) * 64, n0 = (wg & ((1 << GXL) - 1)) * 128;
    const int wm = (w >> 1) * 32, wn = (w & 1) * 64;
    f32x4 acc[2][4] = {};

    const int srow = t >> 2;
    const int scol = ((t & 3) ^ ((t >> 3) & 3)) * 8;
    const uint16_t* ga0 = A + (size_t)(m0 + srow) * KDIM + scol;
    const uint16_t* gb0 = B + (size_t)(n0 + srow) * KDIM + scol;
    const uint16_t* gb1 = B + (size_t)(n0 + 64 + srow) * KDIM + scol;
    uint16_t* lA0 = &As[w * 512];
    uint16_t* lB0 = &Bs[w * 512];
    uint16_t* lB1 = &Bs[2048 + w * 512];

    const int fr = lane & 15, fg = (lane >> 4) * 8;
    const int psl = (((fg >> 3) ^ ((fr >> 1) & 3)) << 3);

    for (int kt = 0; kt < KDIM / 32; ++kt) {
        const int ko = kt * 32;
        gload16(ga0 + ko, lA0);
        gload16(gb0 + ko, lB0);
        gload16(gb1 + ko, lB1);
        __syncthreads();
        short8 a[2], b[4];
#pragma unroll
        for (int i = 0; i < 2; ++i)
            a[i] = *(const short8*)&As[(wm + i * 16 + fr) * 32 + psl];
#pragma unroll
        for (int j = 0; j < 4; ++j)
            b[j] = *(const short8*)&Bs[(wn + j * 16 + fr) * 32 + psl];
#pragma unroll
        for (int i = 0; i < 2; ++i)
#pragma unroll
            for (int j = 0; j < 4; ++j)
                acc[i][j] = __builtin_amdgcn_mfma_f32_16x16x32_bf16(a[i], b[j], acc[i][j], 0, 0, 0);
        __syncthreads();
    }
    const int cr = (lane >> 4) * 4, cc = lane & 15;
#pragma unroll
    for (int i = 0; i < 2; ++i)
#pragma unroll
        for (int j = 0; j < 4; ++j)
#pragma unroll
            for (int r = 0; r < 4; ++r)
                C[(size_t)(m0 + wm + i * 16 + cr + r) * ldc + (n0 + wn + j * 16 + cc)] = acc[i][j][r];
}

// ---------- GEMM2 MFMA K-split: part[kb][4096][48] = xs(chunk) @ Wxt^T ----------
__global__ __launch_bounds__(256) void kgemm2m(const float* __restrict__ xs,
        const float* __restrict__ Wxt, float* __restrict__ part) {
    __shared__ float As[128 * 32];   // 16 KB
    __shared__ float Bs[64 * 32];    // 8 KB
    const int t = threadIdx.x;
    const int w = t >> 6, lane = t & 63;
    const int kb = blockIdx.x;              // 0..15
    const int m0 = blockIdx.y * 128;
    const int kc = kb * 128;
    f32x4 acc[2][3] = {};

    const int srow = t >> 3;                            // 0..31
    const int scol = ((t & 7) ^ ((t >> 3) & 7)) * 4;    // pre-swizzled source (floats)
    float* lA[4]; float* lB[2];
#pragma unroll
    for (int r = 0; r < 4; ++r) lA[r] = &As[(r * 32 + w * 8) * 32];
#pragma unroll
    for (int r = 0; r < 2; ++r) lB[r] = &Bs[(r * 32 + w * 8) * 32];

    const int wm = w * 32;
    const int fr = lane & 15, fg = (lane >> 4) * 8;
    const int plo = (((fg >> 2) ^ (fr & 7))) * 4;
    const int phi = ((((fg >> 2) + 1) ^ (fr & 7))) * 4;

    for (int kt = 0; kt < 4; ++kt) {
        const int ko = kc + kt * 32;
#pragma unroll
        for (int r = 0; r < 4; ++r)
            gload16f(xs + (size_t)(m0 + r * 32 + srow) * 2048 + ko + scol, lA[r]);
#pragma unroll
        for (int r = 0; r < 2; ++r)
            gload16f(Wxt + (size_t)(r * 32 + srow) * 2048 + ko + scol, lB[r]);
        __syncthreads();
        short8 a[2], b[3];
#pragma unroll
        for (int i = 0; i < 2; ++i) {
            const float* base = &As[(wm + i * 16 + fr) * 32];
            a[i] = pack8(*(const float4*)&base[plo], *(const float4*)&base[phi]);
        }
#pragma unroll
        for (int j = 0; j < 3; ++j) {
            const float* base = &Bs[(j * 16 + fr) * 32];
            b[j] = pack8(*(const float4*)&base[plo], *(const float4*)&base[phi]);
        }
#pragma unroll
        for (int i = 0; i < 2; ++i)
#pragma unroll
            for (int j = 0; j < 3; ++j)
                acc[i][j] = __builtin_amdgcn_mfma_f32_16x16x32_bf16(a[i], b[j], acc[i][j], 0, 0, 0);
        __syncthreads();
    }
    const int cr = (lane >> 4) * 4, cc = lane & 15;
    float* pb = part + (size_t)kb * 4096 * 48;
#pragma unroll
    for (int i = 0; i < 2; ++i)
#pragma unroll
        for (int j = 0; j < 3; ++j)
#pragma unroll
            for (int r = 0; r < 4; ++r)
                pb[(size_t)(m0 + wm + i * 16 + cr + r) * 48 + j * 16 + cc] = acc[i][j][r];
}

// ---------- reduce K-split partials -> bcd ----------
__global__ void kred2(const float* __restrict__ part, float* __restrict__ bcd) {
    const int T = blockIdx.x * 256 + threadIdx.x;   // 4096*48
    if (T >= 4096 * 48) return;
    const int row = T / 48, j = T - row * 48;
    if (j >= 33) return;
    float s = 0.f;
#pragma unroll
    for (int ks = 0; ks < KS2; ++ks) s += part[(size_t)ks * 4096 * 48 + T];
    bcd[(size_t)row * BCD_LD + j] = s;
}

// ---------- prep: pack (dt, dt*x) and (silu(z), x*Dp*silu(z)) as bf16 pairs ----------
// dtdx written into xz's dead x_-half; szw written IN-PLACE over the z-half.
__global__ void kprep(const float* __restrict__ bcd, const float* __restrict__ wdt,
                      const float* __restrict__ bdt, const float* __restrict__ Dp,
                      const float* __restrict__ xs, float* __restrict__ xz) {
    const int T = blockIdx.x * 256 + threadIdx.x;   // 4096 rows * 512 groups
    const int row = T >> 9, dg = (T & 511) * 4;
    const float raw = bcd[(size_t)row * BCD_LD + 32];
    const float4 w  = *(const float4*)&wdt[dg];
    const float4 b  = *(const float4*)&bdt[dg];
    const float4 Dv = *(const float4*)&Dp[dg];
    const float4 xv = *(const float4*)&xs[(size_t)row * D_INNER + dg];
    const float4 zv = *(const float4*)&xz[(size_t)row * 4096 + 2048 + dg];
    const float dt0 = softplus_f(raw * w.x + b.x);
    const float dt1 = softplus_f(raw * w.y + b.y);
    const float dt2 = softplus_f(raw * w.z + b.z);
    const float dt3 = softplus_f(raw * w.w + b.w);
    uint4 pd, ps;
    pd.x = pack2bf(dt0, dt0 * xv.x);
    pd.y = pack2bf(dt1, dt1 * xv.y);
    pd.z = pack2bf(dt2, dt2 * xv.z);
    pd.w = pack2bf(dt3, dt3 * xv.w);
    const float s0 = silu_f(zv.x), s1 = silu_f(zv.y), s2 = silu_f(zv.z), s3 = silu_f(zv.w);
    ps.x = pack2bf(s0, xv.x * Dv.x * s0);
    ps.y = pack2bf(s1, xv.y * Dv.y * s1);
    ps.z = pack2bf(s2, xv.z * Dv.z * s2);
    ps.w = pack2bf(s3, xv.w * Dv.w * s3);
    uint32_t* xzu = (uint32_t*)xz;
    *(uint4*)&xzu[(size_t)row * 4096 + dg] = pd;          // dtdx (x_-half, dead)
    *(uint4*)&xzu[(size_t)row * 4096 + 2048 + dg] = ps;   // szw (in-place over z)
}

// ---------- scan phase 1: 2 lanes/channel (8 states each), chunklen 32 ----------
__global__ __launch_bounds__(256) void kscan1(const uint32_t* __restrict__ dtdx,
        const float* __restrict__ bcd, const float* __restrict__ Alog,
        float* __restrict__ hbuf, float* __restrict__ sumdt) {
    const int T = blockIdx.x * 256 + threadIdx.x;
    const int sub = T & 1;                 // states sub*8 .. sub*8+7
    const int ch  = (T >> 1) & 4095;
    const int chunk = T >> 13;
    const int b = ch >> 11, d = ch & 2047;
    float Ae[8]; bool st = true;
#pragma unroll
    for (int i = 0; i < 8; ++i) {
        const float a = __expf(Alog[d * 16 + sub * 8 + i]);
        Ae[i] = -a * L2E;
        st = st && (fabsf(a - (float)(sub * 8 + i + 1)) < 1e-3f);
    }
    float h[8] = {};
    float sdt = 0.f;
    const int row0 = b * SEQLEN + chunk * CHUNKLEN;
    const uint32_t* pD = dtdx + (size_t)row0 * 4096 + d;
    const float* pB = bcd + (size_t)row0 * BCD_LD + sub * 8;
    if (st) {
        for (int l0 = 0; l0 < CHUNKLEN; l0 += 2) {
            uint32_t pk[2]; float4 B0[2], B1[2];
#pragma unroll
            for (int s = 0; s < 2; ++s) {
                pk[s] = pD[(size_t)s * 4096];
                B0[s] = *(const float4*)(pB + s * BCD_LD);
                B1[s] = *(const float4*)(pB + s * BCD_LD + 4);
            }
#pragma unroll
            for (int s = 0; s < 2; ++s) {
                const float dt  = __uint_as_float(pk[s] << 16);
                const float dtx = __uint_as_float(pk[s] & 0xffff0000u);
                sdt += dt;
                const float e0 = __builtin_amdgcn_exp2f(dt * (-L2E));
                const float e2 = e0 * e0, e4 = e2 * e2, e8 = e4 * e4;
                float dec = sub ? e8 : 1.f;
                dec *= e0; h[0] = fmaf(dec, h[0], dtx * B0[s].x);
                dec *= e0; h[1] = fmaf(dec, h[1], dtx * B0[s].y);
                dec *= e0; h[2] = fmaf(dec, h[2], dtx * B0[s].z);
                dec *= e0; h[3] = fmaf(dec, h[3], dtx * B0[s].w);
                dec *= e0; h[4] = fmaf(dec, h[4], dtx * B1[s].x);
                dec *= e0; h[5] = fmaf(dec, h[5], dtx * B1[s].y);
                dec *= e0; h[6] = fmaf(dec, h[6], dtx * B1[s].z);
                dec *= e0; h[7] = fmaf(dec, h[7], dtx * B1[s].w);
            }
            pD += 2 * 4096; pB += 2 * BCD_LD;
        }
    } else {
        for (int l0 = 0; l0 < CHUNKLEN; l0 += 2) {
            uint32_t pk[2]; float4 B0[2], B1[2];
#pragma unroll
            for (int s = 0; s < 2; ++s) {
                pk[s] = pD[(size_t)s * 4096];
                B0[s] = *(const float4*)(pB + s * BCD_LD);
                B1[s] = *(const float4*)(pB + s * BCD_LD + 4);
            }
#pragma unroll
            for (int s = 0; s < 2; ++s) {
                const float dt  = __uint_as_float(pk[s] << 16);
                const float dtx = __uint_as_float(pk[s] & 0xffff0000u);
                sdt += dt;
                h[0] = fmaf(__builtin_amdgcn_exp2f(dt * Ae[0]), h[0], dtx * B0[s].x);
                h[1] = fmaf(__builtin_amdgcn_exp2f(dt * Ae[1]), h[1], dtx * B0[s].y);
                h[2] = fmaf(__builtin_amdgcn_exp2f(dt * Ae[2]), h[2], dtx * B0[s].z);
                h[3] = fmaf(__builtin_amdgcn_exp2f(dt * Ae[3]), h[3], dtx * B0[s].w);
                h[4] = fmaf(__builtin_amdgcn_exp2f(dt * Ae[4]), h[4], dtx * B1[s].x);
                h[5] = fmaf(__builtin_amdgcn_exp2f(dt * Ae[5]), h[5], dtx * B1[s].y);
                h[6] = fmaf(__builtin_amdgcn_exp2f(dt * Ae[6]), h[6], dtx * B1[s].z);
                h[7] = fmaf(__builtin_amdgcn_exp2f(dt * Ae[7]), h[7], dtx * B1[s].w);
            }
            pD += 2 * 4096; pB += 2 * BCD_LD;
        }
    }
    const size_t cc = (size_t)(chunk * 4096 + ch) * 16 + sub * 8;
    *(float4*)&hbuf[cc]     = make_float4(h[0], h[1], h[2], h[3]);
    *(float4*)&hbuf[cc + 4] = make_float4(h[4], h[5], h[6], h[7]);
    if (sub == 0) sumdt[chunk * 4096 + ch] = sdt;
}

// ---------- scan phase 2: chunk combine, carries written IN-PLACE over hbuf ----------
__global__ void kscan2(float* __restrict__ hbuf, const float* __restrict__ sumdt,
                       const float* __restrict__ Alog) {
    const int T = blockIdx.x * 256 + threadIdx.x;   // 65536
    const int n = T & 15, ch = T >> 4;
    const int d = ch & 2047;
    const float Ae = -__expf(Alog[d * 16 + n]) * L2E;
    float h = 0.f;
    for (int c = 0; c < NCHUNK; ++c) {
        const size_t idx = (size_t)(c * 4096 + ch) * 16 + n;
        const float loc = hbuf[idx];
        hbuf[idx] = h;                     // carry (h at chunk start)
        h = __builtin_amdgcn_exp2f(Ae * sumdt[c * 4096 + ch]) * h + loc;
    }
}

// ---------- scan phase 3: replay with carry, u = y*sz + w2 (bf16) ----------
__global__ __launch_bounds__(256) void kscan3(const uint32_t* __restrict__ dtdx,
        const float* __restrict__ bcd, const float* __restrict__ Alog,
        const uint32_t* __restrict__ szw, const float* __restrict__ hbuf,
        uint16_t* __restrict__ u) {
    const int T = blockIdx.x * 256 + threadIdx.x;
    const int sub = T & 1;
    const int ch  = (T >> 1) & 4095;
    const int chunk = T >> 13;
    const int b = ch >> 11, d = ch & 2047;
    float Ae[8]; bool st = true;
#pragma unroll
    for (int i = 0; i < 8; ++i) {
        const float a = __expf(Alog[d * 16 + sub * 8 + i]);
        Ae[i] = -a * L2E;
        st = st && (fabsf(a - (float)(sub * 8 + i + 1)) < 1e-3f);
    }
    float h[8];
    {
        const size_t cc = (size_t)(chunk * 4096 + ch) * 16 + sub * 8;
        const float4 h0 = *(const float4*)&hbuf[cc];
        const float4 h1 = *(const float4*)&hbuf[cc + 4];
        h[0] = h0.x; h[1] = h0.y; h[2] = h0.z; h[3] = h0.w;
        h[4] = h1.x; h[5] = h1.y; h[6] = h1.z; h[7] = h1.w;
    }
    const int row0 = b * SEQLEN + chunk * CHUNKLEN;
    const uint32_t* pD = dtdx + (size_t)row0 * 4096 + d;
    const uint32_t* pS = szw  + (size_t)row0 * 4096 + d;   // szw already offset to z-half
    const float* pB = bcd + (size_t)row0 * BCD_LD + sub * 8;
    uint16_t* pU = u + (size_t)row0 * D_INNER + d;
    if (st) {
        for (int l0 = 0; l0 < CHUNKLEN; l0 += 2) {
            uint32_t pk[2], qk[2]; float4 B0[2], B1[2], C0[2], C1[2];
#pragma unroll
            for (int s = 0; s < 2; ++s) {
                pk[s] = pD[(size_t)s * 4096];
                B0[s] = *(const float4*)(pB + s * BCD_LD);
                B1[s] = *(const float4*)(pB + s * BCD_LD + 4);
                C0[s] = *(const float4*)(pB + s * BCD_LD + 16);
                C1[s] = *(const float4*)(pB + s * BCD_LD + 20);
                if (sub == 0) qk[s] = pS[(size_t)s * 4096];
            }
#pragma unroll
            for (int s = 0; s < 2; ++s) {
                const float dt  = __uint_as_float(pk[s] << 16);
                const float dtx = __uint_as_float(pk[s] & 0xffff0000u);
                const float e0 = __builtin_amdgcn_exp2f(dt * (-L2E));
                const float e2 = e0 * e0, e4 = e2 * e2, e8 = e4 * e4;
                float dec = sub ? e8 : 1.f;
                dec *= e0; h[0] = fmaf(dec, h[0], dtx * B0[s].x);
                dec *= e0; h[1] = fmaf(dec, h[1], dtx * B0[s].y);
                dec *= e0; h[2] = fmaf(dec, h[2], dtx * B0[s].z);
                dec *= e0; h[3] = fmaf(dec, h[3], dtx * B0[s].w);
                dec *= e0; h[4] = fmaf(dec, h[4], dtx * B1[s].x);
                dec *= e0; h[5] = fmaf(dec, h[5], dtx * B1[s].y);
                dec *= e0; h[6] = fmaf(dec, h[6], dtx * B1[s].z);
                dec *= e0; h[7] = fmaf(dec, h[7], dtx * B1[s].w);
                float y = h[0] * C0[s].x + h[1] * C0[s].y + h[2] * C0[s].z + h[3] * C0[s].w
                        + h[4] * C1[s].x + h[5] * C1[s].y + h[6] * C1[s].z + h[7] * C1[s].w;
                y += __shfl_xor(y, 1);
                if (sub == 0) {
                    const float sz = __uint_as_float(qk[s] << 16);
                    const float w2 = __uint_as_float(qk[s] & 0xffff0000u);
                    pU[(size_t)s * D_INNER] = f2bf(fmaf(y, sz, w2));
                }
            }
            pD += 2 * 4096; pS += 2 * 4096; pB += 2 * BCD_LD; pU += 2 * D_INNER;
        }
    } else {
        for (int l0 = 0; l0 < CHUNKLEN; l0 += 2) {
            uint32_t pk[2], qk[2]; float4 B0[2], B1[2], C0[2], C1[2];
#pragma unroll
            for (int s = 0; s < 2; ++s) {
                pk[s] = pD[(size_t)s * 4096];
                B0[s] = *(const float4*)(pB + s * BCD_LD);
                B1[s] = *(const float4*)(pB + s * BCD_LD + 4);
                C0[s] = *(const float4*)(pB + s * BCD_LD + 16);
                C1[s] = *(const float4*)(pB + s * BCD_LD + 20);
                if (sub == 0) qk[s] = pS[(size_t)s * 4096];
            }
#pragma unroll
            for (int s = 0; s < 2; ++s) {
                const float dt  = __uint_as_float(pk[s] << 16);
                const float dtx = __uint_as_float(pk[s] & 0xffff0000u);
                h[0] = fmaf(__builtin_amdgcn_exp2f(dt * Ae[0]), h[0], dtx * B0[s].x);
                h[1] = fmaf(__builtin_amdgcn_exp2f(dt * Ae[1]), h[1], dtx * B0[s].y);
                h[2] = fmaf(__builtin_amdgcn_exp2f(dt * Ae[2]), h[2], dtx * B0[s].z);
                h[3] = fmaf(__builtin_amdgcn_exp2f(dt * Ae[3]), h[3], dtx * B0[s].w);
                h[4] = fmaf(__builtin_amdgcn_exp2f(dt * Ae[4]), h[4], dtx * B1[s].x);
                h[5] = fmaf(__builtin_amdgcn_exp2f(dt * Ae[5]), h[5], dtx * B1[s].y);
                h[6] = fmaf(__builtin_amdgcn_exp2f(dt * Ae[6]), h[6], dtx * B1[s].z);
                h[7] = fmaf(__builtin_amdgcn_exp2f(dt * Ae[7]), h[7], dtx * B1[s].w);
                float y = h[0] * C0[s].x + h[1] * C0[s].y + h[2] * C0[s].z + h[3] * C0[s].w
                        + h[4] * C1[s].x + h[5] * C1[s].y + h[6] * C1[s].z + h[7] * C1[s].w;
                y += __shfl_xor(y, 1);
                if (sub == 0) {
                    const float sz = __uint_as_float(qk[s] << 16);
                    const float w2 = __uint_as_float(qk[s] & 0xffff0000u);
                    pU[(size_t)s * D_INNER] = f2bf(fmaf(y, sz, w2));
                }
            }
            pD += 2 * 4096; pS += 2 * 4096; pB += 2 * BCD_LD; pU += 2 * D_INNER;
        }
    }
}

// ---------- causal depthwise conv (k=4) + bias + SiLU ----------
__global__ void kconv(const float* __restrict__ xz, const float* __restrict__ cw,
                      const float* __restrict__ cb, float* __restrict__ xs) {
    size_t T = (size_t)blockIdx.x * 256 + threadIdx.x;   // over NROWS*D_INNER
    int d = (int)(T & (D_INNER - 1));
    int row = (int)(T >> 11);
    int l = row & (SEQLEN - 1), b = row >> 11;
    const float4 w4 = *(const float4*)&cw[d * 4];
    float acc = cb[d];
    const size_t base = (size_t)b * SEQLEN;
    if (l >= 3) {
        acc += w4.x * xz[(base + l - 3) * 4096 + d];
        acc += w4.y * xz[(base + l - 2) * 4096 + d];
        acc += w4.z * xz[(base + l - 1) * 4096 + d];
        acc += w4.w * xz[(base + l    ) * 4096 + d];
    } else {
        if (l >= 2) acc += w4.y * xz[(base + l - 2) * 4096 + d];
        if (l >= 1) acc += w4.z * xz[(base + l - 1) * 4096 + d];
        acc += w4.w * xz[(base + l) * 4096 + d];
    }
    xs[T] = silu_f(acc);
}

extern "C" void kernel_launch(void* const* d_in, const int* in_sizes, int n_in,
                              void* d_out, int out_size, void* d_ws, size_t ws_size,
                              hipStream_t stream) {
    const float* x      = (const float*)d_in[0];
    const float* W_in   = (const float*)d_in[1];
    const float* conv_w = (const float*)d_in[2];
    const float* conv_b = (const float*)d_in[3];
    const float* W_x    = (const float*)d_in[4];
    const float* w_dt   = (const float*)d_in[5];
    const float* b_dt   = (const float*)d_in[6];
    const float* A_log  = (const float*)d_in[7];
    const float* Dp     = (const float*)d_in[8];
    const float* W_out  = (const float*)d_in[9];
    float* out = (float*)d_out;

    char* p = (char*)d_ws;
    uint16_t* xb  = (uint16_t*)p;  p += (size_t)NROWS * D_MODEL * 2;      // 8 MB (dead after gemm1)
    uint16_t* Wb  = (uint16_t*)p;  p += (size_t)4096 * 1024 * 2;          // 8 MB (dead after gemm1)
    uint16_t* Wob = (uint16_t*)p;  p += (size_t)1024 * 2048 * 2;          // 4 MB  (W_out^T)
    float* xz     = (float*)p;     p += (size_t)NROWS * 4096 * 4;         // 64 MB
    float* xs     = (float*)p;     p += (size_t)NROWS * D_INNER * 4;      // 32 MB
    float* bcd    = (float*)p;     p += (size_t)NROWS * BCD_LD * 4;       // 576 KB
    float* sumdt  = (float*)p;     p += (size_t)NCHUNK * 4096 * 4;        // 1 MB
    float* Wxt    = (float*)p;     p += (size_t)64 * 2048 * 4;            // 512 KB
    uint16_t* ub  = (uint16_t*)p;  p += (size_t)NROWS * D_INNER * 2;      // 16 MB
    // overlays (regions dead during their use):
    float* hbuf   = (float*)xb;        // 16 MB = xb+Wb (dead after gemm1); hloc then in-place carries
    float* part   = (float*)ub;        // 12.6 MB (ub written only by kscan3, later)
    uint32_t* dtdx = (uint32_t*)xz;            // packed (dt, dt*x) in x_-half
    uint32_t* szw  = (uint32_t*)xz + 2048;     // packed (sz, w2) in z-half  [R5 BUGFIX: +2048]

    // 1) dtype prep
    kcvt<<<(NROWS * D_MODEL / 4 + 255) / 256, 256, 0, stream>>>(x, xb, NROWS * D_MODEL / 4);
    ktrans<<<dim3(4096 / 32, 1024 / 32), 256, 0, stream>>>(W_in, Wb, 1024, 4096);
    ktrans<<<dim3(1024 / 32, 2048 / 32), 256, 0, stream>>>(W_out, Wob, 2048, 1024);
    kwxt<<<(64 * 2048) / 256, 256, 0, stream>>>(W_x, Wxt);
    // 2) xz = x @ W_in   (M=4096, N=4096, K=1024)
    kgemm<1024, 5><<<dim3(32, 32), 256, 0, stream>>>(xb, Wb, xz, 4096);
    // 3) conv + silu
    kconv<<<NROWS * D_INNER / 256, 256, 0, stream>>>(xz, conv_w, conv_b, xs);
    // 4) bcd = xs @ W_x  (MFMA, K-split 16 + reduce)
    kgemm2m<<<dim3(KS2, 32), 256, 0, stream>>>(xs, Wxt, part);
    kred2<<<(4096 * 48 + 255) / 256, 256, 0, stream>>>(part, bcd);
    // 5) pack scan operands (dtdx into x_-half, szw in-place over z-half)
    kprep<<<(4096 * 512) / 256, 256, 0, stream>>>(bcd, w_dt, b_dt, Dp, xs, xz);
    // 6) selective scan (3 phases)
    kscan1<<<(4096 * 2 * NCHUNK) / 256, 256, 0, stream>>>(dtdx, bcd, A_log, hbuf, sumdt);
    kscan2<<<(4096 * 16) / 256, 256, 0, stream>>>(hbuf, sumdt, A_log);
    kscan3<<<(4096 * 2 * NCHUNK) / 256, 256, 0, stream>>>(dtdx, bcd, A_log, szw, hbuf, ub);
    // 7) out = u @ W_out (M=4096, N=1024, K=2048)
    kgemm64<2048, 3><<<dim3(1024 / 128, 4096 / 64), 256, 0, stream>>>(ub, Wob, out, 1024);
}

// Round 7
// 223.368 us; speedup vs baseline: 2.4049x; 1.0782x over previous
//
#include <hip/hip_runtime.h>
#include <hip/hip_bf16.h>
#include <stdint.h>

#define D_MODEL 1024
#define D_STATE 16
#define D_CONV  4
#define D_INNER 2048
#define BATCH   2
#define SEQLEN  2048
#define NROWS   (BATCH*SEQLEN)     // 4096
#define BCD_LD  36                 // padded leading dim for bcd (33 used)
#define NCHUNK  64
#define CHUNKLEN (SEQLEN/NCHUNK)   // 32
#define KS2     16                 // K-splits for GEMM2 (chunk = 128)
#define L2E 1.44269504088896340f

typedef __attribute__((ext_vector_type(8))) short   short8;
typedef __attribute__((ext_vector_type(4))) float   f32x4;

__device__ __forceinline__ uint16_t f2bf(float f) {        // RNE f32->bf16
    uint32_t u = __float_as_uint(f);
    return (uint16_t)((u + 0x7FFFu + ((u >> 16) & 1u)) >> 16);
}
__device__ __forceinline__ float bf2f(uint16_t h) {
    return __uint_as_float(((uint32_t)h) << 16);
}
__device__ __forceinline__ uint32_t pack2bf(float lo, float hi) {
    return (uint32_t)f2bf(lo) | ((uint32_t)f2bf(hi) << 16);
}
__device__ __forceinline__ void gload16(const uint16_t* g, uint16_t* l) {
    __builtin_amdgcn_global_load_lds(
        (const __attribute__((address_space(1))) void*)g,
        (__attribute__((address_space(3))) void*)l, 16, 0, 0);
}
__device__ __forceinline__ void gload16f(const float* g, float* l) {
    __builtin_amdgcn_global_load_lds(
        (const __attribute__((address_space(1))) void*)g,
        (__attribute__((address_space(3))) void*)l, 16, 0, 0);
}
__device__ __forceinline__ float softplus_f(float v) {
    return fmaxf(v, 0.f) + __logf(1.f + __expf(-fabsf(v)));
}
__device__ __forceinline__ float silu_f(float v) {
    return v / (1.f + __expf(-v));
}
__device__ __forceinline__ short8 pack8(const float4 lo, const float4 hi) {
    short8 r;
    r[0] = (short)f2bf(lo.x); r[1] = (short)f2bf(lo.y);
    r[2] = (short)f2bf(lo.z); r[3] = (short)f2bf(lo.w);
    r[4] = (short)f2bf(hi.x); r[5] = (short)f2bf(hi.y);
    r[6] = (short)f2bf(hi.z); r[7] = (short)f2bf(hi.w);
    return r;
}

// ---------- f32 -> bf16 elementwise (x) ----------
__global__ void kcvt(const float* __restrict__ in, uint16_t* __restrict__ out, int n4) {
    int T = blockIdx.x * 256 + threadIdx.x;
    if (T >= n4) return;
    const float4 v = *(const float4*)&in[(size_t)T * 4];
    ushort4 o;
    o.x = f2bf(v.x); o.y = f2bf(v.y); o.z = f2bf(v.z); o.w = f2bf(v.w);
    *(ushort4*)&out[(size_t)T * 4] = o;
}

// ---------- transpose+convert: in[Kd][Nd] f32 -> out[Nd][Kd] bf16 ----------
__global__ void ktrans(const float* __restrict__ in, uint16_t* __restrict__ out,
                       int Kd, int Nd) {
    __shared__ float tile[32][33];
    const int n0 = blockIdx.x * 32, k0 = blockIdx.y * 32;
    const int tx = threadIdx.x & 31, ty = threadIdx.x >> 5;   // ty 0..7
#pragma unroll
    for (int i = 0; i < 4; ++i)
        tile[ty + i * 8][tx] = in[(size_t)(k0 + ty + i * 8) * Nd + n0 + tx];
    __syncthreads();
#pragma unroll
    for (int i = 0; i < 4; ++i)
        out[(size_t)(n0 + ty + i * 8) * Kd + k0 + tx] = f2bf(tile[tx][ty + i * 8]);
}

// ---------- Wxt[64][2048] f32 = W_x^T zero-padded (33 -> 64 rows) ----------
__global__ void kwxt(const float* __restrict__ Wx, float* __restrict__ Wxt) {
    const int T = blockIdx.x * 256 + threadIdx.x;   // 64*2048
    const int j = T >> 11, k = T & 2047;
    Wxt[T] = (j < 33) ? Wx[(size_t)k * 33 + j] : 0.f;
}

// ---------- GEMM1: 256x128 tile, 512 thr, bf16 C out (XCD-swizzled) ----------
template<int KDIM, int GXL>
__global__ __launch_bounds__(512) void kgemm256(const uint16_t* __restrict__ A,
                                                const uint16_t* __restrict__ B,
                                                uint16_t* __restrict__ C, const int ldc) {
    __shared__ uint16_t As[256 * 32];   // 16 KB
    __shared__ uint16_t Bs[128 * 32];   // 8 KB
    const int t = threadIdx.x;          // 0..511
    const int w = t >> 6, lane = t & 63;
    int wg = blockIdx.y * (1 << GXL) + blockIdx.x;
    wg = (wg & 7) * ((gridDim.x * gridDim.y) >> 3) + (wg >> 3);   // bijective XCD swizzle
    const int m0 = (wg >> GXL) * 256, n0 = (wg & ((1 << GXL) - 1)) * 128;
    const int wm = (w >> 1) * 64, wn = (w & 1) * 64;
    f32x4 acc[4][4] = {};

    const int srow = t >> 2;                              // 0..127
    const int scol = ((t & 3) ^ ((t >> 3) & 3)) * 8;      // pre-swizzled source slot
    const uint16_t* ga0 = A + (size_t)(m0 + srow) * KDIM + scol;
    const uint16_t* ga1 = A + (size_t)(m0 + 128 + srow) * KDIM + scol;
    const uint16_t* gb0 = B + (size_t)(n0 + srow) * KDIM + scol;
    uint16_t* lA0 = &As[w * 512];
    uint16_t* lA1 = &As[4096 + w * 512];
    uint16_t* lB0 = &Bs[w * 512];

    const int fr = lane & 15, fg = (lane >> 4) * 8;
    const int psl = (((fg >> 3) ^ ((fr >> 1) & 3)) << 3);

    for (int kt = 0; kt < KDIM / 32; ++kt) {
        const int ko = kt * 32;
        gload16(ga0 + ko, lA0);
        gload16(ga1 + ko, lA1);
        gload16(gb0 + ko, lB0);
        __syncthreads();
        short8 a[4], b[4];
#pragma unroll
        for (int i = 0; i < 4; ++i) {
            a[i] = *(const short8*)&As[(wm + i * 16 + fr) * 32 + psl];
            b[i] = *(const short8*)&Bs[(wn + i * 16 + fr) * 32 + psl];
        }
#pragma unroll
        for (int i = 0; i < 4; ++i)
#pragma unroll
            for (int j = 0; j < 4; ++j)
                acc[i][j] = __builtin_amdgcn_mfma_f32_16x16x32_bf16(a[i], b[j], acc[i][j], 0, 0, 0);
        __syncthreads();
    }
    const int cr = (lane >> 4) * 4, cc = lane & 15;
#pragma unroll
    for (int i = 0; i < 4; ++i)
#pragma unroll
        for (int j = 0; j < 4; ++j)
#pragma unroll
            for (int r = 0; r < 4; ++r)
                C[(size_t)(m0 + wm + i * 16 + cr + r) * ldc + (n0 + wn + j * 16 + cc)] =
                    f2bf(acc[i][j][r]);
}

// ---------- TN bf16 MFMA GEMM 64x128 (GEMM3, f32 C), XCD-swizzled ----------
template<int KDIM, int GXL>
__global__ __launch_bounds__(256) void kgemm64(const uint16_t* __restrict__ A,
                                               const uint16_t* __restrict__ B,
                                               float* __restrict__ C, const int ldc) {
    __shared__ uint16_t As[64 * 32];     // 4 KB
    __shared__ uint16_t Bs[128 * 32];    // 8 KB
    const int t = threadIdx.x;
    const int w = t >> 6, lane = t & 63;
    int wg = blockIdx.y * (1 << GXL) + blockIdx.x;
    wg = (wg & 7) * ((gridDim.x * gridDim.y) >> 3) + (wg >> 3);
    const int m0 = (wg >> GXL) * 64, n0 = (wg & ((1 << GXL) - 1)) * 128;
    const int wm = (w >> 1) * 32, wn = (w & 1) * 64;
    f32x4 acc[2][4] = {};

    const int srow = t >> 2;
    const int scol = ((t & 3) ^ ((t >> 3) & 3)) * 8;
    const uint16_t* ga0 = A + (size_t)(m0 + srow) * KDIM + scol;
    const uint16_t* gb0 = B + (size_t)(n0 + srow) * KDIM + scol;
    const uint16_t* gb1 = B + (size_t)(n0 + 64 + srow) * KDIM + scol;
    uint16_t* lA0 = &As[w * 512];
    uint16_t* lB0 = &Bs[w * 512];
    uint16_t* lB1 = &Bs[2048 + w * 512];

    const int fr = lane & 15, fg = (lane >> 4) * 8;
    const int psl = (((fg >> 3) ^ ((fr >> 1) & 3)) << 3);

    for (int kt = 0; kt < KDIM / 32; ++kt) {
        const int ko = kt * 32;
        gload16(ga0 + ko, lA0);
        gload16(gb0 + ko, lB0);
        gload16(gb1 + ko, lB1);
        __syncthreads();
        short8 a[2], b[4];
#pragma unroll
        for (int i = 0; i < 2; ++i)
            a[i] = *(const short8*)&As[(wm + i * 16 + fr) * 32 + psl];
#pragma unroll
        for (int j = 0; j < 4; ++j)
            b[j] = *(const short8*)&Bs[(wn + j * 16 + fr) * 32 + psl];
#pragma unroll
        for (int i = 0; i < 2; ++i)
#pragma unroll
            for (int j = 0; j < 4; ++j)
                acc[i][j] = __builtin_amdgcn_mfma_f32_16x16x32_bf16(a[i], b[j], acc[i][j], 0, 0, 0);
        __syncthreads();
    }
    const int cr = (lane >> 4) * 4, cc = lane & 15;
#pragma unroll
    for (int i = 0; i < 2; ++i)
#pragma unroll
        for (int j = 0; j < 4; ++j)
#pragma unroll
            for (int r = 0; r < 4; ++r)
                C[(size_t)(m0 + wm + i * 16 + cr + r) * ldc + (n0 + wn + j * 16 + cc)] = acc[i][j][r];
}

// ---------- GEMM2 MFMA K-split: part[kb][4096][48] = xs(chunk) @ Wxt^T ----------
__global__ __launch_bounds__(256) void kgemm2m(const float* __restrict__ xs,
        const float* __restrict__ Wxt, float* __restrict__ part) {
    __shared__ float As[128 * 32];   // 16 KB
    __shared__ float Bs[64 * 32];    // 8 KB
    const int t = threadIdx.x;
    const int w = t >> 6, lane = t & 63;
    const int kb = blockIdx.x;              // 0..15
    const int m0 = blockIdx.y * 128;
    const int kc = kb * 128;
    f32x4 acc[2][3] = {};

    const int srow = t >> 3;                            // 0..31
    const int scol = ((t & 7) ^ ((t >> 3) & 7)) * 4;    // pre-swizzled source (floats)
    float* lA[4]; float* lB[2];
#pragma unroll
    for (int r = 0; r < 4; ++r) lA[r] = &As[(r * 32 + w * 8) * 32];
#pragma unroll
    for (int r = 0; r < 2; ++r) lB[r] = &Bs[(r * 32 + w * 8) * 32];

    const int wm = w * 32;
    const int fr = lane & 15, fg = (lane >> 4) * 8;
    const int plo = (((fg >> 2) ^ (fr & 7))) * 4;
    const int phi = ((((fg >> 2) + 1) ^ (fr & 7))) * 4;

    for (int kt = 0; kt < 4; ++kt) {
        const int ko = kc + kt * 32;
#pragma unroll
        for (int r = 0; r < 4; ++r)
            gload16f(xs + (size_t)(m0 + r * 32 + srow) * 2048 + ko + scol, lA[r]);
#pragma unroll
        for (int r = 0; r < 2; ++r)
            gload16f(Wxt + (size_t)(r * 32 + srow) * 2048 + ko + scol, lB[r]);
        __syncthreads();
        short8 a[2], b[3];
#pragma unroll
        for (int i = 0; i < 2; ++i) {
            const float* base = &As[(wm + i * 16 + fr) * 32];
            a[i] = pack8(*(const float4*)&base[plo], *(const float4*)&base[phi]);
        }
#pragma unroll
        for (int j = 0; j < 3; ++j) {
            const float* base = &Bs[(j * 16 + fr) * 32];
            b[j] = pack8(*(const float4*)&base[plo], *(const float4*)&base[phi]);
        }
#pragma unroll
        for (int i = 0; i < 2; ++i)
#pragma unroll
            for (int j = 0; j < 3; ++j)
                acc[i][j] = __builtin_amdgcn_mfma_f32_16x16x32_bf16(a[i], b[j], acc[i][j], 0, 0, 0);
        __syncthreads();
    }
    const int cr = (lane >> 4) * 4, cc = lane & 15;
    float* pb = part + (size_t)kb * 4096 * 48;
#pragma unroll
    for (int i = 0; i < 2; ++i)
#pragma unroll
        for (int j = 0; j < 3; ++j)
#pragma unroll
            for (int r = 0; r < 4; ++r)
                pb[(size_t)(m0 + wm + i * 16 + cr + r) * 48 + j * 16 + cc] = acc[i][j][r];
}

// ---------- reduce K-split partials -> bcd ----------
__global__ void kred2(const float* __restrict__ part, float* __restrict__ bcd) {
    const int T = blockIdx.x * 256 + threadIdx.x;   // 4096*48
    if (T >= 4096 * 48) return;
    const int row = T / 48, j = T - row * 48;
    if (j >= 33) return;
    float s = 0.f;
#pragma unroll
    for (int ks = 0; ks < KS2; ++ks) s += part[(size_t)ks * 4096 * 48 + T];
    bcd[(size_t)row * BCD_LD + j] = s;
}

// ---------- prep: pack (dt, dt*x)->over xs, (silu(z), x*Dp*silu(z))->szw ----------
__global__ void kprep(const float* __restrict__ bcd, const float* __restrict__ wdt,
                      const float* __restrict__ bdt, const float* __restrict__ Dp,
                      float* __restrict__ xs_io, const uint16_t* __restrict__ xzb,
                      uint32_t* __restrict__ szw) {
    const int T = blockIdx.x * 256 + threadIdx.x;   // 4096 rows * 512 groups
    const int row = T >> 9, dg = (T & 511) * 4;
    const float raw = bcd[(size_t)row * BCD_LD + 32];
    const float4 w  = *(const float4*)&wdt[dg];
    const float4 b  = *(const float4*)&bdt[dg];
    const float4 Dv = *(const float4*)&Dp[dg];
    const float4 xv = *(const float4*)&xs_io[(size_t)row * 2048 + dg];
    const ushort4 zu = *(const ushort4*)&xzb[(size_t)row * 4096 + 2048 + dg];
    const float dt0 = softplus_f(raw * w.x + b.x);
    const float dt1 = softplus_f(raw * w.y + b.y);
    const float dt2 = softplus_f(raw * w.z + b.z);
    const float dt3 = softplus_f(raw * w.w + b.w);
    // dtdx pack, stored back over xs (same addresses, float-typed store)
    float4 pd;
    pd.x = __uint_as_float(pack2bf(dt0, dt0 * xv.x));
    pd.y = __uint_as_float(pack2bf(dt1, dt1 * xv.y));
    pd.z = __uint_as_float(pack2bf(dt2, dt2 * xv.z));
    pd.w = __uint_as_float(pack2bf(dt3, dt3 * xv.w));
    const float s0 = silu_f(bf2f(zu.x)), s1 = silu_f(bf2f(zu.y));
    const float s2 = silu_f(bf2f(zu.z)), s3 = silu_f(bf2f(zu.w));
    uint4 ps;
    ps.x = pack2bf(s0, xv.x * Dv.x * s0);
    ps.y = pack2bf(s1, xv.y * Dv.y * s1);
    ps.z = pack2bf(s2, xv.z * Dv.z * s2);
    ps.w = pack2bf(s3, xv.w * Dv.w * s3);
    *(float4*)&xs_io[(size_t)row * 2048 + dg] = pd;
    *(uint4*)&szw[(size_t)row * 2048 + dg] = ps;
}

// ---------- scan phase 1: 2 lanes/channel (8 states each), chunklen 32 ----------
__global__ __launch_bounds__(256) void kscan1(const uint32_t* __restrict__ dtdx,
        const float* __restrict__ bcd, const float* __restrict__ Alog,
        float* __restrict__ hbuf, float* __restrict__ sumdt) {
    const int T = blockIdx.x * 256 + threadIdx.x;
    const int sub = T & 1;                 // states sub*8 .. sub*8+7
    const int ch  = (T >> 1) & 4095;
    const int chunk = T >> 13;
    const int b = ch >> 11, d = ch & 2047;
    float Ae[8]; bool st = true;
#pragma unroll
    for (int i = 0; i < 8; ++i) {
        const float a = __expf(Alog[d * 16 + sub * 8 + i]);
        Ae[i] = -a * L2E;
        st = st && (fabsf(a - (float)(sub * 8 + i + 1)) < 1e-3f);
    }
    float h[8] = {};
    float sdt = 0.f;
    const int row0 = b * SEQLEN + chunk * CHUNKLEN;
    const uint32_t* pD = dtdx + (size_t)row0 * 2048 + d;
    const float* pB = bcd + (size_t)row0 * BCD_LD + sub * 8;
    if (st) {
        for (int l0 = 0; l0 < CHUNKLEN; l0 += 2) {
            uint32_t pk[2]; float4 B0[2], B1[2];
#pragma unroll
            for (int s = 0; s < 2; ++s) {
                pk[s] = pD[(size_t)s * 2048];
                B0[s] = *(const float4*)(pB + s * BCD_LD);
                B1[s] = *(const float4*)(pB + s * BCD_LD + 4);
            }
#pragma unroll
            for (int s = 0; s < 2; ++s) {
                const float dt  = __uint_as_float(pk[s] << 16);
                const float dtx = __uint_as_float(pk[s] & 0xffff0000u);
                sdt += dt;
                const float e0 = __builtin_amdgcn_exp2f(dt * (-L2E));
                const float e2 = e0 * e0, e4 = e2 * e2, e8 = e4 * e4;
                float dec = sub ? e8 : 1.f;
                dec *= e0; h[0] = fmaf(dec, h[0], dtx * B0[s].x);
                dec *= e0; h[1] = fmaf(dec, h[1], dtx * B0[s].y);
                dec *= e0; h[2] = fmaf(dec, h[2], dtx * B0[s].z);
                dec *= e0; h[3] = fmaf(dec, h[3], dtx * B0[s].w);
                dec *= e0; h[4] = fmaf(dec, h[4], dtx * B1[s].x);
                dec *= e0; h[5] = fmaf(dec, h[5], dtx * B1[s].y);
                dec *= e0; h[6] = fmaf(dec, h[6], dtx * B1[s].z);
                dec *= e0; h[7] = fmaf(dec, h[7], dtx * B1[s].w);
            }
            pD += 2 * 2048; pB += 2 * BCD_LD;
        }
    } else {
        for (int l0 = 0; l0 < CHUNKLEN; l0 += 2) {
            uint32_t pk[2]; float4 B0[2], B1[2];
#pragma unroll
            for (int s = 0; s < 2; ++s) {
                pk[s] = pD[(size_t)s * 2048];
                B0[s] = *(const float4*)(pB + s * BCD_LD);
                B1[s] = *(const float4*)(pB + s * BCD_LD + 4);
            }
#pragma unroll
            for (int s = 0; s < 2; ++s) {
                const float dt  = __uint_as_float(pk[s] << 16);
                const float dtx = __uint_as_float(pk[s] & 0xffff0000u);
                sdt += dt;
                h[0] = fmaf(__builtin_amdgcn_exp2f(dt * Ae[0]), h[0], dtx * B0[s].x);
                h[1] = fmaf(__builtin_amdgcn_exp2f(dt * Ae[1]), h[1], dtx * B0[s].y);
                h[2] = fmaf(__builtin_amdgcn_exp2f(dt * Ae[2]), h[2], dtx * B0[s].z);
                h[3] = fmaf(__builtin_amdgcn_exp2f(dt * Ae[3]), h[3], dtx * B0[s].w);
                h[4] = fmaf(__builtin_amdgcn_exp2f(dt * Ae[4]), h[4], dtx * B1[s].x);
                h[5] = fmaf(__builtin_amdgcn_exp2f(dt * Ae[5]), h[5], dtx * B1[s].y);
                h[6] = fmaf(__builtin_amdgcn_exp2f(dt * Ae[6]), h[6], dtx * B1[s].z);
                h[7] = fmaf(__builtin_amdgcn_exp2f(dt * Ae[7]), h[7], dtx * B1[s].w);
            }
            pD += 2 * 2048; pB += 2 * BCD_LD;
        }
    }
    const size_t cc = (size_t)(chunk * 4096 + ch) * 16 + sub * 8;
    *(float4*)&hbuf[cc]     = make_float4(h[0], h[1], h[2], h[3]);
    *(float4*)&hbuf[cc + 4] = make_float4(h[4], h[5], h[6], h[7]);
    if (sub == 0) sumdt[chunk * 4096 + ch] = sdt;
}

// ---------- scan phase 2: chunk combine, carries written IN-PLACE over hbuf ----------
__global__ void kscan2(float* __restrict__ hbuf, const float* __restrict__ sumdt,
                       const float* __restrict__ Alog) {
    const int T = blockIdx.x * 256 + threadIdx.x;   // 65536
    const int n = T & 15, ch = T >> 4;
    const int d = ch & 2047;
    const float Ae = -__expf(Alog[d * 16 + n]) * L2E;
    float h = 0.f;
    for (int c = 0; c < NCHUNK; ++c) {
        const size_t idx = (size_t)(c * 4096 + ch) * 16 + n;
        const float loc = hbuf[idx];
        hbuf[idx] = h;                     // carry (h at chunk start)
        h = __builtin_amdgcn_exp2f(Ae * sumdt[c * 4096 + ch]) * h + loc;
    }
}

// ---------- scan phase 3: replay with carry, u = y*sz + w2 (bf16) ----------
__global__ __launch_bounds__(256) void kscan3(const uint32_t* __restrict__ dtdx,
        const float* __restrict__ bcd, const float* __restrict__ Alog,
        const uint32_t* __restrict__ szw, const float* __restrict__ hbuf,
        uint16_t* __restrict__ u) {
    const int T = blockIdx.x * 256 + threadIdx.x;
    const int sub = T & 1;
    const int ch  = (T >> 1) & 4095;
    const int chunk = T >> 13;
    const int b = ch >> 11, d = ch & 2047;
    float Ae[8]; bool st = true;
#pragma unroll
    for (int i = 0; i < 8; ++i) {
        const float a = __expf(Alog[d * 16 + sub * 8 + i]);
        Ae[i] = -a * L2E;
        st = st && (fabsf(a - (float)(sub * 8 + i + 1)) < 1e-3f);
    }
    float h[8];
    {
        const size_t cc = (size_t)(chunk * 4096 + ch) * 16 + sub * 8;
        const float4 h0 = *(const float4*)&hbuf[cc];
        const float4 h1 = *(const float4*)&hbuf[cc + 4];
        h[0] = h0.x; h[1] = h0.y; h[2] = h0.z; h[3] = h0.w;
        h[4] = h1.x; h[5] = h1.y; h[6] = h1.z; h[7] = h1.w;
    }
    const int row0 = b * SEQLEN + chunk * CHUNKLEN;
    const uint32_t* pD = dtdx + (size_t)row0 * 2048 + d;
    const uint32_t* pS = szw  + (size_t)row0 * 2048 + d;   // only sub==0 reads
    const float* pB = bcd + (size_t)row0 * BCD_LD + sub * 8;
    uint16_t* pU = u + (size_t)row0 * D_INNER + d;
    if (st) {
        for (int l0 = 0; l0 < CHUNKLEN; l0 += 2) {
            uint32_t pk[2], qk[2]; float4 B0[2], B1[2], C0[2], C1[2];
#pragma unroll
            for (int s = 0; s < 2; ++s) {
                pk[s] = pD[(size_t)s * 2048];
                B0[s] = *(const float4*)(pB + s * BCD_LD);
                B1[s] = *(const float4*)(pB + s * BCD_LD + 4);
                C0[s] = *(const float4*)(pB + s * BCD_LD + 16);
                C1[s] = *(const float4*)(pB + s * BCD_LD + 20);
                if (sub == 0) qk[s] = pS[(size_t)s * 2048];
            }
#pragma unroll
            for (int s = 0; s < 2; ++s) {
                const float dt  = __uint_as_float(pk[s] << 16);
                const float dtx = __uint_as_float(pk[s] & 0xffff0000u);
                const float e0 = __builtin_amdgcn_exp2f(dt * (-L2E));
                const float e2 = e0 * e0, e4 = e2 * e2, e8 = e4 * e4;
                float dec = sub ? e8 : 1.f;
                dec *= e0; h[0] = fmaf(dec, h[0], dtx * B0[s].x);
                dec *= e0; h[1] = fmaf(dec, h[1], dtx * B0[s].y);
                dec *= e0; h[2] = fmaf(dec, h[2], dtx * B0[s].z);
                dec *= e0; h[3] = fmaf(dec, h[3], dtx * B0[s].w);
                dec *= e0; h[4] = fmaf(dec, h[4], dtx * B1[s].x);
                dec *= e0; h[5] = fmaf(dec, h[5], dtx * B1[s].y);
                dec *= e0; h[6] = fmaf(dec, h[6], dtx * B1[s].z);
                dec *= e0; h[7] = fmaf(dec, h[7], dtx * B1[s].w);
                float y = h[0] * C0[s].x + h[1] * C0[s].y + h[2] * C0[s].z + h[3] * C0[s].w
                        + h[4] * C1[s].x + h[5] * C1[s].y + h[6] * C1[s].z + h[7] * C1[s].w;
                y += __shfl_xor(y, 1);
                if (sub == 0) {
                    const float sz = __uint_as_float(qk[s] << 16);
                    const float w2 = __uint_as_float(qk[s] & 0xffff0000u);
                    pU[(size_t)s * D_INNER] = f2bf(fmaf(y, sz, w2));
                }
            }
            pD += 2 * 2048; pS += 2 * 2048; pB += 2 * BCD_LD; pU += 2 * D_INNER;
        }
    } else {
        for (int l0 = 0; l0 < CHUNKLEN; l0 += 2) {
            uint32_t pk[2], qk[2]; float4 B0[2], B1[2], C0[2], C1[2];
#pragma unroll
            for (int s = 0; s < 2; ++s) {
                pk[s] = pD[(size_t)s * 2048];
                B0[s] = *(const float4*)(pB + s * BCD_LD);
                B1[s] = *(const float4*)(pB + s * BCD_LD + 4);
                C0[s] = *(const float4*)(pB + s * BCD_LD + 16);
                C1[s] = *(const float4*)(pB + s * BCD_LD + 20);
                if (sub == 0) qk[s] = pS[(size_t)s * 2048];
            }
#pragma unroll
            for (int s = 0; s < 2; ++s) {
                const float dt  = __uint_as_float(pk[s] << 16);
                const float dtx = __uint_as_float(pk[s] & 0xffff0000u);
                h[0] = fmaf(__builtin_amdgcn_exp2f(dt * Ae[0]), h[0], dtx * B0[s].x);
                h[1] = fmaf(__builtin_amdgcn_exp2f(dt * Ae[1]), h[1], dtx * B0[s].y);
                h[2] = fmaf(__builtin_amdgcn_exp2f(dt * Ae[2]), h[2], dtx * B0[s].z);
                h[3] = fmaf(__builtin_amdgcn_exp2f(dt * Ae[3]), h[3], dtx * B0[s].w);
                h[4] = fmaf(__builtin_amdgcn_exp2f(dt * Ae[4]), h[4], dtx * B1[s].x);
                h[5] = fmaf(__builtin_amdgcn_exp2f(dt * Ae[5]), h[5], dtx * B1[s].y);
                h[6] = fmaf(__builtin_amdgcn_exp2f(dt * Ae[6]), h[6], dtx * B1[s].z);
                h[7] = fmaf(__builtin_amdgcn_exp2f(dt * Ae[7]), h[7], dtx * B1[s].w);
                float y = h[0] * C0[s].x + h[1] * C0[s].y + h[2] * C0[s].z + h[3] * C0[s].w
                        + h[4] * C1[s].x + h[5] * C1[s].y + h[6] * C1[s].z + h[7] * C1[s].w;
                y += __shfl_xor(y, 1);
                if (sub == 0) {
                    const float sz = __uint_as_float(qk[s] << 16);
                    const float w2 = __uint_as_float(qk[s] & 0xffff0000u);
                    pU[(size_t)s * D_INNER] = f2bf(fmaf(y, sz, w2));
                }
            }
            pD += 2 * 2048; pS += 2 * 2048; pB += 2 * BCD_LD; pU += 2 * D_INNER;
        }
    }
}

// ---------- causal depthwise conv (k=4) + bias + SiLU, bf16 input ----------
__global__ void kconv(const uint16_t* __restrict__ xzb, const float* __restrict__ cw,
                      const float* __restrict__ cb, float* __restrict__ xs) {
    size_t T = (size_t)blockIdx.x * 256 + threadIdx.x;   // over NROWS*D_INNER
    int d = (int)(T & (D_INNER - 1));
    int row = (int)(T >> 11);
    int l = row & (SEQLEN - 1), b = row >> 11;
    const float4 w4 = *(const float4*)&cw[d * 4];
    float acc = cb[d];
    const size_t base = (size_t)b * SEQLEN;
    if (l >= 3) {
        acc += w4.x * bf2f(xzb[(base + l - 3) * 4096 + d]);
        acc += w4.y * bf2f(xzb[(base + l - 2) * 4096 + d]);
        acc += w4.z * bf2f(xzb[(base + l - 1) * 4096 + d]);
        acc += w4.w * bf2f(xzb[(base + l    ) * 4096 + d]);
    } else {
        if (l >= 2) acc += w4.y * bf2f(xzb[(base + l - 2) * 4096 + d]);
        if (l >= 1) acc += w4.z * bf2f(xzb[(base + l - 1) * 4096 + d]);
        acc += w4.w * bf2f(xzb[(base + l) * 4096 + d]);
    }
    xs[T] = silu_f(acc);
}

extern "C" void kernel_launch(void* const* d_in, const int* in_sizes, int n_in,
                              void* d_out, int out_size, void* d_ws, size_t ws_size,
                              hipStream_t stream) {
    const float* x      = (const float*)d_in[0];
    const float* W_in   = (const float*)d_in[1];
    const float* conv_w = (const float*)d_in[2];
    const float* conv_b = (const float*)d_in[3];
    const float* W_x    = (const float*)d_in[4];
    const float* w_dt   = (const float*)d_in[5];
    const float* b_dt   = (const float*)d_in[6];
    const float* A_log  = (const float*)d_in[7];
    const float* Dp     = (const float*)d_in[8];
    const float* W_out  = (const float*)d_in[9];
    float* out = (float*)d_out;

    char* p = (char*)d_ws;
    uint16_t* xb  = (uint16_t*)p;  p += (size_t)NROWS * D_MODEL * 2;      // 8 MB (dead after gemm1)
    uint16_t* Wb  = (uint16_t*)p;  p += (size_t)4096 * 1024 * 2;          // 8 MB (dead after gemm1)
    uint16_t* Wob = (uint16_t*)p;  p += (size_t)1024 * 2048 * 2;          // 4 MB  (W_out^T)
    uint16_t* xzb = (uint16_t*)p;  p += (size_t)NROWS * 4096 * 2;         // 32 MB (bf16 xz)
    float* xs     = (float*)p;     p += (size_t)NROWS * D_INNER * 4;      // 32 MB (f32 xs, then dtdx pack)
    float* bcd    = (float*)p;     p += (size_t)NROWS * BCD_LD * 4;       // 576 KB
    float* sumdt  = (float*)p;     p += (size_t)NCHUNK * 4096 * 4;        // 1 MB
    float* Wxt    = (float*)p;     p += (size_t)64 * 2048 * 4;            // 512 KB
    uint16_t* ub  = (uint16_t*)p;  p += (size_t)NROWS * D_INNER * 2;      // 16 MB
    uint32_t* szw = (uint32_t*)p;  p += (size_t)NROWS * D_INNER * 4;      // 32 MB (silu(z) pack)
    // overlays (regions dead during their use):
    float* hbuf   = (float*)xb;        // 16 MB = xb+Wb (dead after gemm1)
    float* part   = (float*)ub;        // 12.6 MB (ub written only by kscan3, later)
    uint32_t* dtdx = (uint32_t*)xs;    // packed (dt, dt*x), in-place over xs after kprep

    // 1) dtype prep
    kcvt<<<(NROWS * D_MODEL / 4 + 255) / 256, 256, 0, stream>>>(x, xb, NROWS * D_MODEL / 4);
    ktrans<<<dim3(4096 / 32, 1024 / 32), 256, 0, stream>>>(W_in, Wb, 1024, 4096);
    ktrans<<<dim3(1024 / 32, 2048 / 32), 256, 0, stream>>>(W_out, Wob, 2048, 1024);
    kwxt<<<(64 * 2048) / 256, 256, 0, stream>>>(W_x, Wxt);
    // 2) xz = x @ W_in   (M=4096, N=4096, K=1024), bf16 out, 256x128 tile
    kgemm256<1024, 5><<<dim3(32, 16), 512, 0, stream>>>(xb, Wb, xzb, 4096);
    // 3) conv + silu (bf16 in, f32 out)
    kconv<<<NROWS * D_INNER / 256, 256, 0, stream>>>(xzb, conv_w, conv_b, xs);
    // 4) bcd = xs @ W_x  (MFMA, K-split 16 + reduce)
    kgemm2m<<<dim3(KS2, 32), 256, 0, stream>>>(xs, Wxt, part);
    kred2<<<(4096 * 48 + 255) / 256, 256, 0, stream>>>(part, bcd);
    // 5) pack scan operands (dtdx in-place over xs, szw separate)
    kprep<<<(4096 * 512) / 256, 256, 0, stream>>>(bcd, w_dt, b_dt, Dp, xs, xzb, szw);
    // 6) selective scan (3 phases)
    kscan1<<<(4096 * 2 * NCHUNK) / 256, 256, 0, stream>>>(dtdx, bcd, A_log, hbuf, sumdt);
    kscan2<<<(4096 * 16) / 256, 256, 0, stream>>>(hbuf, sumdt, A_log);
    kscan3<<<(4096 * 2 * NCHUNK) / 256, 256, 0, stream>>>(dtdx, bcd, A_log, szw, hbuf, ub);
    // 7) out = u @ W_out (M=4096, N=1024, K=2048)
    kgemm64<2048, 3><<<dim3(1024 / 128, 4096 / 64), 256, 0, stream>>>(ub, Wob, out, 1024);
}

// Round 8
// 222.161 us; speedup vs baseline: 2.4180x; 1.0054x over previous
//
#include <hip/hip_runtime.h>
#include <hip/hip_bf16.h>
#include <stdint.h>

#define D_MODEL 1024
#define D_STATE 16
#define D_CONV  4
#define D_INNER 2048
#define BATCH   2
#define SEQLEN  2048
#define NROWS   (BATCH*SEQLEN)     // 4096
#define BCD_LD  36                 // padded leading dim for bcd (33 used)
#define NCHUNK  64
#define CHUNKLEN (SEQLEN/NCHUNK)   // 32
#define KS2     16                 // K-splits for GEMM2 (chunk = 128)
#define L2E 1.44269504088896340f

typedef __attribute__((ext_vector_type(8))) short   short8;
typedef __attribute__((ext_vector_type(4))) float   f32x4;

__device__ __forceinline__ uint16_t f2bf(float f) {        // RNE f32->bf16
    uint32_t u = __float_as_uint(f);
    return (uint16_t)((u + 0x7FFFu + ((u >> 16) & 1u)) >> 16);
}
__device__ __forceinline__ float bf2f(uint16_t h) {
    return __uint_as_float(((uint32_t)h) << 16);
}
__device__ __forceinline__ uint32_t pack2bf(float lo, float hi) {
    return (uint32_t)f2bf(lo) | ((uint32_t)f2bf(hi) << 16);
}
__device__ __forceinline__ void gload16(const uint16_t* g, uint16_t* l) {
    __builtin_amdgcn_global_load_lds(
        (const __attribute__((address_space(1))) void*)g,
        (__attribute__((address_space(3))) void*)l, 16, 0, 0);
}
__device__ __forceinline__ void gload16f(const float* g, float* l) {
    __builtin_amdgcn_global_load_lds(
        (const __attribute__((address_space(1))) void*)g,
        (__attribute__((address_space(3))) void*)l, 16, 0, 0);
}
__device__ __forceinline__ float softplus_f(float v) {
    return fmaxf(v, 0.f) + __logf(1.f + __expf(-fabsf(v)));
}
__device__ __forceinline__ float silu_f(float v) {
    return v / (1.f + __expf(-v));
}
__device__ __forceinline__ short8 pack8(const float4 lo, const float4 hi) {
    short8 r;
    r[0] = (short)f2bf(lo.x); r[1] = (short)f2bf(lo.y);
    r[2] = (short)f2bf(lo.z); r[3] = (short)f2bf(lo.w);
    r[4] = (short)f2bf(hi.x); r[5] = (short)f2bf(hi.y);
    r[6] = (short)f2bf(hi.z); r[7] = (short)f2bf(hi.w);
    return r;
}

// ---------- f32 -> bf16 elementwise (x) ----------
__global__ void kcvt(const float* __restrict__ in, uint16_t* __restrict__ out, int n4) {
    int T = blockIdx.x * 256 + threadIdx.x;
    if (T >= n4) return;
    const float4 v = *(const float4*)&in[(size_t)T * 4];
    ushort4 o;
    o.x = f2bf(v.x); o.y = f2bf(v.y); o.z = f2bf(v.z); o.w = f2bf(v.w);
    *(ushort4*)&out[(size_t)T * 4] = o;
}

// ---------- transpose+convert: in[Kd][Nd] f32 -> out[Nd][Kd] bf16 ----------
__global__ void ktrans(const float* __restrict__ in, uint16_t* __restrict__ out,
                       int Kd, int Nd) {
    __shared__ float tile[32][33];
    const int n0 = blockIdx.x * 32, k0 = blockIdx.y * 32;
    const int tx = threadIdx.x & 31, ty = threadIdx.x >> 5;   // ty 0..7
#pragma unroll
    for (int i = 0; i < 4; ++i)
        tile[ty + i * 8][tx] = in[(size_t)(k0 + ty + i * 8) * Nd + n0 + tx];
    __syncthreads();
#pragma unroll
    for (int i = 0; i < 4; ++i)
        out[(size_t)(n0 + ty + i * 8) * Kd + k0 + tx] = f2bf(tile[tx][ty + i * 8]);
}

// ---------- Wxt[64][2048] f32 = W_x^T zero-padded (33 -> 64 rows) ----------
__global__ void kwxt(const float* __restrict__ Wx, float* __restrict__ Wxt) {
    const int T = blockIdx.x * 256 + threadIdx.x;   // 64*2048
    const int j = T >> 11, k = T & 2047;
    Wxt[T] = (j < 33) ? Wx[(size_t)k * 33 + j] : 0.f;
}

// ---------- GEMM1: 256x128 tile, 512 thr, bf16 C out (XCD-swizzled) ----------
template<int KDIM, int GXL>
__global__ __launch_bounds__(512) void kgemm256(const uint16_t* __restrict__ A,
                                                const uint16_t* __restrict__ B,
                                                uint16_t* __restrict__ C, const int ldc) {
    __shared__ uint16_t As[256 * 32];   // 16 KB
    __shared__ uint16_t Bs[128 * 32];   // 8 KB
    const int t = threadIdx.x;          // 0..511
    const int w = t >> 6, lane = t & 63;
    int wg = blockIdx.y * (1 << GXL) + blockIdx.x;
    wg = (wg & 7) * ((gridDim.x * gridDim.y) >> 3) + (wg >> 3);   // bijective XCD swizzle
    const int m0 = (wg >> GXL) * 256, n0 = (wg & ((1 << GXL) - 1)) * 128;
    const int wm = (w >> 1) * 64, wn = (w & 1) * 64;
    f32x4 acc[4][4] = {};

    const int srow = t >> 2;                              // 0..127
    const int scol = ((t & 3) ^ ((t >> 3) & 3)) * 8;      // pre-swizzled source slot
    const uint16_t* ga0 = A + (size_t)(m0 + srow) * KDIM + scol;
    const uint16_t* ga1 = A + (size_t)(m0 + 128 + srow) * KDIM + scol;
    const uint16_t* gb0 = B + (size_t)(n0 + srow) * KDIM + scol;
    uint16_t* lA0 = &As[w * 512];
    uint16_t* lA1 = &As[4096 + w * 512];
    uint16_t* lB0 = &Bs[w * 512];

    const int fr = lane & 15, fg = (lane >> 4) * 8;
    const int psl = (((fg >> 3) ^ ((fr >> 1) & 3)) << 3);

    for (int kt = 0; kt < KDIM / 32; ++kt) {
        const int ko = kt * 32;
        gload16(ga0 + ko, lA0);
        gload16(ga1 + ko, lA1);
        gload16(gb0 + ko, lB0);
        __syncthreads();
        short8 a[4], b[4];
#pragma unroll
        for (int i = 0; i < 4; ++i) {
            a[i] = *(const short8*)&As[(wm + i * 16 + fr) * 32 + psl];
            b[i] = *(const short8*)&Bs[(wn + i * 16 + fr) * 32 + psl];
        }
#pragma unroll
        for (int i = 0; i < 4; ++i)
#pragma unroll
            for (int j = 0; j < 4; ++j)
                acc[i][j] = __builtin_amdgcn_mfma_f32_16x16x32_bf16(a[i], b[j], acc[i][j], 0, 0, 0);
        __syncthreads();
    }
    const int cr = (lane >> 4) * 4, cc = lane & 15;
#pragma unroll
    for (int i = 0; i < 4; ++i)
#pragma unroll
        for (int j = 0; j < 4; ++j)
#pragma unroll
            for (int r = 0; r < 4; ++r)
                C[(size_t)(m0 + wm + i * 16 + cr + r) * ldc + (n0 + wn + j * 16 + cc)] =
                    f2bf(acc[i][j][r]);
}

// ---------- TN bf16 MFMA GEMM 64x128 (GEMM3, f32 C), XCD-swizzled ----------
template<int KDIM, int GXL>
__global__ __launch_bounds__(256) void kgemm64(const uint16_t* __restrict__ A,
                                               const uint16_t* __restrict__ B,
                                               float* __restrict__ C, const int ldc) {
    __shared__ uint16_t As[64 * 32];     // 4 KB
    __shared__ uint16_t Bs[128 * 32];    // 8 KB
    const int t = threadIdx.x;
    const int w = t >> 6, lane = t & 63;
    int wg = blockIdx.y * (1 << GXL) + blockIdx.x;
    wg = (wg & 7) * ((gridDim.x * gridDim.y) >> 3) + (wg >> 3);
    const int m0 = (wg >> GXL) * 64, n0 = (wg & ((1 << GXL) - 1)) * 128;
    const int wm = (w >> 1) * 32, wn = (w & 1) * 64;
    f32x4 acc[2][4] = {};

    const int srow = t >> 2;
    const int scol = ((t & 3) ^ ((t >> 3) & 3)) * 8;
    const uint16_t* ga0 = A + (size_t)(m0 + srow) * KDIM + scol;
    const uint16_t* gb0 = B + (size_t)(n0 + srow) * KDIM + scol;
    const uint16_t* gb1 = B + (size_t)(n0 + 64 + srow) * KDIM + scol;
    uint16_t* lA0 = &As[w * 512];
    uint16_t* lB0 = &Bs[w * 512];
    uint16_t* lB1 = &Bs[2048 + w * 512];

    const int fr = lane & 15, fg = (lane >> 4) * 8;
    const int psl = (((fg >> 3) ^ ((fr >> 1) & 3)) << 3);

    for (int kt = 0; kt < KDIM / 32; ++kt) {
        const int ko = kt * 32;
        gload16(ga0 + ko, lA0);
        gload16(gb0 + ko, lB0);
        gload16(gb1 + ko, lB1);
        __syncthreads();
        short8 a[2], b[4];
#pragma unroll
        for (int i = 0; i < 2; ++i)
            a[i] = *(const short8*)&As[(wm + i * 16 + fr) * 32 + psl];
#pragma unroll
        for (int j = 0; j < 4; ++j)
            b[j] = *(const short8*)&Bs[(wn + j * 16 + fr) * 32 + psl];
#pragma unroll
        for (int i = 0; i < 2; ++i)
#pragma unroll
            for (int j = 0; j < 4; ++j)
                acc[i][j] = __builtin_amdgcn_mfma_f32_16x16x32_bf16(a[i], b[j], acc[i][j], 0, 0, 0);
        __syncthreads();
    }
    const int cr = (lane >> 4) * 4, cc = lane & 15;
#pragma unroll
    for (int i = 0; i < 2; ++i)
#pragma unroll
        for (int j = 0; j < 4; ++j)
#pragma unroll
            for (int r = 0; r < 4; ++r)
                C[(size_t)(m0 + wm + i * 16 + cr + r) * ldc + (n0 + wn + j * 16 + cc)] = acc[i][j][r];
}

// ---------- GEMM2 MFMA K-split: part[kb][4096][48] = xs(chunk) @ Wxt^T ----------
__global__ __launch_bounds__(256) void kgemm2m(const float* __restrict__ xs,
        const float* __restrict__ Wxt, float* __restrict__ part) {
    __shared__ float As[128 * 32];   // 16 KB
    __shared__ float Bs[64 * 32];    // 8 KB
    const int t = threadIdx.x;
    const int w = t >> 6, lane = t & 63;
    const int kb = blockIdx.x;              // 0..15
    const int m0 = blockIdx.y * 128;
    const int kc = kb * 128;
    f32x4 acc[2][3] = {};

    const int srow = t >> 3;                            // 0..31
    const int scol = ((t & 7) ^ ((t >> 3) & 7)) * 4;    // pre-swizzled source (floats)
    float* lA[4]; float* lB[2];
#pragma unroll
    for (int r = 0; r < 4; ++r) lA[r] = &As[(r * 32 + w * 8) * 32];
#pragma unroll
    for (int r = 0; r < 2; ++r) lB[r] = &Bs[(r * 32 + w * 8) * 32];

    const int wm = w * 32;
    const int fr = lane & 15, fg = (lane >> 4) * 8;
    const int plo = (((fg >> 2) ^ (fr & 7))) * 4;
    const int phi = ((((fg >> 2) + 1) ^ (fr & 7))) * 4;

    for (int kt = 0; kt < 4; ++kt) {
        const int ko = kc + kt * 32;
#pragma unroll
        for (int r = 0; r < 4; ++r)
            gload16f(xs + (size_t)(m0 + r * 32 + srow) * 2048 + ko + scol, lA[r]);
#pragma unroll
        for (int r = 0; r < 2; ++r)
            gload16f(Wxt + (size_t)(r * 32 + srow) * 2048 + ko + scol, lB[r]);
        __syncthreads();
        short8 a[2], b[3];
#pragma unroll
        for (int i = 0; i < 2; ++i) {
            const float* base = &As[(wm + i * 16 + fr) * 32];
            a[i] = pack8(*(const float4*)&base[plo], *(const float4*)&base[phi]);
        }
#pragma unroll
        for (int j = 0; j < 3; ++j) {
            const float* base = &Bs[(j * 16 + fr) * 32];
            b[j] = pack8(*(const float4*)&base[plo], *(const float4*)&base[phi]);
        }
#pragma unroll
        for (int i = 0; i < 2; ++i)
#pragma unroll
            for (int j = 0; j < 3; ++j)
                acc[i][j] = __builtin_amdgcn_mfma_f32_16x16x32_bf16(a[i], b[j], acc[i][j], 0, 0, 0);
        __syncthreads();
    }
    const int cr = (lane >> 4) * 4, cc = lane & 15;
    float* pb = part + (size_t)kb * 4096 * 48;
#pragma unroll
    for (int i = 0; i < 2; ++i)
#pragma unroll
        for (int j = 0; j < 3; ++j)
#pragma unroll
            for (int r = 0; r < 4; ++r)
                pb[(size_t)(m0 + wm + i * 16 + cr + r) * 48 + j * 16 + cc] = acc[i][j][r];
}

// ---------- reduce K-split partials -> bcd ----------
__global__ void kred2(const float* __restrict__ part, float* __restrict__ bcd) {
    const int T = blockIdx.x * 256 + threadIdx.x;   // 4096*48
    if (T >= 4096 * 48) return;
    const int row = T / 48, j = T - row * 48;
    if (j >= 33) return;
    float s = 0.f;
#pragma unroll
    for (int ks = 0; ks < KS2; ++ks) s += part[(size_t)ks * 4096 * 48 + T];
    bcd[(size_t)row * BCD_LD + j] = s;
}

// ---------- prep: pack (dt, dt*x)->over xs, (silu(z), x*Dp*silu(z))->szw ----------
__global__ void kprep(const float* __restrict__ bcd, const float* __restrict__ wdt,
                      const float* __restrict__ bdt, const float* __restrict__ Dp,
                      float* __restrict__ xs_io, const uint16_t* __restrict__ xzb,
                      uint32_t* __restrict__ szw) {
    const int T = blockIdx.x * 256 + threadIdx.x;   // 4096 rows * 512 groups
    const int row = T >> 9, dg = (T & 511) * 4;
    const float raw = bcd[(size_t)row * BCD_LD + 32];
    const float4 w  = *(const float4*)&wdt[dg];
    const float4 b  = *(const float4*)&bdt[dg];
    const float4 Dv = *(const float4*)&Dp[dg];
    const float4 xv = *(const float4*)&xs_io[(size_t)row * 2048 + dg];
    const ushort4 zu = *(const ushort4*)&xzb[(size_t)row * 4096 + 2048 + dg];
    const float dt0 = softplus_f(raw * w.x + b.x);
    const float dt1 = softplus_f(raw * w.y + b.y);
    const float dt2 = softplus_f(raw * w.z + b.z);
    const float dt3 = softplus_f(raw * w.w + b.w);
    float4 pd;
    pd.x = __uint_as_float(pack2bf(dt0, dt0 * xv.x));
    pd.y = __uint_as_float(pack2bf(dt1, dt1 * xv.y));
    pd.z = __uint_as_float(pack2bf(dt2, dt2 * xv.z));
    pd.w = __uint_as_float(pack2bf(dt3, dt3 * xv.w));
    const float s0 = silu_f(bf2f(zu.x)), s1 = silu_f(bf2f(zu.y));
    const float s2 = silu_f(bf2f(zu.z)), s3 = silu_f(bf2f(zu.w));
    uint4 ps;
    ps.x = pack2bf(s0, xv.x * Dv.x * s0);
    ps.y = pack2bf(s1, xv.y * Dv.y * s1);
    ps.z = pack2bf(s2, xv.z * Dv.z * s2);
    ps.w = pack2bf(s3, xv.w * Dv.w * s3);
    *(float4*)&xs_io[(size_t)row * 2048 + dg] = pd;
    *(uint4*)&szw[(size_t)row * 2048 + dg] = ps;
}

// ---------- scan phase 1: 2 channels/thread, 8 states each, chunklen 32 ----------
// T: sub = T&1 (states sub*8..+7), cp = (T>>1)&2047 (b*1024+dp), chunk = T>>12
__global__ __launch_bounds__(256) void kscan1(const uint32_t* __restrict__ dtdx,
        const float* __restrict__ bcd, const float* __restrict__ Alog,
        float* __restrict__ hbuf, float* __restrict__ sumdt) {
    const int T = blockIdx.x * 256 + threadIdx.x;
    const int sub = T & 1;
    const int cp  = (T >> 1) & 2047;
    const int chunk = T >> 12;
    const int b = cp >> 10, d0 = (cp & 1023) * 2;
    float Ae0[8], Ae1[8]; bool st = true;
#pragma unroll
    for (int i = 0; i < 8; ++i) {
        const float a0 = __expf(Alog[d0 * 16 + sub * 8 + i]);
        const float a1 = __expf(Alog[(d0 + 1) * 16 + sub * 8 + i]);
        Ae0[i] = -a0 * L2E; Ae1[i] = -a1 * L2E;
        st = st && (fabsf(a0 - (float)(sub * 8 + i + 1)) < 1e-3f)
                && (fabsf(a1 - (float)(sub * 8 + i + 1)) < 1e-3f);
    }
    float hA[8] = {}, hB[8] = {};
    float sdtA = 0.f, sdtB = 0.f;
    const int row0 = b * SEQLEN + chunk * CHUNKLEN;
    const uint32_t* pD = dtdx + (size_t)row0 * 2048 + d0;
    const float* pB = bcd + (size_t)row0 * BCD_LD + sub * 8;
    if (st) {
        for (int l0 = 0; l0 < CHUNKLEN; l0 += 2) {
            uint2 pk[2]; float4 B0[2], B1[2];
#pragma unroll
            for (int s = 0; s < 2; ++s) {
                pk[s] = *(const uint2*)(pD + (size_t)s * 2048);
                B0[s] = *(const float4*)(pB + s * BCD_LD);
                B1[s] = *(const float4*)(pB + s * BCD_LD + 4);
            }
#pragma unroll
            for (int s = 0; s < 2; ++s) {
                const float dtA  = __uint_as_float(pk[s].x << 16);
                const float dtxA = __uint_as_float(pk[s].x & 0xffff0000u);
                const float dtB  = __uint_as_float(pk[s].y << 16);
                const float dtxB = __uint_as_float(pk[s].y & 0xffff0000u);
                sdtA += dtA; sdtB += dtB;
                const float e0A = __builtin_amdgcn_exp2f(dtA * (-L2E));
                const float e0B = __builtin_amdgcn_exp2f(dtB * (-L2E));
                const float e8A = (e0A*e0A)*(e0A*e0A)*(e0A*e0A)*(e0A*e0A);
                const float e8B = (e0B*e0B)*(e0B*e0B)*(e0B*e0B)*(e0B*e0B);
                float dA = sub ? e8A : 1.f, dB = sub ? e8B : 1.f;
                dA *= e0A; dB *= e0B; hA[0] = fmaf(dA, hA[0], dtxA * B0[s].x); hB[0] = fmaf(dB, hB[0], dtxB * B0[s].x);
                dA *= e0A; dB *= e0B; hA[1] = fmaf(dA, hA[1], dtxA * B0[s].y); hB[1] = fmaf(dB, hB[1], dtxB * B0[s].y);
                dA *= e0A; dB *= e0B; hA[2] = fmaf(dA, hA[2], dtxA * B0[s].z); hB[2] = fmaf(dB, hB[2], dtxB * B0[s].z);
                dA *= e0A; dB *= e0B; hA[3] = fmaf(dA, hA[3], dtxA * B0[s].w); hB[3] = fmaf(dB, hB[3], dtxB * B0[s].w);
                dA *= e0A; dB *= e0B; hA[4] = fmaf(dA, hA[4], dtxA * B1[s].x); hB[4] = fmaf(dB, hB[4], dtxB * B1[s].x);
                dA *= e0A; dB *= e0B; hA[5] = fmaf(dA, hA[5], dtxA * B1[s].y); hB[5] = fmaf(dB, hB[5], dtxB * B1[s].y);
                dA *= e0A; dB *= e0B; hA[6] = fmaf(dA, hA[6], dtxA * B1[s].z); hB[6] = fmaf(dB, hB[6], dtxB * B1[s].z);
                dA *= e0A; dB *= e0B; hA[7] = fmaf(dA, hA[7], dtxA * B1[s].w); hB[7] = fmaf(dB, hB[7], dtxB * B1[s].w);
            }
            pD += 2 * 2048; pB += 2 * BCD_LD;
        }
    } else {
        for (int l0 = 0; l0 < CHUNKLEN; l0 += 2) {
            uint2 pk[2]; float4 B0[2], B1[2];
#pragma unroll
            for (int s = 0; s < 2; ++s) {
                pk[s] = *(const uint2*)(pD + (size_t)s * 2048);
                B0[s] = *(const float4*)(pB + s * BCD_LD);
                B1[s] = *(const float4*)(pB + s * BCD_LD + 4);
            }
#pragma unroll
            for (int s = 0; s < 2; ++s) {
                const float dtA  = __uint_as_float(pk[s].x << 16);
                const float dtxA = __uint_as_float(pk[s].x & 0xffff0000u);
                const float dtB  = __uint_as_float(pk[s].y << 16);
                const float dtxB = __uint_as_float(pk[s].y & 0xffff0000u);
                sdtA += dtA; sdtB += dtB;
                const float Bv[8] = {B0[s].x, B0[s].y, B0[s].z, B0[s].w,
                                     B1[s].x, B1[s].y, B1[s].z, B1[s].w};
#pragma unroll
                for (int i = 0; i < 8; ++i) {
                    hA[i] = fmaf(__builtin_amdgcn_exp2f(dtA * Ae0[i]), hA[i], dtxA * Bv[i]);
                    hB[i] = fmaf(__builtin_amdgcn_exp2f(dtB * Ae1[i]), hB[i], dtxB * Bv[i]);
                }
            }
            pD += 2 * 2048; pB += 2 * BCD_LD;
        }
    }
    const size_t cc0 = (size_t)(chunk * 4096 + b * 2048 + d0) * 16 + sub * 8;
    *(float4*)&hbuf[cc0]          = make_float4(hA[0], hA[1], hA[2], hA[3]);
    *(float4*)&hbuf[cc0 + 4]      = make_float4(hA[4], hA[5], hA[6], hA[7]);
    *(float4*)&hbuf[cc0 + 16]     = make_float4(hB[0], hB[1], hB[2], hB[3]);
    *(float4*)&hbuf[cc0 + 20]     = make_float4(hB[4], hB[5], hB[6], hB[7]);
    if (sub == 0)
        *(float2*)&sumdt[chunk * 4096 + b * 2048 + d0] = make_float2(sdtA, sdtB);
}

// ---------- scan phase 2: chunk combine, carries written IN-PLACE over hbuf ----------
__global__ void kscan2(float* __restrict__ hbuf, const float* __restrict__ sumdt,
                       const float* __restrict__ Alog) {
    const int T = blockIdx.x * 256 + threadIdx.x;   // 65536
    const int n = T & 15, ch = T >> 4;
    const int d = ch & 2047;
    const float Ae = -__expf(Alog[d * 16 + n]) * L2E;
    float h = 0.f;
    for (int c = 0; c < NCHUNK; ++c) {
        const size_t idx = (size_t)(c * 4096 + ch) * 16 + n;
        const float loc = hbuf[idx];
        hbuf[idx] = h;                     // carry (h at chunk start)
        h = __builtin_amdgcn_exp2f(Ae * sumdt[c * 4096 + ch]) * h + loc;
    }
}

// ---------- scan phase 3: 2 channels/thread, replay with carry, u packed store ----------
__global__ __launch_bounds__(256) void kscan3(const uint32_t* __restrict__ dtdx,
        const float* __restrict__ bcd, const float* __restrict__ Alog,
        const uint32_t* __restrict__ szw, const float* __restrict__ hbuf,
        uint16_t* __restrict__ u) {
    const int T = blockIdx.x * 256 + threadIdx.x;
    const int sub = T & 1;
    const int cp  = (T >> 1) & 2047;
    const int chunk = T >> 12;
    const int b = cp >> 10, d0 = (cp & 1023) * 2;
    float Ae0[8], Ae1[8]; bool st = true;
#pragma unroll
    for (int i = 0; i < 8; ++i) {
        const float a0 = __expf(Alog[d0 * 16 + sub * 8 + i]);
        const float a1 = __expf(Alog[(d0 + 1) * 16 + sub * 8 + i]);
        Ae0[i] = -a0 * L2E; Ae1[i] = -a1 * L2E;
        st = st && (fabsf(a0 - (float)(sub * 8 + i + 1)) < 1e-3f)
                && (fabsf(a1 - (float)(sub * 8 + i + 1)) < 1e-3f);
    }
    float hA[8], hB[8];
    {
        const size_t cc0 = (size_t)(chunk * 4096 + b * 2048 + d0) * 16 + sub * 8;
        const float4 a0 = *(const float4*)&hbuf[cc0];
        const float4 a1 = *(const float4*)&hbuf[cc0 + 4];
        const float4 b0 = *(const float4*)&hbuf[cc0 + 16];
        const float4 b1 = *(const float4*)&hbuf[cc0 + 20];
        hA[0]=a0.x; hA[1]=a0.y; hA[2]=a0.z; hA[3]=a0.w;
        hA[4]=a1.x; hA[5]=a1.y; hA[6]=a1.z; hA[7]=a1.w;
        hB[0]=b0.x; hB[1]=b0.y; hB[2]=b0.z; hB[3]=b0.w;
        hB[4]=b1.x; hB[5]=b1.y; hB[6]=b1.z; hB[7]=b1.w;
    }
    const int row0 = b * SEQLEN + chunk * CHUNKLEN;
    const uint32_t* pD = dtdx + (size_t)row0 * 2048 + d0;
    const uint32_t* pS = szw  + (size_t)row0 * 2048 + d0;   // only sub==0 reads
    const float* pB = bcd + (size_t)row0 * BCD_LD + sub * 8;
    uint16_t* pU = u + (size_t)row0 * D_INNER + d0;
    if (st) {
        for (int l0 = 0; l0 < CHUNKLEN; l0 += 2) {
            uint2 pk[2], qk[2]; float4 B0[2], B1[2], C0[2], C1[2];
#pragma unroll
            for (int s = 0; s < 2; ++s) {
                pk[s] = *(const uint2*)(pD + (size_t)s * 2048);
                B0[s] = *(const float4*)(pB + s * BCD_LD);
                B1[s] = *(const float4*)(pB + s * BCD_LD + 4);
                C0[s] = *(const float4*)(pB + s * BCD_LD + 16);
                C1[s] = *(const float4*)(pB + s * BCD_LD + 20);
                if (sub == 0) qk[s] = *(const uint2*)(pS + (size_t)s * 2048);
            }
#pragma unroll
            for (int s = 0; s < 2; ++s) {
                const float dtA  = __uint_as_float(pk[s].x << 16);
                const float dtxA = __uint_as_float(pk[s].x & 0xffff0000u);
                const float dtB  = __uint_as_float(pk[s].y << 16);
                const float dtxB = __uint_as_float(pk[s].y & 0xffff0000u);
                const float e0A = __builtin_amdgcn_exp2f(dtA * (-L2E));
                const float e0B = __builtin_amdgcn_exp2f(dtB * (-L2E));
                const float e8A = (e0A*e0A)*(e0A*e0A)*(e0A*e0A)*(e0A*e0A);
                const float e8B = (e0B*e0B)*(e0B*e0B)*(e0B*e0B)*(e0B*e0B);
                float dA = sub ? e8A : 1.f, dB = sub ? e8B : 1.f;
                float yA, yB;
                dA *= e0A; dB *= e0B; hA[0] = fmaf(dA, hA[0], dtxA * B0[s].x); hB[0] = fmaf(dB, hB[0], dtxB * B0[s].x);
                dA *= e0A; dB *= e0B; hA[1] = fmaf(dA, hA[1], dtxA * B0[s].y); hB[1] = fmaf(dB, hB[1], dtxB * B0[s].y);
                dA *= e0A; dB *= e0B; hA[2] = fmaf(dA, hA[2], dtxA * B0[s].z); hB[2] = fmaf(dB, hB[2], dtxB * B0[s].z);
                dA *= e0A; dB *= e0B; hA[3] = fmaf(dA, hA[3], dtxA * B0[s].w); hB[3] = fmaf(dB, hB[3], dtxB * B0[s].w);
                dA *= e0A; dB *= e0B; hA[4] = fmaf(dA, hA[4], dtxA * B1[s].x); hB[4] = fmaf(dB, hB[4], dtxB * B1[s].x);
                dA *= e0A; dB *= e0B; hA[5] = fmaf(dA, hA[5], dtxA * B1[s].y); hB[5] = fmaf(dB, hB[5], dtxB * B1[s].y);
                dA *= e0A; dB *= e0B; hA[6] = fmaf(dA, hA[6], dtxA * B1[s].z); hB[6] = fmaf(dB, hB[6], dtxB * B1[s].z);
                dA *= e0A; dB *= e0B; hA[7] = fmaf(dA, hA[7], dtxA * B1[s].w); hB[7] = fmaf(dB, hB[7], dtxB * B1[s].w);
                yA = hA[0]*C0[s].x + hA[1]*C0[s].y + hA[2]*C0[s].z + hA[3]*C0[s].w
                   + hA[4]*C1[s].x + hA[5]*C1[s].y + hA[6]*C1[s].z + hA[7]*C1[s].w;
                yB = hB[0]*C0[s].x + hB[1]*C0[s].y + hB[2]*C0[s].z + hB[3]*C0[s].w
                   + hB[4]*C1[s].x + hB[5]*C1[s].y + hB[6]*C1[s].z + hB[7]*C1[s].w;
                yA += __shfl_xor(yA, 1);
                yB += __shfl_xor(yB, 1);
                if (sub == 0) {
                    const float szA = __uint_as_float(qk[s].x << 16);
                    const float w2A = __uint_as_float(qk[s].x & 0xffff0000u);
                    const float szB = __uint_as_float(qk[s].y << 16);
                    const float w2B = __uint_as_float(qk[s].y & 0xffff0000u);
                    *(uint32_t*)(pU + (size_t)s * D_INNER) =
                        pack2bf(fmaf(yA, szA, w2A), fmaf(yB, szB, w2B));
                }
            }
            pD += 2 * 2048; pS += 2 * 2048; pB += 2 * BCD_LD; pU += 2 * D_INNER;
        }
    } else {
        for (int l0 = 0; l0 < CHUNKLEN; l0 += 2) {
            uint2 pk[2], qk[2]; float4 B0[2], B1[2], C0[2], C1[2];
#pragma unroll
            for (int s = 0; s < 2; ++s) {
                pk[s] = *(const uint2*)(pD + (size_t)s * 2048);
                B0[s] = *(const float4*)(pB + s * BCD_LD);
                B1[s] = *(const float4*)(pB + s * BCD_LD + 4);
                C0[s] = *(const float4*)(pB + s * BCD_LD + 16);
                C1[s] = *(const float4*)(pB + s * BCD_LD + 20);
                if (sub == 0) qk[s] = *(const uint2*)(pS + (size_t)s * 2048);
            }
#pragma unroll
            for (int s = 0; s < 2; ++s) {
                const float dtA  = __uint_as_float(pk[s].x << 16);
                const float dtxA = __uint_as_float(pk[s].x & 0xffff0000u);
                const float dtB  = __uint_as_float(pk[s].y << 16);
                const float dtxB = __uint_as_float(pk[s].y & 0xffff0000u);
                const float Bv[8] = {B0[s].x, B0[s].y, B0[s].z, B0[s].w,
                                     B1[s].x, B1[s].y, B1[s].z, B1[s].w};
                const float Cv[8] = {C0[s].x, C0[s].y, C0[s].z, C0[s].w,
                                     C1[s].x, C1[s].y, C1[s].z, C1[s].w};
                float yA = 0.f, yB = 0.f;
#pragma unroll
                for (int i = 0; i < 8; ++i) {
                    hA[i] = fmaf(__builtin_amdgcn_exp2f(dtA * Ae0[i]), hA[i], dtxA * Bv[i]);
                    hB[i] = fmaf(__builtin_amdgcn_exp2f(dtB * Ae1[i]), hB[i], dtxB * Bv[i]);
                    yA = fmaf(hA[i], Cv[i], yA);
                    yB = fmaf(hB[i], Cv[i], yB);
                }
                yA += __shfl_xor(yA, 1);
                yB += __shfl_xor(yB, 1);
                if (sub == 0) {
                    const float szA = __uint_as_float(qk[s].x << 16);
                    const float w2A = __uint_as_float(qk[s].x & 0xffff0000u);
                    const float szB = __uint_as_float(qk[s].y << 16);
                    const float w2B = __uint_as_float(qk[s].y & 0xffff0000u);
                    *(uint32_t*)(pU + (size_t)s * D_INNER) =
                        pack2bf(fmaf(yA, szA, w2A), fmaf(yB, szB, w2B));
                }
            }
            pD += 2 * 2048; pS += 2 * 2048; pB += 2 * BCD_LD; pU += 2 * D_INNER;
        }
    }
}

// ---------- causal depthwise conv (k=4) + bias + SiLU, 2 channels/thread ----------
__global__ void kconv(const uint16_t* __restrict__ xzb, const float* __restrict__ cw,
                      const float* __restrict__ cb, float* __restrict__ xs) {
    const int T = blockIdx.x * 256 + threadIdx.x;   // over NROWS*1024
    const int d0 = (T & 1023) * 2;
    const int row = T >> 10;
    const int l = row & (SEQLEN - 1), b = row >> 11;
    const float4 wA = *(const float4*)&cw[d0 * 4];
    const float4 wB = *(const float4*)&cw[d0 * 4 + 4];
    const float2 bias = *(const float2*)&cb[d0];
    float a0 = bias.x, a1 = bias.y;
    const size_t base = (size_t)b * SEQLEN;
    if (l >= 3) {
        uint32_t v;
        v = *(const uint32_t*)&xzb[(base + l - 3) * 4096 + d0];
        a0 += wA.x * bf2f((uint16_t)v); a1 += wB.x * bf2f((uint16_t)(v >> 16));
        v = *(const uint32_t*)&xzb[(base + l - 2) * 4096 + d0];
        a0 += wA.y * bf2f((uint16_t)v); a1 += wB.y * bf2f((uint16_t)(v >> 16));
        v = *(const uint32_t*)&xzb[(base + l - 1) * 4096 + d0];
        a0 += wA.z * bf2f((uint16_t)v); a1 += wB.z * bf2f((uint16_t)(v >> 16));
        v = *(const uint32_t*)&xzb[(base + l    ) * 4096 + d0];
        a0 += wA.w * bf2f((uint16_t)v); a1 += wB.w * bf2f((uint16_t)(v >> 16));
    } else {
        uint32_t v;
        if (l >= 2) {
            v = *(const uint32_t*)&xzb[(base + l - 2) * 4096 + d0];
            a0 += wA.y * bf2f((uint16_t)v); a1 += wB.y * bf2f((uint16_t)(v >> 16));
        }
        if (l >= 1) {
            v = *(const uint32_t*)&xzb[(base + l - 1) * 4096 + d0];
            a0 += wA.z * bf2f((uint16_t)v); a1 += wB.z * bf2f((uint16_t)(v >> 16));
        }
        v = *(const uint32_t*)&xzb[(base + l) * 4096 + d0];
        a0 += wA.w * bf2f((uint16_t)v); a1 += wB.w * bf2f((uint16_t)(v >> 16));
    }
    *(float2*)&xs[(size_t)row * 2048 + d0] = make_float2(silu_f(a0), silu_f(a1));
}

extern "C" void kernel_launch(void* const* d_in, const int* in_sizes, int n_in,
                              void* d_out, int out_size, void* d_ws, size_t ws_size,
                              hipStream_t stream) {
    const float* x      = (const float*)d_in[0];
    const float* W_in   = (const float*)d_in[1];
    const float* conv_w = (const float*)d_in[2];
    const float* conv_b = (const float*)d_in[3];
    const float* W_x    = (const float*)d_in[4];
    const float* w_dt   = (const float*)d_in[5];
    const float* b_dt   = (const float*)d_in[6];
    const float* A_log  = (const float*)d_in[7];
    const float* Dp     = (const float*)d_in[8];
    const float* W_out  = (const float*)d_in[9];
    float* out = (float*)d_out;

    char* p = (char*)d_ws;
    uint16_t* xb  = (uint16_t*)p;  p += (size_t)NROWS * D_MODEL * 2;      // 8 MB (dead after gemm1)
    uint16_t* Wb  = (uint16_t*)p;  p += (size_t)4096 * 1024 * 2;          // 8 MB (dead after gemm1)
    uint16_t* Wob = (uint16_t*)p;  p += (size_t)1024 * 2048 * 2;          // 4 MB  (W_out^T)
    uint16_t* xzb = (uint16_t*)p;  p += (size_t)NROWS * 4096 * 2;         // 32 MB (bf16 xz)
    float* xs     = (float*)p;     p += (size_t)NROWS * D_INNER * 4;      // 32 MB (f32 xs, then dtdx pack)
    float* bcd    = (float*)p;     p += (size_t)NROWS * BCD_LD * 4;       // 576 KB
    float* sumdt  = (float*)p;     p += (size_t)NCHUNK * 4096 * 4;        // 1 MB
    float* Wxt    = (float*)p;     p += (size_t)64 * 2048 * 4;            // 512 KB
    uint16_t* ub  = (uint16_t*)p;  p += (size_t)NROWS * D_INNER * 2;      // 16 MB
    uint32_t* szw = (uint32_t*)p;  p += (size_t)NROWS * D_INNER * 4;      // 32 MB (silu(z) pack)
    // overlays (regions dead during their use):
    float* hbuf   = (float*)xb;        // 16 MB = xb+Wb (dead after gemm1)
    float* part   = (float*)ub;        // 12.6 MB (ub written only by kscan3, later)
    uint32_t* dtdx = (uint32_t*)xs;    // packed (dt, dt*x), in-place over xs after kprep

    // 1) dtype prep
    kcvt<<<(NROWS * D_MODEL / 4 + 255) / 256, 256, 0, stream>>>(x, xb, NROWS * D_MODEL / 4);
    ktrans<<<dim3(4096 / 32, 1024 / 32), 256, 0, stream>>>(W_in, Wb, 1024, 4096);
    ktrans<<<dim3(1024 / 32, 2048 / 32), 256, 0, stream>>>(W_out, Wob, 2048, 1024);
    kwxt<<<(64 * 2048) / 256, 256, 0, stream>>>(W_x, Wxt);
    // 2) xz = x @ W_in   (M=4096, N=4096, K=1024), bf16 out, 256x128 tile
    kgemm256<1024, 5><<<dim3(32, 16), 512, 0, stream>>>(xb, Wb, xzb, 4096);
    // 3) conv + silu (bf16 in, f32 out), 2 ch/thread
    kconv<<<NROWS * 1024 / 256, 256, 0, stream>>>(xzb, conv_w, conv_b, xs);
    // 4) bcd = xs @ W_x  (MFMA, K-split 16 + reduce)
    kgemm2m<<<dim3(KS2, 32), 256, 0, stream>>>(xs, Wxt, part);
    kred2<<<(4096 * 48 + 255) / 256, 256, 0, stream>>>(part, bcd);
    // 5) pack scan operands (dtdx in-place over xs, szw separate)
    kprep<<<(4096 * 512) / 256, 256, 0, stream>>>(bcd, w_dt, b_dt, Dp, xs, xzb, szw);
    // 6) selective scan (3 phases), 2 channels/thread
    kscan1<<<(4096 * NCHUNK) / 256, 256, 0, stream>>>(dtdx, bcd, A_log, hbuf, sumdt);
    kscan2<<<(4096 * 16) / 256, 256, 0, stream>>>(hbuf, sumdt, A_log);
    kscan3<<<(4096 * NCHUNK) / 256, 256, 0, stream>>>(dtdx, bcd, A_log, szw, hbuf, ub);
    // 7) out = u @ W_out (M=4096, N=1024, K=2048)
    kgemm64<2048, 3><<<dim3(1024 / 128, 4096 / 64), 256, 0, stream>>>(ub, Wob, out, 1024);
}

// Round 9
// 221.326 us; speedup vs baseline: 2.4271x; 1.0038x over previous
//
#include <hip/hip_runtime.h>
#include <hip/hip_bf16.h>
#include <stdint.h>

#define D_MODEL 1024
#define D_STATE 16
#define D_CONV  4
#define D_INNER 2048
#define BATCH   2
#define SEQLEN  2048
#define NROWS   (BATCH*SEQLEN)     // 4096
#define BCD_LD  36                 // padded leading dim for bcd (33 used)
#define NCHUNK  64
#define CHUNKLEN (SEQLEN/NCHUNK)   // 32
#define KS2     16                 // K-splits for GEMM2 (chunk = 128)
#define L2E 1.44269504088896340f

typedef __attribute__((ext_vector_type(8))) short   short8;
typedef __attribute__((ext_vector_type(4))) float   f32x4;

__device__ __forceinline__ uint16_t f2bf(float f) {        // RNE f32->bf16
    uint32_t u = __float_as_uint(f);
    return (uint16_t)((u + 0x7FFFu + ((u >> 16) & 1u)) >> 16);
}
__device__ __forceinline__ float bf2f(uint16_t h) {
    return __uint_as_float(((uint32_t)h) << 16);
}
__device__ __forceinline__ uint32_t pack2bf(float lo, float hi) {
    return (uint32_t)f2bf(lo) | ((uint32_t)f2bf(hi) << 16);
}
__device__ __forceinline__ void gload16(const uint16_t* g, uint16_t* l) {
    __builtin_amdgcn_global_load_lds(
        (const __attribute__((address_space(1))) void*)g,
        (__attribute__((address_space(3))) void*)l, 16, 0, 0);
}
__device__ __forceinline__ void gload16f(const float* g, float* l) {
    __builtin_amdgcn_global_load_lds(
        (const __attribute__((address_space(1))) void*)g,
        (__attribute__((address_space(3))) void*)l, 16, 0, 0);
}
__device__ __forceinline__ float softplus_f(float v) {
    return fmaxf(v, 0.f) + __logf(1.f + __expf(-fabsf(v)));
}
__device__ __forceinline__ float silu_f(float v) {
    return v / (1.f + __expf(-v));
}
__device__ __forceinline__ short8 pack8(const float4 lo, const float4 hi) {
    short8 r;
    r[0] = (short)f2bf(lo.x); r[1] = (short)f2bf(lo.y);
    r[2] = (short)f2bf(lo.z); r[3] = (short)f2bf(lo.w);
    r[4] = (short)f2bf(hi.x); r[5] = (short)f2bf(hi.y);
    r[6] = (short)f2bf(hi.z); r[7] = (short)f2bf(hi.w);
    return r;
}

// ---------- f32 -> bf16 elementwise (x) ----------
__global__ void kcvt(const float* __restrict__ in, uint16_t* __restrict__ out, int n4) {
    int T = blockIdx.x * 256 + threadIdx.x;
    if (T >= n4) return;
    const float4 v = *(const float4*)&in[(size_t)T * 4];
    ushort4 o;
    o.x = f2bf(v.x); o.y = f2bf(v.y); o.z = f2bf(v.z); o.w = f2bf(v.w);
    *(ushort4*)&out[(size_t)T * 4] = o;
}

// ---------- transpose+convert: in[Kd][Nd] f32 -> out[Nd][Kd] bf16 ----------
__global__ void ktrans(const float* __restrict__ in, uint16_t* __restrict__ out,
                       int Kd, int Nd) {
    __shared__ float tile[32][33];
    const int n0 = blockIdx.x * 32, k0 = blockIdx.y * 32;
    const int tx = threadIdx.x & 31, ty = threadIdx.x >> 5;   // ty 0..7
#pragma unroll
    for (int i = 0; i < 4; ++i)
        tile[ty + i * 8][tx] = in[(size_t)(k0 + ty + i * 8) * Nd + n0 + tx];
    __syncthreads();
#pragma unroll
    for (int i = 0; i < 4; ++i)
        out[(size_t)(n0 + ty + i * 8) * Kd + k0 + tx] = f2bf(tile[tx][ty + i * 8]);
}

// ---------- Wxt[64][2048] f32 = W_x^T zero-padded (33 -> 64 rows) ----------
__global__ void kwxt(const float* __restrict__ Wx, float* __restrict__ Wxt) {
    const int T = blockIdx.x * 256 + threadIdx.x;   // 64*2048
    const int j = T >> 11, k = T & 2047;
    Wxt[T] = (j < 33) ? Wx[(size_t)k * 33 + j] : 0.f;
}

// ---------- GEMM1: 256x128 tile, 512 thr, 2-phase dbuf, bf16 C (XCD-swizzled) ----------
template<int KDIM, int GXL>
__global__ __launch_bounds__(512) void kgemm256(const uint16_t* __restrict__ A,
                                                const uint16_t* __restrict__ B,
                                                uint16_t* __restrict__ C, const int ldc) {
    __shared__ uint16_t As[2][256 * 32];   // 2 x 16 KB
    __shared__ uint16_t Bsh[2][128 * 32];  // 2 x 8 KB
    const int t = threadIdx.x;          // 0..511
    const int w = t >> 6, lane = t & 63;
    int wg = blockIdx.y * (1 << GXL) + blockIdx.x;
    wg = (wg & 7) * ((gridDim.x * gridDim.y) >> 3) + (wg >> 3);   // bijective XCD swizzle
    const int m0 = (wg >> GXL) * 256, n0 = (wg & ((1 << GXL) - 1)) * 128;
    const int wm = (w >> 1) * 64, wn = (w & 1) * 64;
    f32x4 acc[4][4] = {};

    const int srow = t >> 2;                              // 0..127
    const int scol = ((t & 3) ^ ((t >> 3) & 3)) * 8;      // pre-swizzled source slot
    const uint16_t* ga0 = A + (size_t)(m0 + srow) * KDIM + scol;
    const uint16_t* ga1 = A + (size_t)(m0 + 128 + srow) * KDIM + scol;
    const uint16_t* gb0 = B + (size_t)(n0 + srow) * KDIM + scol;

    const int fr = lane & 15, fg = (lane >> 4) * 8;
    const int psl = (((fg >> 3) ^ ((fr >> 1) & 3)) << 3);

    auto stage = [&](int buf, int ko) {
        gload16(ga0 + ko, &As[buf][w * 512]);
        gload16(ga1 + ko, &As[buf][4096 + w * 512]);
        gload16(gb0 + ko, &Bsh[buf][w * 512]);
    };

    stage(0, 0);
    __syncthreads();
    int cur = 0;
    for (int kt = 0; kt < KDIM / 32; ++kt) {
        if (kt + 1 < KDIM / 32) stage(cur ^ 1, (kt + 1) * 32);   // prefetch next tile
        short8 a[4], b[4];
#pragma unroll
        for (int i = 0; i < 4; ++i) {
            a[i] = *(const short8*)&As[cur][(wm + i * 16 + fr) * 32 + psl];
            b[i] = *(const short8*)&Bsh[cur][(wn + i * 16 + fr) * 32 + psl];
        }
#pragma unroll
        for (int i = 0; i < 4; ++i)
#pragma unroll
            for (int j = 0; j < 4; ++j)
                acc[i][j] = __builtin_amdgcn_mfma_f32_16x16x32_bf16(a[i], b[j], acc[i][j], 0, 0, 0);
        __syncthreads();            // drains prefetch (vmcnt 0) + sync reads
        cur ^= 1;
    }
    const int cr = (lane >> 4) * 4, cc = lane & 15;
#pragma unroll
    for (int i = 0; i < 4; ++i)
#pragma unroll
        for (int j = 0; j < 4; ++j)
#pragma unroll
            for (int r = 0; r < 4; ++r)
                C[(size_t)(m0 + wm + i * 16 + cr + r) * ldc + (n0 + wn + j * 16 + cc)] =
                    f2bf(acc[i][j][r]);
}

// ---------- GEMM3: 64x128 tile, 2-phase dbuf, f32 C (XCD-swizzled) ----------
template<int KDIM, int GXL>
__global__ __launch_bounds__(256) void kgemm64(const uint16_t* __restrict__ A,
                                               const uint16_t* __restrict__ B,
                                               float* __restrict__ C, const int ldc) {
    __shared__ uint16_t As[2][64 * 32];      // 2 x 4 KB
    __shared__ uint16_t Bsh[2][128 * 32];    // 2 x 8 KB
    const int t = threadIdx.x;
    const int w = t >> 6, lane = t & 63;
    int wg = blockIdx.y * (1 << GXL) + blockIdx.x;
    wg = (wg & 7) * ((gridDim.x * gridDim.y) >> 3) + (wg >> 3);
    const int m0 = (wg >> GXL) * 64, n0 = (wg & ((1 << GXL) - 1)) * 128;
    const int wm = (w >> 1) * 32, wn = (w & 1) * 64;
    f32x4 acc[2][4] = {};

    const int srow = t >> 2;
    const int scol = ((t & 3) ^ ((t >> 3) & 3)) * 8;
    const uint16_t* ga0 = A + (size_t)(m0 + srow) * KDIM + scol;
    const uint16_t* gb0 = B + (size_t)(n0 + srow) * KDIM + scol;
    const uint16_t* gb1 = B + (size_t)(n0 + 64 + srow) * KDIM + scol;

    const int fr = lane & 15, fg = (lane >> 4) * 8;
    const int psl = (((fg >> 3) ^ ((fr >> 1) & 3)) << 3);

    auto stage = [&](int buf, int ko) {
        gload16(ga0 + ko, &As[buf][w * 512]);
        gload16(gb0 + ko, &Bsh[buf][w * 512]);
        gload16(gb1 + ko, &Bsh[buf][2048 + w * 512]);
    };

    stage(0, 0);
    __syncthreads();
    int cur = 0;
    for (int kt = 0; kt < KDIM / 32; ++kt) {
        if (kt + 1 < KDIM / 32) stage(cur ^ 1, (kt + 1) * 32);
        short8 a[2], b[4];
#pragma unroll
        for (int i = 0; i < 2; ++i)
            a[i] = *(const short8*)&As[cur][(wm + i * 16 + fr) * 32 + psl];
#pragma unroll
        for (int j = 0; j < 4; ++j)
            b[j] = *(const short8*)&Bsh[cur][(wn + j * 16 + fr) * 32 + psl];
#pragma unroll
        for (int i = 0; i < 2; ++i)
#pragma unroll
            for (int j = 0; j < 4; ++j)
                acc[i][j] = __builtin_amdgcn_mfma_f32_16x16x32_bf16(a[i], b[j], acc[i][j], 0, 0, 0);
        __syncthreads();
        cur ^= 1;
    }
    const int cr = (lane >> 4) * 4, cc = lane & 15;
#pragma unroll
    for (int i = 0; i < 2; ++i)
#pragma unroll
        for (int j = 0; j < 4; ++j)
#pragma unroll
            for (int r = 0; r < 4; ++r)
                C[(size_t)(m0 + wm + i * 16 + cr + r) * ldc + (n0 + wn + j * 16 + cc)] = acc[i][j][r];
}

// ---------- GEMM2 MFMA K-split: part[kb][4096][48] = xs(chunk) @ Wxt^T ----------
__global__ __launch_bounds__(256) void kgemm2m(const float* __restrict__ xs,
        const float* __restrict__ Wxt, float* __restrict__ part) {
    __shared__ float As[128 * 32];   // 16 KB
    __shared__ float Bs[64 * 32];    // 8 KB
    const int t = threadIdx.x;
    const int w = t >> 6, lane = t & 63;
    const int kb = blockIdx.x;              // 0..15
    const int m0 = blockIdx.y * 128;
    const int kc = kb * 128;
    f32x4 acc[2][3] = {};

    const int srow = t >> 3;                            // 0..31
    const int scol = ((t & 7) ^ ((t >> 3) & 7)) * 4;    // pre-swizzled source (floats)
    float* lA[4]; float* lB[2];
#pragma unroll
    for (int r = 0; r < 4; ++r) lA[r] = &As[(r * 32 + w * 8) * 32];
#pragma unroll
    for (int r = 0; r < 2; ++r) lB[r] = &Bs[(r * 32 + w * 8) * 32];

    const int wm = w * 32;
    const int fr = lane & 15, fg = (lane >> 4) * 8;
    const int plo = (((fg >> 2) ^ (fr & 7))) * 4;
    const int phi = ((((fg >> 2) + 1) ^ (fr & 7))) * 4;

    for (int kt = 0; kt < 4; ++kt) {
        const int ko = kc + kt * 32;
#pragma unroll
        for (int r = 0; r < 4; ++r)
            gload16f(xs + (size_t)(m0 + r * 32 + srow) * 2048 + ko + scol, lA[r]);
#pragma unroll
        for (int r = 0; r < 2; ++r)
            gload16f(Wxt + (size_t)(r * 32 + srow) * 2048 + ko + scol, lB[r]);
        __syncthreads();
        short8 a[2], b[3];
#pragma unroll
        for (int i = 0; i < 2; ++i) {
            const float* base = &As[(wm + i * 16 + fr) * 32];
            a[i] = pack8(*(const float4*)&base[plo], *(const float4*)&base[phi]);
        }
#pragma unroll
        for (int j = 0; j < 3; ++j) {
            const float* base = &Bs[(j * 16 + fr) * 32];
            b[j] = pack8(*(const float4*)&base[plo], *(const float4*)&base[phi]);
        }
#pragma unroll
        for (int i = 0; i < 2; ++i)
#pragma unroll
            for (int j = 0; j < 3; ++j)
                acc[i][j] = __builtin_amdgcn_mfma_f32_16x16x32_bf16(a[i], b[j], acc[i][j], 0, 0, 0);
        __syncthreads();
    }
    const int cr = (lane >> 4) * 4, cc = lane & 15;
    float* pb = part + (size_t)kb * 4096 * 48;
#pragma unroll
    for (int i = 0; i < 2; ++i)
#pragma unroll
        for (int j = 0; j < 3; ++j)
#pragma unroll
            for (int r = 0; r < 4; ++r)
                pb[(size_t)(m0 + wm + i * 16 + cr + r) * 48 + j * 16 + cc] = acc[i][j][r];
}

// ---------- reduce K-split partials -> bcd ----------
__global__ void kred2(const float* __restrict__ part, float* __restrict__ bcd) {
    const int T = blockIdx.x * 256 + threadIdx.x;   // 4096*48
    if (T >= 4096 * 48) return;
    const int row = T / 48, j = T - row * 48;
    if (j >= 33) return;
    float s = 0.f;
#pragma unroll
    for (int ks = 0; ks < KS2; ++ks) s += part[(size_t)ks * 4096 * 48 + T];
    bcd[(size_t)row * BCD_LD + j] = s;
}

// ---------- prep: pack (dt, dt*x)->over xs, (silu(z), x*Dp*silu(z))->szw ----------
__global__ void kprep(const float* __restrict__ bcd, const float* __restrict__ wdt,
                      const float* __restrict__ bdt, const float* __restrict__ Dp,
                      float* __restrict__ xs_io, const uint16_t* __restrict__ xzb,
                      uint32_t* __restrict__ szw) {
    const int T = blockIdx.x * 256 + threadIdx.x;   // 4096 rows * 512 groups
    const int row = T >> 9, dg = (T & 511) * 4;
    const float raw = bcd[(size_t)row * BCD_LD + 32];
    const float4 w  = *(const float4*)&wdt[dg];
    const float4 b  = *(const float4*)&bdt[dg];
    const float4 Dv = *(const float4*)&Dp[dg];
    const float4 xv = *(const float4*)&xs_io[(size_t)row * 2048 + dg];
    const ushort4 zu = *(const ushort4*)&xzb[(size_t)row * 4096 + 2048 + dg];
    const float dt0 = softplus_f(raw * w.x + b.x);
    const float dt1 = softplus_f(raw * w.y + b.y);
    const float dt2 = softplus_f(raw * w.z + b.z);
    const float dt3 = softplus_f(raw * w.w + b.w);
    float4 pd;
    pd.x = __uint_as_float(pack2bf(dt0, dt0 * xv.x));
    pd.y = __uint_as_float(pack2bf(dt1, dt1 * xv.y));
    pd.z = __uint_as_float(pack2bf(dt2, dt2 * xv.z));
    pd.w = __uint_as_float(pack2bf(dt3, dt3 * xv.w));
    const float s0 = silu_f(bf2f(zu.x)), s1 = silu_f(bf2f(zu.y));
    const float s2 = silu_f(bf2f(zu.z)), s3 = silu_f(bf2f(zu.w));
    uint4 ps;
    ps.x = pack2bf(s0, xv.x * Dv.x * s0);
    ps.y = pack2bf(s1, xv.y * Dv.y * s1);
    ps.z = pack2bf(s2, xv.z * Dv.z * s2);
    ps.w = pack2bf(s3, xv.w * Dv.w * s3);
    *(float4*)&xs_io[(size_t)row * 2048 + dg] = pd;
    *(uint4*)&szw[(size_t)row * 2048 + dg] = ps;
}

// ---------- scan phase 1: 2 ch/thread, bcd B staged in LDS ----------
__global__ __launch_bounds__(256) void kscan1(const uint32_t* __restrict__ dtdx,
        const float* __restrict__ bcd, const float* __restrict__ Alog,
        float* __restrict__ hbuf, float* __restrict__ sumdt) {
    const int T = blockIdx.x * 256 + threadIdx.x;
    const int sub = T & 1;
    const int cp  = (T >> 1) & 2047;
    const int chunk = T >> 12;
    const int b = cp >> 10, d0 = (cp & 1023) * 2;
    const int row0 = b * SEQLEN + chunk * CHUNKLEN;    // same for whole block

    __shared__ float Bls[32][16];       // B part (cols 0..15) of the 32 chunk rows
    {
        const int r = threadIdx.x >> 3, c = (threadIdx.x & 7) * 2;
        const float2 v = *(const float2*)&bcd[(size_t)(row0 + r) * BCD_LD + c];
        Bls[r][c] = v.x; Bls[r][c + 1] = v.y;
    }
    __syncthreads();

    float Ae0[8], Ae1[8]; bool st = true;
#pragma unroll
    for (int i = 0; i < 8; ++i) {
        const float a0 = __expf(Alog[d0 * 16 + sub * 8 + i]);
        const float a1 = __expf(Alog[(d0 + 1) * 16 + sub * 8 + i]);
        Ae0[i] = -a0 * L2E; Ae1[i] = -a1 * L2E;
        st = st && (fabsf(a0 - (float)(sub * 8 + i + 1)) < 1e-3f)
                && (fabsf(a1 - (float)(sub * 8 + i + 1)) < 1e-3f);
    }
    float hA[8] = {}, hB[8] = {};
    float sdtA = 0.f, sdtB = 0.f;
    const uint32_t* pD = dtdx + (size_t)row0 * 2048 + d0;
    if (st) {
        for (int l0 = 0; l0 < CHUNKLEN; l0 += 2) {
            uint2 pk[2]; float4 B0[2], B1[2];
#pragma unroll
            for (int s = 0; s < 2; ++s) {
                pk[s] = *(const uint2*)(pD + (size_t)s * 2048);
                B0[s] = *(const float4*)&Bls[l0 + s][sub * 8];
                B1[s] = *(const float4*)&Bls[l0 + s][sub * 8 + 4];
            }
#pragma unroll
            for (int s = 0; s < 2; ++s) {
                const float dtA  = __uint_as_float(pk[s].x << 16);
                const float dtxA = __uint_as_float(pk[s].x & 0xffff0000u);
                const float dtB  = __uint_as_float(pk[s].y << 16);
                const float dtxB = __uint_as_float(pk[s].y & 0xffff0000u);
                sdtA += dtA; sdtB += dtB;
                const float e0A = __builtin_amdgcn_exp2f(dtA * (-L2E));
                const float e0B = __builtin_amdgcn_exp2f(dtB * (-L2E));
                const float e8A = (e0A*e0A)*(e0A*e0A)*(e0A*e0A)*(e0A*e0A);
                const float e8B = (e0B*e0B)*(e0B*e0B)*(e0B*e0B)*(e0B*e0B);
                float dA = sub ? e8A : 1.f, dB = sub ? e8B : 1.f;
                dA *= e0A; dB *= e0B; hA[0] = fmaf(dA, hA[0], dtxA * B0[s].x); hB[0] = fmaf(dB, hB[0], dtxB * B0[s].x);
                dA *= e0A; dB *= e0B; hA[1] = fmaf(dA, hA[1], dtxA * B0[s].y); hB[1] = fmaf(dB, hB[1], dtxB * B0[s].y);
                dA *= e0A; dB *= e0B; hA[2] = fmaf(dA, hA[2], dtxA * B0[s].z); hB[2] = fmaf(dB, hB[2], dtxB * B0[s].z);
                dA *= e0A; dB *= e0B; hA[3] = fmaf(dA, hA[3], dtxA * B0[s].w); hB[3] = fmaf(dB, hB[3], dtxB * B0[s].w);
                dA *= e0A; dB *= e0B; hA[4] = fmaf(dA, hA[4], dtxA * B1[s].x); hB[4] = fmaf(dB, hB[4], dtxB * B1[s].x);
                dA *= e0A; dB *= e0B; hA[5] = fmaf(dA, hA[5], dtxA * B1[s].y); hB[5] = fmaf(dB, hB[5], dtxB * B1[s].y);
                dA *= e0A; dB *= e0B; hA[6] = fmaf(dA, hA[6], dtxA * B1[s].z); hB[6] = fmaf(dB, hB[6], dtxB * B1[s].z);
                dA *= e0A; dB *= e0B; hA[7] = fmaf(dA, hA[7], dtxA * B1[s].w); hB[7] = fmaf(dB, hB[7], dtxB * B1[s].w);
            }
            pD += 2 * 2048;
        }
    } else {
        for (int l0 = 0; l0 < CHUNKLEN; l0 += 2) {
            uint2 pk[2]; float4 B0[2], B1[2];
#pragma unroll
            for (int s = 0; s < 2; ++s) {
                pk[s] = *(const uint2*)(pD + (size_t)s * 2048);
                B0[s] = *(const float4*)&Bls[l0 + s][sub * 8];
                B1[s] = *(const float4*)&Bls[l0 + s][sub * 8 + 4];
            }
#pragma unroll
            for (int s = 0; s < 2; ++s) {
                const float dtA  = __uint_as_float(pk[s].x << 16);
                const float dtxA = __uint_as_float(pk[s].x & 0xffff0000u);
                const float dtB  = __uint_as_float(pk[s].y << 16);
                const float dtxB = __uint_as_float(pk[s].y & 0xffff0000u);
                sdtA += dtA; sdtB += dtB;
                const float Bv[8] = {B0[s].x, B0[s].y, B0[s].z, B0[s].w,
                                     B1[s].x, B1[s].y, B1[s].z, B1[s].w};
#pragma unroll
                for (int i = 0; i < 8; ++i) {
                    hA[i] = fmaf(__builtin_amdgcn_exp2f(dtA * Ae0[i]), hA[i], dtxA * Bv[i]);
                    hB[i] = fmaf(__builtin_amdgcn_exp2f(dtB * Ae1[i]), hB[i], dtxB * Bv[i]);
                }
            }
            pD += 2 * 2048;
        }
    }
    const size_t cc0 = (size_t)(chunk * 4096 + b * 2048 + d0) * 16 + sub * 8;
    *(float4*)&hbuf[cc0]          = make_float4(hA[0], hA[1], hA[2], hA[3]);
    *(float4*)&hbuf[cc0 + 4]      = make_float4(hA[4], hA[5], hA[6], hA[7]);
    *(float4*)&hbuf[cc0 + 16]     = make_float4(hB[0], hB[1], hB[2], hB[3]);
    *(float4*)&hbuf[cc0 + 20]     = make_float4(hB[4], hB[5], hB[6], hB[7]);
    if (sub == 0)
        *(float2*)&sumdt[chunk * 4096 + b * 2048 + d0] = make_float2(sdtA, sdtB);
}

// ---------- scan phase 2: chunk combine, carries written IN-PLACE over hbuf ----------
__global__ void kscan2(float* __restrict__ hbuf, const float* __restrict__ sumdt,
                       const float* __restrict__ Alog) {
    const int T = blockIdx.x * 256 + threadIdx.x;   // 65536
    const int n = T & 15, ch = T >> 4;
    const int d = ch & 2047;
    const float Ae = -__expf(Alog[d * 16 + n]) * L2E;
    float h = 0.f;
    for (int c = 0; c < NCHUNK; ++c) {
        const size_t idx = (size_t)(c * 4096 + ch) * 16 + n;
        const float loc = hbuf[idx];
        hbuf[idx] = h;                     // carry (h at chunk start)
        h = __builtin_amdgcn_exp2f(Ae * sumdt[c * 4096 + ch]) * h + loc;
    }
}

// ---------- scan phase 3: 2 ch/thread, bcd B+C staged in LDS, u packed store ----------
__global__ __launch_bounds__(256) void kscan3(const uint32_t* __restrict__ dtdx,
        const float* __restrict__ bcd, const float* __restrict__ Alog,
        const uint32_t* __restrict__ szw, const float* __restrict__ hbuf,
        uint16_t* __restrict__ u) {
    const int T = blockIdx.x * 256 + threadIdx.x;
    const int sub = T & 1;
    const int cp  = (T >> 1) & 2047;
    const int chunk = T >> 12;
    const int b = cp >> 10, d0 = (cp & 1023) * 2;
    const int row0 = b * SEQLEN + chunk * CHUNKLEN;    // same for whole block

    __shared__ float BC[32][32];        // B (0..15) + C (16..31) of the 32 chunk rows
    {
        const int r = threadIdx.x >> 3, c = (threadIdx.x & 7) * 4;
        *(float4*)&BC[r][c] = *(const float4*)&bcd[(size_t)(row0 + r) * BCD_LD + c];
    }
    __syncthreads();

    float Ae0[8], Ae1[8]; bool st = true;
#pragma unroll
    for (int i = 0; i < 8; ++i) {
        const float a0 = __expf(Alog[d0 * 16 + sub * 8 + i]);
        const float a1 = __expf(Alog[(d0 + 1) * 16 + sub * 8 + i]);
        Ae0[i] = -a0 * L2E; Ae1[i] = -a1 * L2E;
        st = st && (fabsf(a0 - (float)(sub * 8 + i + 1)) < 1e-3f)
                && (fabsf(a1 - (float)(sub * 8 + i + 1)) < 1e-3f);
    }
    float hA[8], hB[8];
    {
        const size_t cc0 = (size_t)(chunk * 4096 + b * 2048 + d0) * 16 + sub * 8;
        const float4 a0 = *(const float4*)&hbuf[cc0];
        const float4 a1 = *(const float4*)&hbuf[cc0 + 4];
        const float4 b0 = *(const float4*)&hbuf[cc0 + 16];
        const float4 b1 = *(const float4*)&hbuf[cc0 + 20];
        hA[0]=a0.x; hA[1]=a0.y; hA[2]=a0.z; hA[3]=a0.w;
        hA[4]=a1.x; hA[5]=a1.y; hA[6]=a1.z; hA[7]=a1.w;
        hB[0]=b0.x; hB[1]=b0.y; hB[2]=b0.z; hB[3]=b0.w;
        hB[4]=b1.x; hB[5]=b1.y; hB[6]=b1.z; hB[7]=b1.w;
    }
    const uint32_t* pD = dtdx + (size_t)row0 * 2048 + d0;
    const uint32_t* pS = szw  + (size_t)row0 * 2048 + d0;   // only sub==0 reads
    uint16_t* pU = u + (size_t)row0 * D_INNER + d0;
    if (st) {
        for (int l0 = 0; l0 < CHUNKLEN; l0 += 2) {
            uint2 pk[2], qk[2]; float4 B0[2], B1[2], C0[2], C1[2];
#pragma unroll
            for (int s = 0; s < 2; ++s) {
                pk[s] = *(const uint2*)(pD + (size_t)s * 2048);
                B0[s] = *(const float4*)&BC[l0 + s][sub * 8];
                B1[s] = *(const float4*)&BC[l0 + s][sub * 8 + 4];
                C0[s] = *(const float4*)&BC[l0 + s][16 + sub * 8];
                C1[s] = *(const float4*)&BC[l0 + s][20 + sub * 8];
                if (sub == 0) qk[s] = *(const uint2*)(pS + (size_t)s * 2048);
            }
#pragma unroll
            for (int s = 0; s < 2; ++s) {
                const float dtA  = __uint_as_float(pk[s].x << 16);
                const float dtxA = __uint_as_float(pk[s].x & 0xffff0000u);
                const float dtB  = __uint_as_float(pk[s].y << 16);
                const float dtxB = __uint_as_float(pk[s].y & 0xffff0000u);
                const float e0A = __builtin_amdgcn_exp2f(dtA * (-L2E));
                const float e0B = __builtin_amdgcn_exp2f(dtB * (-L2E));
                const float e8A = (e0A*e0A)*(e0A*e0A)*(e0A*e0A)*(e0A*e0A);
                const float e8B = (e0B*e0B)*(e0B*e0B)*(e0B*e0B)*(e0B*e0B);
                float dA = sub ? e8A : 1.f, dB = sub ? e8B : 1.f;
                float yA, yB;
                dA *= e0A; dB *= e0B; hA[0] = fmaf(dA, hA[0], dtxA * B0[s].x); hB[0] = fmaf(dB, hB[0], dtxB * B0[s].x);
                dA *= e0A; dB *= e0B; hA[1] = fmaf(dA, hA[1], dtxA * B0[s].y); hB[1] = fmaf(dB, hB[1], dtxB * B0[s].y);
                dA *= e0A; dB *= e0B; hA[2] = fmaf(dA, hA[2], dtxA * B0[s].z); hB[2] = fmaf(dB, hB[2], dtxB * B0[s].z);
                dA *= e0A; dB *= e0B; hA[3] = fmaf(dA, hA[3], dtxA * B0[s].w); hB[3] = fmaf(dB, hB[3], dtxB * B0[s].w);
                dA *= e0A; dB *= e0B; hA[4] = fmaf(dA, hA[4], dtxA * B1[s].x); hB[4] = fmaf(dB, hB[4], dtxB * B1[s].x);
                dA *= e0A; dB *= e0B; hA[5] = fmaf(dA, hA[5], dtxA * B1[s].y); hB[5] = fmaf(dB, hB[5], dtxB * B1[s].y);
                dA *= e0A; dB *= e0B; hA[6] = fmaf(dA, hA[6], dtxA * B1[s].z); hB[6] = fmaf(dB, hB[6], dtxB * B1[s].z);
                dA *= e0A; dB *= e0B; hA[7] = fmaf(dA, hA[7], dtxA * B1[s].w); hB[7] = fmaf(dB, hB[7], dtxB * B1[s].w);
                yA = hA[0]*C0[s].x + hA[1]*C0[s].y + hA[2]*C0[s].z + hA[3]*C0[s].w
                   + hA[4]*C1[s].x + hA[5]*C1[s].y + hA[6]*C1[s].z + hA[7]*C1[s].w;
                yB = hB[0]*C0[s].x + hB[1]*C0[s].y + hB[2]*C0[s].z + hB[3]*C0[s].w
                   + hB[4]*C1[s].x + hB[5]*C1[s].y + hB[6]*C1[s].z + hB[7]*C1[s].w;
                yA += __shfl_xor(yA, 1);
                yB += __shfl_xor(yB, 1);
                if (sub == 0) {
                    const float szA = __uint_as_float(qk[s].x << 16);
                    const float w2A = __uint_as_float(qk[s].x & 0xffff0000u);
                    const float szB = __uint_as_float(qk[s].y << 16);
                    const float w2B = __uint_as_float(qk[s].y & 0xffff0000u);
                    *(uint32_t*)(pU + (size_t)s * D_INNER) =
                        pack2bf(fmaf(yA, szA, w2A), fmaf(yB, szB, w2B));
                }
            }
            pD += 2 * 2048; pS += 2 * 2048; pU += 2 * D_INNER;
        }
    } else {
        for (int l0 = 0; l0 < CHUNKLEN; l0 += 2) {
            uint2 pk[2], qk[2]; float4 B0[2], B1[2], C0[2], C1[2];
#pragma unroll
            for (int s = 0; s < 2; ++s) {
                pk[s] = *(const uint2*)(pD + (size_t)s * 2048);
                B0[s] = *(const float4*)&BC[l0 + s][sub * 8];
                B1[s] = *(const float4*)&BC[l0 + s][sub * 8 + 4];
                C0[s] = *(const float4*)&BC[l0 + s][16 + sub * 8];
                C1[s] = *(const float4*)&BC[l0 + s][20 + sub * 8];
                if (sub == 0) qk[s] = *(const uint2*)(pS + (size_t)s * 2048);
            }
#pragma unroll
            for (int s = 0; s < 2; ++s) {
                const float dtA  = __uint_as_float(pk[s].x << 16);
                const float dtxA = __uint_as_float(pk[s].x & 0xffff0000u);
                const float dtB  = __uint_as_float(pk[s].y << 16);
                const float dtxB = __uint_as_float(pk[s].y & 0xffff0000u);
                const float Bv[8] = {B0[s].x, B0[s].y, B0[s].z, B0[s].w,
                                     B1[s].x, B1[s].y, B1[s].z, B1[s].w};
                const float Cv[8] = {C0[s].x, C0[s].y, C0[s].z, C0[s].w,
                                     C1[s].x, C1[s].y, C1[s].z, C1[s].w};
                float yA = 0.f, yB = 0.f;
#pragma unroll
                for (int i = 0; i < 8; ++i) {
                    hA[i] = fmaf(__builtin_amdgcn_exp2f(dtA * Ae0[i]), hA[i], dtxA * Bv[i]);
                    hB[i] = fmaf(__builtin_amdgcn_exp2f(dtB * Ae1[i]), hB[i], dtxB * Bv[i]);
                    yA = fmaf(hA[i], Cv[i], yA);
                    yB = fmaf(hB[i], Cv[i], yB);
                }
                yA += __shfl_xor(yA, 1);
                yB += __shfl_xor(yB, 1);
                if (sub == 0) {
                    const float szA = __uint_as_float(qk[s].x << 16);
                    const float w2A = __uint_as_float(qk[s].x & 0xffff0000u);
                    const float szB = __uint_as_float(qk[s].y << 16);
                    const float w2B = __uint_as_float(qk[s].y & 0xffff0000u);
                    *(uint32_t*)(pU + (size_t)s * D_INNER) =
                        pack2bf(fmaf(yA, szA, w2A), fmaf(yB, szB, w2B));
                }
            }
            pD += 2 * 2048; pS += 2 * 2048; pU += 2 * D_INNER;
        }
    }
}

// ---------- causal depthwise conv (k=4) + bias + SiLU, 2 channels/thread ----------
__global__ void kconv(const uint16_t* __restrict__ xzb, const float* __restrict__ cw,
                      const float* __restrict__ cb, float* __restrict__ xs) {
    const int T = blockIdx.x * 256 + threadIdx.x;   // over NROWS*1024
    const int d0 = (T & 1023) * 2;
    const int row = T >> 10;
    const int l = row & (SEQLEN - 1), b = row >> 11;
    const float4 wA = *(const float4*)&cw[d0 * 4];
    const float4 wB = *(const float4*)&cw[d0 * 4 + 4];
    const float2 bias = *(const float2*)&cb[d0];
    float a0 = bias.x, a1 = bias.y;
    const size_t base = (size_t)b * SEQLEN;
    if (l >= 3) {
        uint32_t v;
        v = *(const uint32_t*)&xzb[(base + l - 3) * 4096 + d0];
        a0 += wA.x * bf2f((uint16_t)v); a1 += wB.x * bf2f((uint16_t)(v >> 16));
        v = *(const uint32_t*)&xzb[(base + l - 2) * 4096 + d0];
        a0 += wA.y * bf2f((uint16_t)v); a1 += wB.y * bf2f((uint16_t)(v >> 16));
        v = *(const uint32_t*)&xzb[(base + l - 1) * 4096 + d0];
        a0 += wA.z * bf2f((uint16_t)v); a1 += wB.z * bf2f((uint16_t)(v >> 16));
        v = *(const uint32_t*)&xzb[(base + l    ) * 4096 + d0];
        a0 += wA.w * bf2f((uint16_t)v); a1 += wB.w * bf2f((uint16_t)(v >> 16));
    } else {
        uint32_t v;
        if (l >= 2) {
            v = *(const uint32_t*)&xzb[(base + l - 2) * 4096 + d0];
            a0 += wA.y * bf2f((uint16_t)v); a1 += wB.y * bf2f((uint16_t)(v >> 16));
        }
        if (l >= 1) {
            v = *(const uint32_t*)&xzb[(base + l - 1) * 4096 + d0];
            a0 += wA.z * bf2f((uint16_t)v); a1 += wB.z * bf2f((uint16_t)(v >> 16));
        }
        v = *(const uint32_t*)&xzb[(base + l) * 4096 + d0];
        a0 += wA.w * bf2f((uint16_t)v); a1 += wB.w * bf2f((uint16_t)(v >> 16));
    }
    *(float2*)&xs[(size_t)row * 2048 + d0] = make_float2(silu_f(a0), silu_f(a1));
}

extern "C" void kernel_launch(void* const* d_in, const int* in_sizes, int n_in,
                              void* d_out, int out_size, void* d_ws, size_t ws_size,
                              hipStream_t stream) {
    const float* x      = (const float*)d_in[0];
    const float* W_in   = (const float*)d_in[1];
    const float* conv_w = (const float*)d_in[2];
    const float* conv_b = (const float*)d_in[3];
    const float* W_x    = (const float*)d_in[4];
    const float* w_dt   = (const float*)d_in[5];
    const float* b_dt   = (const float*)d_in[6];
    const float* A_log  = (const float*)d_in[7];
    const float* Dp     = (const float*)d_in[8];
    const float* W_out  = (const float*)d_in[9];
    float* out = (float*)d_out;

    char* p = (char*)d_ws;
    uint16_t* xb  = (uint16_t*)p;  p += (size_t)NROWS * D_MODEL * 2;      // 8 MB (dead after gemm1)
    uint16_t* Wb  = (uint16_t*)p;  p += (size_t)4096 * 1024 * 2;          // 8 MB (dead after gemm1)
    uint16_t* Wob = (uint16_t*)p;  p += (size_t)1024 * 2048 * 2;          // 4 MB  (W_out^T)
    uint16_t* xzb = (uint16_t*)p;  p += (size_t)NROWS * 4096 * 2;         // 32 MB (bf16 xz)
    float* xs     = (float*)p;     p += (size_t)NROWS * D_INNER * 4;      // 32 MB (f32 xs, then dtdx pack)
    float* bcd    = (float*)p;     p += (size_t)NROWS * BCD_LD * 4;       // 576 KB
    float* sumdt  = (float*)p;     p += (size_t)NCHUNK * 4096 * 4;        // 1 MB
    float* Wxt    = (float*)p;     p += (size_t)64 * 2048 * 4;            // 512 KB
    uint16_t* ub  = (uint16_t*)p;  p += (size_t)NROWS * D_INNER * 2;      // 16 MB
    uint32_t* szw = (uint32_t*)p;  p += (size_t)NROWS * D_INNER * 4;      // 32 MB (silu(z) pack)
    // overlays (regions dead during their use):
    float* hbuf   = (float*)xb;        // 16 MB = xb+Wb (dead after gemm1)
    float* part   = (float*)ub;        // 12.6 MB (ub written only by kscan3, later)
    uint32_t* dtdx = (uint32_t*)xs;    // packed (dt, dt*x), in-place over xs after kprep

    // 1) dtype prep
    kcvt<<<(NROWS * D_MODEL / 4 + 255) / 256, 256, 0, stream>>>(x, xb, NROWS * D_MODEL / 4);
    ktrans<<<dim3(4096 / 32, 1024 / 32), 256, 0, stream>>>(W_in, Wb, 1024, 4096);
    ktrans<<<dim3(1024 / 32, 2048 / 32), 256, 0, stream>>>(W_out, Wob, 2048, 1024);
    kwxt<<<(64 * 2048) / 256, 256, 0, stream>>>(W_x, Wxt);
    // 2) xz = x @ W_in   (M=4096, N=4096, K=1024), bf16 out, 256x128 dbuf
    kgemm256<1024, 5><<<dim3(32, 16), 512, 0, stream>>>(xb, Wb, xzb, 4096);
    // 3) conv + silu (bf16 in, f32 out), 2 ch/thread
    kconv<<<NROWS * 1024 / 256, 256, 0, stream>>>(xzb, conv_w, conv_b, xs);
    // 4) bcd = xs @ W_x  (MFMA, K-split 16 + reduce)
    kgemm2m<<<dim3(KS2, 32), 256, 0, stream>>>(xs, Wxt, part);
    kred2<<<(4096 * 48 + 255) / 256, 256, 0, stream>>>(part, bcd);
    // 5) pack scan operands (dtdx in-place over xs, szw separate)
    kprep<<<(4096 * 512) / 256, 256, 0, stream>>>(bcd, w_dt, b_dt, Dp, xs, xzb, szw);
    // 6) selective scan (3 phases), 2 ch/thread, LDS-staged bcd
    kscan1<<<(4096 * NCHUNK) / 256, 256, 0, stream>>>(dtdx, bcd, A_log, hbuf, sumdt);
    kscan2<<<(4096 * 16) / 256, 256, 0, stream>>>(hbuf, sumdt, A_log);
    kscan3<<<(4096 * NCHUNK) / 256, 256, 0, stream>>>(dtdx, bcd, A_log, szw, hbuf, ub);
    // 7) out = u @ W_out (M=4096, N=1024, K=2048), dbuf
    kgemm64<2048, 3><<<dim3(1024 / 128, 4096 / 64), 256, 0, stream>>>(ub, Wob, out, 1024);
}

// Round 10
// 214.727 us; speedup vs baseline: 2.5017x; 1.0307x over previous
//
#include <hip/hip_runtime.h>
#include <hip/hip_bf16.h>
#include <stdint.h>

#define D_MODEL 1024
#define D_STATE 16
#define D_CONV  4
#define D_INNER 2048
#define BATCH   2
#define SEQLEN  2048
#define NROWS   (BATCH*SEQLEN)     // 4096
#define BCD_LD  36                 // padded leading dim for bcd (33 used)
#define NCHUNK  64
#define CHUNKLEN (SEQLEN/NCHUNK)   // 32
#define KS2     16                 // K-splits for GEMM2 (chunk = 128)
#define L2E 1.44269504088896340f

typedef __attribute__((ext_vector_type(8))) short   short8;
typedef __attribute__((ext_vector_type(4))) float   f32x4;

__device__ __forceinline__ uint16_t f2bf(float f) {        // RNE f32->bf16
    uint32_t u = __float_as_uint(f);
    return (uint16_t)((u + 0x7FFFu + ((u >> 16) & 1u)) >> 16);
}
__device__ __forceinline__ float bf2f(uint16_t h) {
    return __uint_as_float(((uint32_t)h) << 16);
}
__device__ __forceinline__ uint32_t pack2bf(float lo, float hi) {
    return (uint32_t)f2bf(lo) | ((uint32_t)f2bf(hi) << 16);
}
__device__ __forceinline__ void gload16(const uint16_t* g, uint16_t* l) {
    __builtin_amdgcn_global_load_lds(
        (const __attribute__((address_space(1))) void*)g,
        (__attribute__((address_space(3))) void*)l, 16, 0, 0);
}
__device__ __forceinline__ void gload16f(const float* g, float* l) {
    __builtin_amdgcn_global_load_lds(
        (const __attribute__((address_space(1))) void*)g,
        (__attribute__((address_space(3))) void*)l, 16, 0, 0);
}
__device__ __forceinline__ float softplus_f(float v) {
    return fmaxf(v, 0.f) + __logf(1.f + __expf(-fabsf(v)));
}
__device__ __forceinline__ float silu_f(float v) {
    return v / (1.f + __expf(-v));
}
__device__ __forceinline__ short8 pack8(const float4 lo, const float4 hi) {
    short8 r;
    r[0] = (short)f2bf(lo.x); r[1] = (short)f2bf(lo.y);
    r[2] = (short)f2bf(lo.z); r[3] = (short)f2bf(lo.w);
    r[4] = (short)f2bf(hi.x); r[5] = (short)f2bf(hi.y);
    r[6] = (short)f2bf(hi.z); r[7] = (short)f2bf(hi.w);
    return r;
}

// ---------- fused input prep: kcvt | ktrans(W_in) | ktrans(W_out) | kwxt ----------
// linear grid sections: [0,4096) cvt, [4096,8192) trans Win, [8192,10240) trans Wout,
// [10240,10752) wxt
__global__ void kprep0(const float* __restrict__ x, uint16_t* __restrict__ xb,
                       const float* __restrict__ W_in, uint16_t* __restrict__ Wb,
                       const float* __restrict__ W_out, uint16_t* __restrict__ Wob,
                       const float* __restrict__ Wx, float* __restrict__ Wxt) {
    __shared__ float tile[32][33];
    const int blk = blockIdx.x;
    const int tid = threadIdx.x;
    if (blk < 4096) {                          // ---- cvt x -> bf16 (1M float4s)
        const int T = blk * 256 + tid;
        const float4 v = *(const float4*)&x[(size_t)T * 4];
        ushort4 o;
        o.x = f2bf(v.x); o.y = f2bf(v.y); o.z = f2bf(v.z); o.w = f2bf(v.w);
        *(ushort4*)&xb[(size_t)T * 4] = o;
    } else if (blk < 8192) {                   // ---- W_in [1024][4096] -> Wb [4096][1024]
        const int bb = blk - 4096;
        const int n0 = (bb & 127) * 32, k0 = (bb >> 7) * 32;
        const int tx = tid & 31, ty = tid >> 5;
#pragma unroll
        for (int i = 0; i < 4; ++i)
            tile[ty + i * 8][tx] = W_in[(size_t)(k0 + ty + i * 8) * 4096 + n0 + tx];
        __syncthreads();
#pragma unroll
        for (int i = 0; i < 4; ++i)
            Wb[(size_t)(n0 + ty + i * 8) * 1024 + k0 + tx] = f2bf(tile[tx][ty + i * 8]);
    } else if (blk < 10240) {                  // ---- W_out [2048][1024] -> Wob [1024][2048]
        const int bb = blk - 8192;
        const int n0 = (bb & 31) * 32, k0 = (bb >> 5) * 32;
        const int tx = tid & 31, ty = tid >> 5;
#pragma unroll
        for (int i = 0; i < 4; ++i)
            tile[ty + i * 8][tx] = W_out[(size_t)(k0 + ty + i * 8) * 1024 + n0 + tx];
        __syncthreads();
#pragma unroll
        for (int i = 0; i < 4; ++i)
            Wob[(size_t)(n0 + ty + i * 8) * 2048 + k0 + tx] = f2bf(tile[tx][ty + i * 8]);
    } else {                                   // ---- Wxt[64][2048] = W_x^T zero-padded
        const int T = (blk - 10240) * 256 + tid;
        const int j = T >> 11, k = T & 2047;
        Wxt[T] = (j < 33) ? Wx[(size_t)k * 33 + j] : 0.f;
    }
}

// ---------- GEMM1: 256x128 tile, 512 thr, 2-phase dbuf, bf16 C (XCD-swizzled) ----------
template<int KDIM, int GXL>
__global__ __launch_bounds__(512) void kgemm256(const uint16_t* __restrict__ A,
                                                const uint16_t* __restrict__ B,
                                                uint16_t* __restrict__ C, const int ldc) {
    __shared__ uint16_t As[2][256 * 32];   // 2 x 16 KB
    __shared__ uint16_t Bsh[2][128 * 32];  // 2 x 8 KB
    const int t = threadIdx.x;          // 0..511
    const int w = t >> 6, lane = t & 63;
    int wg = blockIdx.y * (1 << GXL) + blockIdx.x;
    wg = (wg & 7) * ((gridDim.x * gridDim.y) >> 3) + (wg >> 3);   // bijective XCD swizzle
    const int m0 = (wg >> GXL) * 256, n0 = (wg & ((1 << GXL) - 1)) * 128;
    const int wm = (w >> 1) * 64, wn = (w & 1) * 64;
    f32x4 acc[4][4] = {};

    const int srow = t >> 2;                              // 0..127
    const int scol = ((t & 3) ^ ((t >> 3) & 3)) * 8;      // pre-swizzled source slot
    const uint16_t* ga0 = A + (size_t)(m0 + srow) * KDIM + scol;
    const uint16_t* ga1 = A + (size_t)(m0 + 128 + srow) * KDIM + scol;
    const uint16_t* gb0 = B + (size_t)(n0 + srow) * KDIM + scol;

    const int fr = lane & 15, fg = (lane >> 4) * 8;
    const int psl = (((fg >> 3) ^ ((fr >> 1) & 3)) << 3);

    auto stage = [&](int buf, int ko) {
        gload16(ga0 + ko, &As[buf][w * 512]);
        gload16(ga1 + ko, &As[buf][4096 + w * 512]);
        gload16(gb0 + ko, &Bsh[buf][w * 512]);
    };

    stage(0, 0);
    __syncthreads();
    int cur = 0;
    for (int kt = 0; kt < KDIM / 32; ++kt) {
        if (kt + 1 < KDIM / 32) stage(cur ^ 1, (kt + 1) * 32);   // prefetch next tile
        short8 a[4], b[4];
#pragma unroll
        for (int i = 0; i < 4; ++i) {
            a[i] = *(const short8*)&As[cur][(wm + i * 16 + fr) * 32 + psl];
            b[i] = *(const short8*)&Bsh[cur][(wn + i * 16 + fr) * 32 + psl];
        }
#pragma unroll
        for (int i = 0; i < 4; ++i)
#pragma unroll
            for (int j = 0; j < 4; ++j)
                acc[i][j] = __builtin_amdgcn_mfma_f32_16x16x32_bf16(a[i], b[j], acc[i][j], 0, 0, 0);
        __syncthreads();
        cur ^= 1;
    }
    const int cr = (lane >> 4) * 4, cc = lane & 15;
#pragma unroll
    for (int i = 0; i < 4; ++i)
#pragma unroll
        for (int j = 0; j < 4; ++j)
#pragma unroll
            for (int r = 0; r < 4; ++r)
                C[(size_t)(m0 + wm + i * 16 + cr + r) * ldc + (n0 + wn + j * 16 + cc)] =
                    f2bf(acc[i][j][r]);
}

// ---------- GEMM3: 64x128 tile, 2-phase dbuf, f32 C (XCD-swizzled) ----------
template<int KDIM, int GXL>
__global__ __launch_bounds__(256) void kgemm64(const uint16_t* __restrict__ A,
                                               const uint16_t* __restrict__ B,
                                               float* __restrict__ C, const int ldc) {
    __shared__ uint16_t As[2][64 * 32];      // 2 x 4 KB
    __shared__ uint16_t Bsh[2][128 * 32];    // 2 x 8 KB
    const int t = threadIdx.x;
    const int w = t >> 6, lane = t & 63;
    int wg = blockIdx.y * (1 << GXL) + blockIdx.x;
    wg = (wg & 7) * ((gridDim.x * gridDim.y) >> 3) + (wg >> 3);
    const int m0 = (wg >> GXL) * 64, n0 = (wg & ((1 << GXL) - 1)) * 128;
    const int wm = (w >> 1) * 32, wn = (w & 1) * 64;
    f32x4 acc[2][4] = {};

    const int srow = t >> 2;
    const int scol = ((t & 3) ^ ((t >> 3) & 3)) * 8;
    const uint16_t* ga0 = A + (size_t)(m0 + srow) * KDIM + scol;
    const uint16_t* gb0 = B + (size_t)(n0 + srow) * KDIM + scol;
    const uint16_t* gb1 = B + (size_t)(n0 + 64 + srow) * KDIM + scol;

    const int fr = lane & 15, fg = (lane >> 4) * 8;
    const int psl = (((fg >> 3) ^ ((fr >> 1) & 3)) << 3);

    auto stage = [&](int buf, int ko) {
        gload16(ga0 + ko, &As[buf][w * 512]);
        gload16(gb0 + ko, &Bsh[buf][w * 512]);
        gload16(gb1 + ko, &Bsh[buf][2048 + w * 512]);
    };

    stage(0, 0);
    __syncthreads();
    int cur = 0;
    for (int kt = 0; kt < KDIM / 32; ++kt) {
        if (kt + 1 < KDIM / 32) stage(cur ^ 1, (kt + 1) * 32);
        short8 a[2], b[4];
#pragma unroll
        for (int i = 0; i < 2; ++i)
            a[i] = *(const short8*)&As[cur][(wm + i * 16 + fr) * 32 + psl];
#pragma unroll
        for (int j = 0; j < 4; ++j)
            b[j] = *(const short8*)&Bsh[cur][(wn + j * 16 + fr) * 32 + psl];
#pragma unroll
        for (int i = 0; i < 2; ++i)
#pragma unroll
            for (int j = 0; j < 4; ++j)
                acc[i][j] = __builtin_amdgcn_mfma_f32_16x16x32_bf16(a[i], b[j], acc[i][j], 0, 0, 0);
        __syncthreads();
        cur ^= 1;
    }
    const int cr = (lane >> 4) * 4, cc = lane & 15;
#pragma unroll
    for (int i = 0; i < 2; ++i)
#pragma unroll
        for (int j = 0; j < 4; ++j)
#pragma unroll
            for (int r = 0; r < 4; ++r)
                C[(size_t)(m0 + wm + i * 16 + cr + r) * ldc + (n0 + wn + j * 16 + cc)] = acc[i][j][r];
}

// ---------- GEMM2 MFMA K-split: part[kb][4096][48] = xs(chunk) @ Wxt^T ----------
__global__ __launch_bounds__(256) void kgemm2m(const float* __restrict__ xs,
        const float* __restrict__ Wxt, float* __restrict__ part) {
    __shared__ float As[128 * 32];   // 16 KB
    __shared__ float Bs[64 * 32];    // 8 KB
    const int t = threadIdx.x;
    const int w = t >> 6, lane = t & 63;
    const int kb = blockIdx.x;              // 0..15
    const int m0 = blockIdx.y * 128;
    const int kc = kb * 128;
    f32x4 acc[2][3] = {};

    const int srow = t >> 3;                            // 0..31
    const int scol = ((t & 7) ^ ((t >> 3) & 7)) * 4;    // pre-swizzled source (floats)
    float* lA[4]; float* lB[2];
#pragma unroll
    for (int r = 0; r < 4; ++r) lA[r] = &As[(r * 32 + w * 8) * 32];
#pragma unroll
    for (int r = 0; r < 2; ++r) lB[r] = &Bs[(r * 32 + w * 8) * 32];

    const int wm = w * 32;
    const int fr = lane & 15, fg = (lane >> 4) * 8;
    const int plo = (((fg >> 2) ^ (fr & 7))) * 4;
    const int phi = ((((fg >> 2) + 1) ^ (fr & 7))) * 4;

    for (int kt = 0; kt < 4; ++kt) {
        const int ko = kc + kt * 32;
#pragma unroll
        for (int r = 0; r < 4; ++r)
            gload16f(xs + (size_t)(m0 + r * 32 + srow) * 2048 + ko + scol, lA[r]);
#pragma unroll
        for (int r = 0; r < 2; ++r)
            gload16f(Wxt + (size_t)(r * 32 + srow) * 2048 + ko + scol, lB[r]);
        __syncthreads();
        short8 a[2], b[3];
#pragma unroll
        for (int i = 0; i < 2; ++i) {
            const float* base = &As[(wm + i * 16 + fr) * 32];
            a[i] = pack8(*(const float4*)&base[plo], *(const float4*)&base[phi]);
        }
#pragma unroll
        for (int j = 0; j < 3; ++j) {
            const float* base = &Bs[(j * 16 + fr) * 32];
            b[j] = pack8(*(const float4*)&base[plo], *(const float4*)&base[phi]);
        }
#pragma unroll
        for (int i = 0; i < 2; ++i)
#pragma unroll
            for (int j = 0; j < 3; ++j)
                acc[i][j] = __builtin_amdgcn_mfma_f32_16x16x32_bf16(a[i], b[j], acc[i][j], 0, 0, 0);
        __syncthreads();
    }
    const int cr = (lane >> 4) * 4, cc = lane & 15;
    float* pb = part + (size_t)kb * 4096 * 48;
#pragma unroll
    for (int i = 0; i < 2; ++i)
#pragma unroll
        for (int j = 0; j < 3; ++j)
#pragma unroll
            for (int r = 0; r < 4; ++r)
                pb[(size_t)(m0 + wm + i * 16 + cr + r) * 48 + j * 16 + cc] = acc[i][j][r];
}

// ---------- fused: reduce K-split partials -> bcd row, then pack scan operands ----------
// one block per row (256 thr). Phase A: t<33 sums 16 partials; Phase B: 8 ch/thread packs.
__global__ __launch_bounds__(256) void kredprep(const float* __restrict__ part,
        const float* __restrict__ wdt, const float* __restrict__ bdt,
        const float* __restrict__ Dp, float* __restrict__ xs_io,
        const uint16_t* __restrict__ xzb, uint32_t* __restrict__ szw,
        float* __restrict__ bcd) {
    const int row = blockIdx.x;
    const int t = threadIdx.x;
    __shared__ float rawsh;
    if (t < 33) {
        float s = 0.f;
#pragma unroll
        for (int ks = 0; ks < KS2; ++ks)
            s += part[(size_t)ks * 4096 * 48 + (size_t)row * 48 + t];
        bcd[(size_t)row * BCD_LD + t] = s;
        if (t == 32) rawsh = s;
    }
    __syncthreads();
    const float raw = rawsh;
#pragma unroll
    for (int g = 0; g < 2; ++g) {
        const int dg = t * 8 + g * 4;
        const float4 w  = *(const float4*)&wdt[dg];
        const float4 b  = *(const float4*)&bdt[dg];
        const float4 Dv = *(const float4*)&Dp[dg];
        const float4 xv = *(const float4*)&xs_io[(size_t)row * 2048 + dg];
        const ushort4 zu = *(const ushort4*)&xzb[(size_t)row * 4096 + 2048 + dg];
        const float dt0 = softplus_f(raw * w.x + b.x);
        const float dt1 = softplus_f(raw * w.y + b.y);
        const float dt2 = softplus_f(raw * w.z + b.z);
        const float dt3 = softplus_f(raw * w.w + b.w);
        float4 pd;
        pd.x = __uint_as_float(pack2bf(dt0, dt0 * xv.x));
        pd.y = __uint_as_float(pack2bf(dt1, dt1 * xv.y));
        pd.z = __uint_as_float(pack2bf(dt2, dt2 * xv.z));
        pd.w = __uint_as_float(pack2bf(dt3, dt3 * xv.w));
        const float s0 = silu_f(bf2f(zu.x)), s1 = silu_f(bf2f(zu.y));
        const float s2 = silu_f(bf2f(zu.z)), s3 = silu_f(bf2f(zu.w));
        uint4 ps;
        ps.x = pack2bf(s0, xv.x * Dv.x * s0);
        ps.y = pack2bf(s1, xv.y * Dv.y * s1);
        ps.z = pack2bf(s2, xv.z * Dv.z * s2);
        ps.w = pack2bf(s3, xv.w * Dv.w * s3);
        *(float4*)&xs_io[(size_t)row * 2048 + dg] = pd;
        *(uint4*)&szw[(size_t)row * 2048 + dg] = ps;
    }
}

// ---------- scan phase 1: 2 ch/thread, bcd B in LDS, 4-deep global batching ----------
__global__ __launch_bounds__(256) void kscan1(const uint32_t* __restrict__ dtdx,
        const float* __restrict__ bcd, const float* __restrict__ Alog,
        float* __restrict__ hbuf, float* __restrict__ sumdt) {
    const int T = blockIdx.x * 256 + threadIdx.x;
    const int sub = T & 1;
    const int cp  = (T >> 1) & 2047;
    const int chunk = T >> 12;
    const int b = cp >> 10, d0 = (cp & 1023) * 2;
    const int row0 = b * SEQLEN + chunk * CHUNKLEN;    // same for whole block

    __shared__ float Bls[32][16];       // B part (cols 0..15) of the 32 chunk rows
    {
        const int r = threadIdx.x >> 3, c = (threadIdx.x & 7) * 2;
        const float2 v = *(const float2*)&bcd[(size_t)(row0 + r) * BCD_LD + c];
        Bls[r][c] = v.x; Bls[r][c + 1] = v.y;
    }
    __syncthreads();

    float Ae0[8], Ae1[8]; bool st = true;
#pragma unroll
    for (int i = 0; i < 8; ++i) {
        const float a0 = __expf(Alog[d0 * 16 + sub * 8 + i]);
        const float a1 = __expf(Alog[(d0 + 1) * 16 + sub * 8 + i]);
        Ae0[i] = -a0 * L2E; Ae1[i] = -a1 * L2E;
        st = st && (fabsf(a0 - (float)(sub * 8 + i + 1)) < 1e-3f)
                && (fabsf(a1 - (float)(sub * 8 + i + 1)) < 1e-3f);
    }
    float hA[8] = {}, hB[8] = {};
    float sdtA = 0.f, sdtB = 0.f;
    const uint32_t* pD = dtdx + (size_t)row0 * 2048 + d0;
    if (st) {
        for (int l0 = 0; l0 < CHUNKLEN; l0 += 4) {
            uint2 pk[4];
#pragma unroll
            for (int s = 0; s < 4; ++s) pk[s] = *(const uint2*)(pD + (size_t)s * 2048);
#pragma unroll
            for (int s = 0; s < 4; ++s) {
                const float4 B0 = *(const float4*)&Bls[l0 + s][sub * 8];
                const float4 B1 = *(const float4*)&Bls[l0 + s][sub * 8 + 4];
                const float dtA  = __uint_as_float(pk[s].x << 16);
                const float dtxA = __uint_as_float(pk[s].x & 0xffff0000u);
                const float dtB  = __uint_as_float(pk[s].y << 16);
                const float dtxB = __uint_as_float(pk[s].y & 0xffff0000u);
                sdtA += dtA; sdtB += dtB;
                const float e0A = __builtin_amdgcn_exp2f(dtA * (-L2E));
                const float e0B = __builtin_amdgcn_exp2f(dtB * (-L2E));
                const float e8A = (e0A*e0A)*(e0A*e0A)*(e0A*e0A)*(e0A*e0A);
                const float e8B = (e0B*e0B)*(e0B*e0B)*(e0B*e0B)*(e0B*e0B);
                float dA = sub ? e8A : 1.f, dB = sub ? e8B : 1.f;
                dA *= e0A; dB *= e0B; hA[0] = fmaf(dA, hA[0], dtxA * B0.x); hB[0] = fmaf(dB, hB[0], dtxB * B0.x);
                dA *= e0A; dB *= e0B; hA[1] = fmaf(dA, hA[1], dtxA * B0.y); hB[1] = fmaf(dB, hB[1], dtxB * B0.y);
                dA *= e0A; dB *= e0B; hA[2] = fmaf(dA, hA[2], dtxA * B0.z); hB[2] = fmaf(dB, hB[2], dtxB * B0.z);
                dA *= e0A; dB *= e0B; hA[3] = fmaf(dA, hA[3], dtxA * B0.w); hB[3] = fmaf(dB, hB[3], dtxB * B0.w);
                dA *= e0A; dB *= e0B; hA[4] = fmaf(dA, hA[4], dtxA * B1.x); hB[4] = fmaf(dB, hB[4], dtxB * B1.x);
                dA *= e0A; dB *= e0B; hA[5] = fmaf(dA, hA[5], dtxA * B1.y); hB[5] = fmaf(dB, hB[5], dtxB * B1.y);
                dA *= e0A; dB *= e0B; hA[6] = fmaf(dA, hA[6], dtxA * B1.z); hB[6] = fmaf(dB, hB[6], dtxB * B1.z);
                dA *= e0A; dB *= e0B; hA[7] = fmaf(dA, hA[7], dtxA * B1.w); hB[7] = fmaf(dB, hB[7], dtxB * B1.w);
            }
            pD += 4 * 2048;
        }
    } else {
        for (int l0 = 0; l0 < CHUNKLEN; l0 += 4) {
            uint2 pk[4];
#pragma unroll
            for (int s = 0; s < 4; ++s) pk[s] = *(const uint2*)(pD + (size_t)s * 2048);
#pragma unroll
            for (int s = 0; s < 4; ++s) {
                const float4 B0 = *(const float4*)&Bls[l0 + s][sub * 8];
                const float4 B1 = *(const float4*)&Bls[l0 + s][sub * 8 + 4];
                const float dtA  = __uint_as_float(pk[s].x << 16);
                const float dtxA = __uint_as_float(pk[s].x & 0xffff0000u);
                const float dtB  = __uint_as_float(pk[s].y << 16);
                const float dtxB = __uint_as_float(pk[s].y & 0xffff0000u);
                sdtA += dtA; sdtB += dtB;
                const float Bv[8] = {B0.x, B0.y, B0.z, B0.w, B1.x, B1.y, B1.z, B1.w};
#pragma unroll
                for (int i = 0; i < 8; ++i) {
                    hA[i] = fmaf(__builtin_amdgcn_exp2f(dtA * Ae0[i]), hA[i], dtxA * Bv[i]);
                    hB[i] = fmaf(__builtin_amdgcn_exp2f(dtB * Ae1[i]), hB[i], dtxB * Bv[i]);
                }
            }
            pD += 4 * 2048;
        }
    }
    const size_t cc0 = (size_t)(chunk * 4096 + b * 2048 + d0) * 16 + sub * 8;
    *(float4*)&hbuf[cc0]          = make_float4(hA[0], hA[1], hA[2], hA[3]);
    *(float4*)&hbuf[cc0 + 4]      = make_float4(hA[4], hA[5], hA[6], hA[7]);
    *(float4*)&hbuf[cc0 + 16]     = make_float4(hB[0], hB[1], hB[2], hB[3]);
    *(float4*)&hbuf[cc0 + 20]     = make_float4(hB[4], hB[5], hB[6], hB[7]);
    if (sub == 0)
        *(float2*)&sumdt[chunk * 4096 + b * 2048 + d0] = make_float2(sdtA, sdtB);
}

// ---------- scan phase 2: chunk combine (in-place carries), next-iter prefetch ----------
__global__ void kscan2(float* __restrict__ hbuf, const float* __restrict__ sumdt,
                       const float* __restrict__ Alog) {
    const int T = blockIdx.x * 256 + threadIdx.x;   // 65536
    const int n = T & 15, ch = T >> 4;
    const int d = ch & 2047;
    const float Ae = -__expf(Alog[d * 16 + n]) * L2E;
    float h = 0.f;
    size_t idx = (size_t)ch * 16 + n;
    float loc = hbuf[idx];
    float sd  = sumdt[ch];
    for (int c = 0; c < NCHUNK; ++c) {
        float locN = 0.f, sdN = 0.f;
        const size_t idxN = idx + (size_t)4096 * 16;
        if (c + 1 < NCHUNK) {                 // prefetch next chunk's inputs
            locN = hbuf[idxN];
            sdN  = sumdt[(size_t)(c + 1) * 4096 + ch];
        }
        hbuf[idx] = h;                         // carry (h at chunk start)
        h = __builtin_amdgcn_exp2f(Ae * sd) * h + loc;
        loc = locN; sd = sdN; idx = idxN;
    }
}

// ---------- scan phase 3: 2 ch/thread, bcd B+C in LDS, 4-deep batching ----------
__global__ __launch_bounds__(256) void kscan3(const uint32_t* __restrict__ dtdx,
        const float* __restrict__ bcd, const float* __restrict__ Alog,
        const uint32_t* __restrict__ szw, const float* __restrict__ hbuf,
        uint16_t* __restrict__ u) {
    const int T = blockIdx.x * 256 + threadIdx.x;
    const int sub = T & 1;
    const int cp  = (T >> 1) & 2047;
    const int chunk = T >> 12;
    const int b = cp >> 10, d0 = (cp & 1023) * 2;
    const int row0 = b * SEQLEN + chunk * CHUNKLEN;    // same for whole block

    __shared__ float BC[32][32];        // B (0..15) + C (16..31) of the 32 chunk rows
    {
        const int r = threadIdx.x >> 3, c = (threadIdx.x & 7) * 4;
        *(float4*)&BC[r][c] = *(const float4*)&bcd[(size_t)(row0 + r) * BCD_LD + c];
    }
    __syncthreads();

    float Ae0[8], Ae1[8]; bool st = true;
#pragma unroll
    for (int i = 0; i < 8; ++i) {
        const float a0 = __expf(Alog[d0 * 16 + sub * 8 + i]);
        const float a1 = __expf(Alog[(d0 + 1) * 16 + sub * 8 + i]);
        Ae0[i] = -a0 * L2E; Ae1[i] = -a1 * L2E;
        st = st && (fabsf(a0 - (float)(sub * 8 + i + 1)) < 1e-3f)
                && (fabsf(a1 - (float)(sub * 8 + i + 1)) < 1e-3f);
    }
    float hA[8], hB[8];
    {
        const size_t cc0 = (size_t)(chunk * 4096 + b * 2048 + d0) * 16 + sub * 8;
        const float4 a0 = *(const float4*)&hbuf[cc0];
        const float4 a1 = *(const float4*)&hbuf[cc0 + 4];
        const float4 b0 = *(const float4*)&hbuf[cc0 + 16];
        const float4 b1 = *(const float4*)&hbuf[cc0 + 20];
        hA[0]=a0.x; hA[1]=a0.y; hA[2]=a0.z; hA[3]=a0.w;
        hA[4]=a1.x; hA[5]=a1.y; hA[6]=a1.z; hA[7]=a1.w;
        hB[0]=b0.x; hB[1]=b0.y; hB[2]=b0.z; hB[3]=b0.w;
        hB[4]=b1.x; hB[5]=b1.y; hB[6]=b1.z; hB[7]=b1.w;
    }
    const uint32_t* pD = dtdx + (size_t)row0 * 2048 + d0;
    const uint32_t* pS = szw  + (size_t)row0 * 2048 + d0;   // only sub==0 reads
    uint16_t* pU = u + (size_t)row0 * D_INNER + d0;
    if (st) {
        for (int l0 = 0; l0 < CHUNKLEN; l0 += 4) {
            uint2 pk[4], qk[4];
#pragma unroll
            for (int s = 0; s < 4; ++s) {
                pk[s] = *(const uint2*)(pD + (size_t)s * 2048);
                if (sub == 0) qk[s] = *(const uint2*)(pS + (size_t)s * 2048);
            }
#pragma unroll
            for (int s = 0; s < 4; ++s) {
                const float4 B0 = *(const float4*)&BC[l0 + s][sub * 8];
                const float4 B1 = *(const float4*)&BC[l0 + s][sub * 8 + 4];
                const float4 C0 = *(const float4*)&BC[l0 + s][16 + sub * 8];
                const float4 C1 = *(const float4*)&BC[l0 + s][20 + sub * 8];
                const float dtA  = __uint_as_float(pk[s].x << 16);
                const float dtxA = __uint_as_float(pk[s].x & 0xffff0000u);
                const float dtB  = __uint_as_float(pk[s].y << 16);
                const float dtxB = __uint_as_float(pk[s].y & 0xffff0000u);
                const float e0A = __builtin_amdgcn_exp2f(dtA * (-L2E));
                const float e0B = __builtin_amdgcn_exp2f(dtB * (-L2E));
                const float e8A = (e0A*e0A)*(e0A*e0A)*(e0A*e0A)*(e0A*e0A);
                const float e8B = (e0B*e0B)*(e0B*e0B)*(e0B*e0B)*(e0B*e0B);
                float dA = sub ? e8A : 1.f, dB = sub ? e8B : 1.f;
                float yA, yB;
                dA *= e0A; dB *= e0B; hA[0] = fmaf(dA, hA[0], dtxA * B0.x); hB[0] = fmaf(dB, hB[0], dtxB * B0.x);
                dA *= e0A; dB *= e0B; hA[1] = fmaf(dA, hA[1], dtxA * B0.y); hB[1] = fmaf(dB, hB[1], dtxB * B0.y);
                dA *= e0A; dB *= e0B; hA[2] = fmaf(dA, hA[2], dtxA * B0.z); hB[2] = fmaf(dB, hB[2], dtxB * B0.z);
                dA *= e0A; dB *= e0B; hA[3] = fmaf(dA, hA[3], dtxA * B0.w); hB[3] = fmaf(dB, hB[3], dtxB * B0.w);
                dA *= e0A; dB *= e0B; hA[4] = fmaf(dA, hA[4], dtxA * B1.x); hB[4] = fmaf(dB, hB[4], dtxB * B1.x);
                dA *= e0A; dB *= e0B; hA[5] = fmaf(dA, hA[5], dtxA * B1.y); hB[5] = fmaf(dB, hB[5], dtxB * B1.y);
                dA *= e0A; dB *= e0B; hA[6] = fmaf(dA, hA[6], dtxA * B1.z); hB[6] = fmaf(dB, hB[6], dtxB * B1.z);
                dA *= e0A; dB *= e0B; hA[7] = fmaf(dA, hA[7], dtxA * B1.w); hB[7] = fmaf(dB, hB[7], dtxB * B1.w);
                yA = hA[0]*C0.x + hA[1]*C0.y + hA[2]*C0.z + hA[3]*C0.w
                   + hA[4]*C1.x + hA[5]*C1.y + hA[6]*C1.z + hA[7]*C1.w;
                yB = hB[0]*C0.x + hB[1]*C0.y + hB[2]*C0.z + hB[3]*C0.w
                   + hB[4]*C1.x + hB[5]*C1.y + hB[6]*C1.z + hB[7]*C1.w;
                yA += __shfl_xor(yA, 1);
                yB += __shfl_xor(yB, 1);
                if (sub == 0) {
                    const float szA = __uint_as_float(qk[s].x << 16);
                    const float w2A = __uint_as_float(qk[s].x & 0xffff0000u);
                    const float szB = __uint_as_float(qk[s].y << 16);
                    const float w2B = __uint_as_float(qk[s].y & 0xffff0000u);
                    *(uint32_t*)(pU + (size_t)s * D_INNER) =
                        pack2bf(fmaf(yA, szA, w2A), fmaf(yB, szB, w2B));
                }
            }
            pD += 4 * 2048; pS += 4 * 2048; pU += 4 * D_INNER;
        }
    } else {
        for (int l0 = 0; l0 < CHUNKLEN; l0 += 4) {
            uint2 pk[4], qk[4];
#pragma unroll
            for (int s = 0; s < 4; ++s) {
                pk[s] = *(const uint2*)(pD + (size_t)s * 2048);
                if (sub == 0) qk[s] = *(const uint2*)(pS + (size_t)s * 2048);
            }
#pragma unroll
            for (int s = 0; s < 4; ++s) {
                const float4 B0 = *(const float4*)&BC[l0 + s][sub * 8];
                const float4 B1 = *(const float4*)&BC[l0 + s][sub * 8 + 4];
                const float4 C0 = *(const float4*)&BC[l0 + s][16 + sub * 8];
                const float4 C1 = *(const float4*)&BC[l0 + s][20 + sub * 8];
                const float dtA  = __uint_as_float(pk[s].x << 16);
                const float dtxA = __uint_as_float(pk[s].x & 0xffff0000u);
                const float dtB  = __uint_as_float(pk[s].y << 16);
                const float dtxB = __uint_as_float(pk[s].y & 0xffff0000u);
                const float Bv[8] = {B0.x, B0.y, B0.z, B0.w, B1.x, B1.y, B1.z, B1.w};
                const float Cv[8] = {C0.x, C0.y, C0.z, C0.w, C1.x, C1.y, C1.z, C1.w};
                float yA = 0.f, yB = 0.f;
#pragma unroll
                for (int i = 0; i < 8; ++i) {
                    hA[i] = fmaf(__builtin_amdgcn_exp2f(dtA * Ae0[i]), hA[i], dtxA * Bv[i]);
                    hB[i] = fmaf(__builtin_amdgcn_exp2f(dtB * Ae1[i]), hB[i], dtxB * Bv[i]);
                    yA = fmaf(hA[i], Cv[i], yA);
                    yB = fmaf(hB[i], Cv[i], yB);
                }
                yA += __shfl_xor(yA, 1);
                yB += __shfl_xor(yB, 1);
                if (sub == 0) {
                    const float szA = __uint_as_float(qk[s].x << 16);
                    const float w2A = __uint_as_float(qk[s].x & 0xffff0000u);
                    const float szB = __uint_as_float(qk[s].y << 16);
                    const float w2B = __uint_as_float(qk[s].y & 0xffff0000u);
                    *(uint32_t*)(pU + (size_t)s * D_INNER) =
                        pack2bf(fmaf(yA, szA, w2A), fmaf(yB, szB, w2B));
                }
            }
            pD += 4 * 2048; pS += 4 * 2048; pU += 4 * D_INNER;
        }
    }
}

// ---------- causal depthwise conv (k=4) + bias + SiLU, 2 channels/thread ----------
__global__ void kconv(const uint16_t* __restrict__ xzb, const float* __restrict__ cw,
                      const float* __restrict__ cb, float* __restrict__ xs) {
    const int T = blockIdx.x * 256 + threadIdx.x;   // over NROWS*1024
    const int d0 = (T & 1023) * 2;
    const int row = T >> 10;
    const int l = row & (SEQLEN - 1), b = row >> 11;
    const float4 wA = *(const float4*)&cw[d0 * 4];
    const float4 wB = *(const float4*)&cw[d0 * 4 + 4];
    const float2 bias = *(const float2*)&cb[d0];
    float a0 = bias.x, a1 = bias.y;
    const size_t base = (size_t)b * SEQLEN;
    if (l >= 3) {
        uint32_t v;
        v = *(const uint32_t*)&xzb[(base + l - 3) * 4096 + d0];
        a0 += wA.x * bf2f((uint16_t)v); a1 += wB.x * bf2f((uint16_t)(v >> 16));
        v = *(const uint32_t*)&xzb[(base + l - 2) * 4096 + d0];
        a0 += wA.y * bf2f((uint16_t)v); a1 += wB.y * bf2f((uint16_t)(v >> 16));
        v = *(const uint32_t*)&xzb[(base + l - 1) * 4096 + d0];
        a0 += wA.z * bf2f((uint16_t)v); a1 += wB.z * bf2f((uint16_t)(v >> 16));
        v = *(const uint32_t*)&xzb[(base + l    ) * 4096 + d0];
        a0 += wA.w * bf2f((uint16_t)v); a1 += wB.w * bf2f((uint16_t)(v >> 16));
    } else {
        uint32_t v;
        if (l >= 2) {
            v = *(const uint32_t*)&xzb[(base + l - 2) * 4096 + d0];
            a0 += wA.y * bf2f((uint16_t)v); a1 += wB.y * bf2f((uint16_t)(v >> 16));
        }
        if (l >= 1) {
            v = *(const uint32_t*)&xzb[(base + l - 1) * 4096 + d0];
            a0 += wA.z * bf2f((uint16_t)v); a1 += wB.z * bf2f((uint16_t)(v >> 16));
        }
        v = *(const uint32_t*)&xzb[(base + l) * 4096 + d0];
        a0 += wA.w * bf2f((uint16_t)v); a1 += wB.w * bf2f((uint16_t)(v >> 16));
    }
    *(float2*)&xs[(size_t)row * 2048 + d0] = make_float2(silu_f(a0), silu_f(a1));
}

extern "C" void kernel_launch(void* const* d_in, const int* in_sizes, int n_in,
                              void* d_out, int out_size, void* d_ws, size_t ws_size,
                              hipStream_t stream) {
    const float* x      = (const float*)d_in[0];
    const float* W_in   = (const float*)d_in[1];
    const float* conv_w = (const float*)d_in[2];
    const float* conv_b = (const float*)d_in[3];
    const float* W_x    = (const float*)d_in[4];
    const float* w_dt   = (const float*)d_in[5];
    const float* b_dt   = (const float*)d_in[6];
    const float* A_log  = (const float*)d_in[7];
    const float* Dp     = (const float*)d_in[8];
    const float* W_out  = (const float*)d_in[9];
    float* out = (float*)d_out;

    char* p = (char*)d_ws;
    uint16_t* xb  = (uint16_t*)p;  p += (size_t)NROWS * D_MODEL * 2;      // 8 MB (dead after gemm1)
    uint16_t* Wb  = (uint16_t*)p;  p += (size_t)4096 * 1024 * 2;          // 8 MB (dead after gemm1)
    uint16_t* Wob = (uint16_t*)p;  p += (size_t)1024 * 2048 * 2;          // 4 MB  (W_out^T)
    uint16_t* xzb = (uint16_t*)p;  p += (size_t)NROWS * 4096 * 2;         // 32 MB (bf16 xz)
    float* xs     = (float*)p;     p += (size_t)NROWS * D_INNER * 4;      // 32 MB (f32 xs, then dtdx pack)
    float* bcd    = (float*)p;     p += (size_t)NROWS * BCD_LD * 4;       // 576 KB
    float* sumdt  = (float*)p;     p += (size_t)NCHUNK * 4096 * 4;        // 1 MB
    float* Wxt    = (float*)p;     p += (size_t)64 * 2048 * 4;            // 512 KB
    uint16_t* ub  = (uint16_t*)p;  p += (size_t)NROWS * D_INNER * 2;      // 16 MB
    uint32_t* szw = (uint32_t*)p;  p += (size_t)NROWS * D_INNER * 4;      // 32 MB (silu(z) pack)
    // overlays (regions dead during their use):
    float* hbuf   = (float*)xb;        // 16 MB = xb+Wb (dead after gemm1)
    float* part   = (float*)ub;        // 12.6 MB (ub written only by kscan3, later)
    uint32_t* dtdx = (uint32_t*)xs;    // packed (dt, dt*x), in-place over xs after kredprep

    // 1) fused input prep (cvt + 2 transposes + Wxt)
    kprep0<<<10752, 256, 0, stream>>>(x, xb, W_in, Wb, W_out, Wob, W_x, Wxt);
    // 2) xz = x @ W_in   (M=4096, N=4096, K=1024), bf16 out, 256x128 dbuf
    kgemm256<1024, 5><<<dim3(32, 16), 512, 0, stream>>>(xb, Wb, xzb, 4096);
    // 3) conv + silu (bf16 in, f32 out), 2 ch/thread
    kconv<<<NROWS * 1024 / 256, 256, 0, stream>>>(xzb, conv_w, conv_b, xs);
    // 4) bcd partials = xs @ W_x  (MFMA, K-split 16)
    kgemm2m<<<dim3(KS2, 32), 256, 0, stream>>>(xs, Wxt, part);
    // 5) fused reduce + scan-operand packing (dtdx in-place over xs, szw separate)
    kredprep<<<NROWS, 256, 0, stream>>>(part, w_dt, b_dt, Dp, xs, xzb, szw, bcd);
    // 6) selective scan (3 phases), 2 ch/thread, LDS-staged bcd, 4-deep batching
    kscan1<<<(4096 * NCHUNK) / 256, 256, 0, stream>>>(dtdx, bcd, A_log, hbuf, sumdt);
    kscan2<<<(4096 * 16) / 256, 256, 0, stream>>>(hbuf, sumdt, A_log);
    kscan3<<<(4096 * NCHUNK) / 256, 256, 0, stream>>>(dtdx, bcd, A_log, szw, hbuf, ub);
    // 7) out = u @ W_out (M=4096, N=1024, K=2048), dbuf
    kgemm64<2048, 3><<<dim3(1024 / 128, 4096 / 64), 256, 0, stream>>>(ub, Wob, out, 1024);
}

// Round 11
// 213.950 us; speedup vs baseline: 2.5108x; 1.0036x over previous
//
#include <hip/hip_runtime.h>
#include <hip/hip_bf16.h>
#include <stdint.h>

#define D_MODEL 1024
#define D_STATE 16
#define D_CONV  4
#define D_INNER 2048
#define BATCH   2
#define SEQLEN  2048
#define NROWS   (BATCH*SEQLEN)     // 4096
#define BCD_LD  36                 // padded leading dim for bcd (33 used)
#define NCHUNK  64
#define CHUNKLEN (SEQLEN/NCHUNK)   // 32
#define KS2     16                 // K-splits for GEMM2 (chunk = 128)
#define L2E 1.44269504088896340f

typedef __attribute__((ext_vector_type(8))) short   short8;
typedef __attribute__((ext_vector_type(4))) float   f32x4;

__device__ __forceinline__ uint16_t f2bf(float f) {        // RNE f32->bf16
    uint32_t u = __float_as_uint(f);
    return (uint16_t)((u + 0x7FFFu + ((u >> 16) & 1u)) >> 16);
}
__device__ __forceinline__ float bf2f(uint16_t h) {
    return __uint_as_float(((uint32_t)h) << 16);
}
__device__ __forceinline__ uint32_t pack2bf(float lo, float hi) {
    return (uint32_t)f2bf(lo) | ((uint32_t)f2bf(hi) << 16);
}
__device__ __forceinline__ void gload16(const uint16_t* g, uint16_t* l) {
    __builtin_amdgcn_global_load_lds(
        (const __attribute__((address_space(1))) void*)g,
        (__attribute__((address_space(3))) void*)l, 16, 0, 0);
}
__device__ __forceinline__ void gload16f(const float* g, float* l) {
    __builtin_amdgcn_global_load_lds(
        (const __attribute__((address_space(1))) void*)g,
        (__attribute__((address_space(3))) void*)l, 16, 0, 0);
}
__device__ __forceinline__ float softplus_f(float v) {
    return fmaxf(v, 0.f) + __logf(1.f + __expf(-fabsf(v)));
}
__device__ __forceinline__ float silu_f(float v) {
    return v / (1.f + __expf(-v));
}
__device__ __forceinline__ short8 pack8(const float4 lo, const float4 hi) {
    short8 r;
    r[0] = (short)f2bf(lo.x); r[1] = (short)f2bf(lo.y);
    r[2] = (short)f2bf(lo.z); r[3] = (short)f2bf(lo.w);
    r[4] = (short)f2bf(hi.x); r[5] = (short)f2bf(hi.y);
    r[6] = (short)f2bf(hi.z); r[7] = (short)f2bf(hi.w);
    return r;
}

// ---------- fused input prep: kcvt | ktrans(W_in) | ktrans(W_out) | kwxt ----------
__global__ void kprep0(const float* __restrict__ x, uint16_t* __restrict__ xb,
                       const float* __restrict__ W_in, uint16_t* __restrict__ Wb,
                       const float* __restrict__ W_out, uint16_t* __restrict__ Wob,
                       const float* __restrict__ Wx, float* __restrict__ Wxt) {
    __shared__ float tile[32][33];
    const int blk = blockIdx.x;
    const int tid = threadIdx.x;
    if (blk < 4096) {                          // ---- cvt x -> bf16 (1M float4s)
        const int T = blk * 256 + tid;
        const float4 v = *(const float4*)&x[(size_t)T * 4];
        ushort4 o;
        o.x = f2bf(v.x); o.y = f2bf(v.y); o.z = f2bf(v.z); o.w = f2bf(v.w);
        *(ushort4*)&xb[(size_t)T * 4] = o;
    } else if (blk < 8192) {                   // ---- W_in [1024][4096] -> Wb [4096][1024]
        const int bb = blk - 4096;
        const int n0 = (bb & 127) * 32, k0 = (bb >> 7) * 32;
        const int tx = tid & 31, ty = tid >> 5;
#pragma unroll
        for (int i = 0; i < 4; ++i)
            tile[ty + i * 8][tx] = W_in[(size_t)(k0 + ty + i * 8) * 4096 + n0 + tx];
        __syncthreads();
#pragma unroll
        for (int i = 0; i < 4; ++i)
            Wb[(size_t)(n0 + ty + i * 8) * 1024 + k0 + tx] = f2bf(tile[tx][ty + i * 8]);
    } else if (blk < 10240) {                  // ---- W_out [2048][1024] -> Wob [1024][2048]
        const int bb = blk - 8192;
        const int n0 = (bb & 31) * 32, k0 = (bb >> 5) * 32;
        const int tx = tid & 31, ty = tid >> 5;
#pragma unroll
        for (int i = 0; i < 4; ++i)
            tile[ty + i * 8][tx] = W_out[(size_t)(k0 + ty + i * 8) * 1024 + n0 + tx];
        __syncthreads();
#pragma unroll
        for (int i = 0; i < 4; ++i)
            Wob[(size_t)(n0 + ty + i * 8) * 2048 + k0 + tx] = f2bf(tile[tx][ty + i * 8]);
    } else {                                   // ---- Wxt[64][2048] = W_x^T zero-padded
        const int T = (blk - 10240) * 256 + tid;
        const int j = T >> 11, k = T & 2047;
        Wxt[T] = (j < 33) ? Wx[(size_t)k * 33 + j] : 0.f;
    }
}

// ---------- GEMM1: 256x128 tile, 512 thr, 3-buf counted-vmcnt pipeline ----------
template<int KDIM, int GXL>
__global__ __launch_bounds__(512) void kgemm256(const uint16_t* __restrict__ A,
                                                const uint16_t* __restrict__ B,
                                                uint16_t* __restrict__ C, const int ldc) {
    __shared__ uint16_t As[3][256 * 32];   // 3 x 16 KB
    __shared__ uint16_t Bsh[3][128 * 32];  // 3 x 8 KB  (72 KB total)
    const int t = threadIdx.x;          // 0..511
    const int w = t >> 6, lane = t & 63;
    int wg = blockIdx.y * (1 << GXL) + blockIdx.x;
    wg = (wg & 7) * ((gridDim.x * gridDim.y) >> 3) + (wg >> 3);   // bijective XCD swizzle
    const int m0 = (wg >> GXL) * 256, n0 = (wg & ((1 << GXL) - 1)) * 128;
    const int wm = (w >> 1) * 64, wn = (w & 1) * 64;
    f32x4 acc[4][4] = {};

    const int srow = t >> 2;                              // 0..127
    const int scol = ((t & 3) ^ ((t >> 3) & 3)) * 8;      // pre-swizzled source slot
    const uint16_t* ga0 = A + (size_t)(m0 + srow) * KDIM + scol;
    const uint16_t* ga1 = A + (size_t)(m0 + 128 + srow) * KDIM + scol;
    const uint16_t* gb0 = B + (size_t)(n0 + srow) * KDIM + scol;

    const int fr = lane & 15, fg = (lane >> 4) * 8;
    const int psl = (((fg >> 3) ^ ((fr >> 1) & 3)) << 3);

    auto stage = [&](int buf, int ko) {
        gload16(ga0 + ko, &As[buf][w * 512]);
        gload16(ga1 + ko, &As[buf][4096 + w * 512]);
        gload16(gb0 + ko, &Bsh[buf][w * 512]);
    };

    constexpr int KT = KDIM / 32;
    stage(0, 0);
    stage(1, 32);                       // 6 loads in flight
    int cur = 0;
    for (int kt = 0; kt < KT; ++kt) {
        // retire tile kt's 3 loads; keep tile kt+1's 3 in flight (never drain mid-loop)
        if (kt + 1 < KT) asm volatile("s_waitcnt vmcnt(3)" ::: "memory");
        else             asm volatile("s_waitcnt vmcnt(0)" ::: "memory");
        asm volatile("s_barrier" ::: "memory");      // all waves' tile-kt loads landed
        if (kt + 2 < KT) stage((kt + 2) % 3, (kt + 2) * 32);  // overwrites buf (kt-1)%3
        short8 a[4], b[4];
#pragma unroll
        for (int i = 0; i < 4; ++i) {
            a[i] = *(const short8*)&As[cur][(wm + i * 16 + fr) * 32 + psl];
            b[i] = *(const short8*)&Bsh[cur][(wn + i * 16 + fr) * 32 + psl];
        }
#pragma unroll
        for (int i = 0; i < 4; ++i)
#pragma unroll
            for (int j = 0; j < 4; ++j)
                acc[i][j] = __builtin_amdgcn_mfma_f32_16x16x32_bf16(a[i], b[j], acc[i][j], 0, 0, 0);
        cur = (cur + 1) % 3;
    }
    const int cr = (lane >> 4) * 4, cc = lane & 15;
#pragma unroll
    for (int i = 0; i < 4; ++i)
#pragma unroll
        for (int j = 0; j < 4; ++j)
#pragma unroll
            for (int r = 0; r < 4; ++r)
                C[(size_t)(m0 + wm + i * 16 + cr + r) * ldc + (n0 + wn + j * 16 + cc)] =
                    f2bf(acc[i][j][r]);
}

// ---------- GEMM3: 64x128 tile, 3-buf counted-vmcnt pipeline, f32 C ----------
template<int KDIM, int GXL>
__global__ __launch_bounds__(256) void kgemm64(const uint16_t* __restrict__ A,
                                               const uint16_t* __restrict__ B,
                                               float* __restrict__ C, const int ldc) {
    __shared__ uint16_t As[3][64 * 32];      // 3 x 4 KB
    __shared__ uint16_t Bsh[3][128 * 32];    // 3 x 8 KB  (36 KB total)
    const int t = threadIdx.x;
    const int w = t >> 6, lane = t & 63;
    int wg = blockIdx.y * (1 << GXL) + blockIdx.x;
    wg = (wg & 7) * ((gridDim.x * gridDim.y) >> 3) + (wg >> 3);
    const int m0 = (wg >> GXL) * 64, n0 = (wg & ((1 << GXL) - 1)) * 128;
    const int wm = (w >> 1) * 32, wn = (w & 1) * 64;
    f32x4 acc[2][4] = {};

    const int srow = t >> 2;
    const int scol = ((t & 3) ^ ((t >> 3) & 3)) * 8;
    const uint16_t* ga0 = A + (size_t)(m0 + srow) * KDIM + scol;
    const uint16_t* gb0 = B + (size_t)(n0 + srow) * KDIM + scol;
    const uint16_t* gb1 = B + (size_t)(n0 + 64 + srow) * KDIM + scol;

    const int fr = lane & 15, fg = (lane >> 4) * 8;
    const int psl = (((fg >> 3) ^ ((fr >> 1) & 3)) << 3);

    auto stage = [&](int buf, int ko) {
        gload16(ga0 + ko, &As[buf][w * 512]);
        gload16(gb0 + ko, &Bsh[buf][w * 512]);
        gload16(gb1 + ko, &Bsh[buf][2048 + w * 512]);
    };

    constexpr int KT = KDIM / 32;
    stage(0, 0);
    stage(1, 32);
    int cur = 0;
    for (int kt = 0; kt < KT; ++kt) {
        if (kt + 1 < KT) asm volatile("s_waitcnt vmcnt(3)" ::: "memory");
        else             asm volatile("s_waitcnt vmcnt(0)" ::: "memory");
        asm volatile("s_barrier" ::: "memory");
        if (kt + 2 < KT) stage((kt + 2) % 3, (kt + 2) * 32);
        short8 a[2], b[4];
#pragma unroll
        for (int i = 0; i < 2; ++i)
            a[i] = *(const short8*)&As[cur][(wm + i * 16 + fr) * 32 + psl];
#pragma unroll
        for (int j = 0; j < 4; ++j)
            b[j] = *(const short8*)&Bsh[cur][(wn + j * 16 + fr) * 32 + psl];
#pragma unroll
        for (int i = 0; i < 2; ++i)
#pragma unroll
            for (int j = 0; j < 4; ++j)
                acc[i][j] = __builtin_amdgcn_mfma_f32_16x16x32_bf16(a[i], b[j], acc[i][j], 0, 0, 0);
        cur = (cur + 1) % 3;
    }
    const int cr = (lane >> 4) * 4, cc = lane & 15;
#pragma unroll
    for (int i = 0; i < 2; ++i)
#pragma unroll
        for (int j = 0; j < 4; ++j)
#pragma unroll
            for (int r = 0; r < 4; ++r)
                C[(size_t)(m0 + wm + i * 16 + cr + r) * ldc + (n0 + wn + j * 16 + cc)] = acc[i][j][r];
}

// ---------- GEMM2 MFMA K-split: part[kb][4096][48] = xs(chunk) @ Wxt^T ----------
__global__ __launch_bounds__(256) void kgemm2m(const float* __restrict__ xs,
        const float* __restrict__ Wxt, float* __restrict__ part) {
    __shared__ float As[128 * 32];   // 16 KB
    __shared__ float Bs[64 * 32];    // 8 KB
    const int t = threadIdx.x;
    const int w = t >> 6, lane = t & 63;
    const int kb = blockIdx.x;              // 0..15
    const int m0 = blockIdx.y * 128;
    const int kc = kb * 128;
    f32x4 acc[2][3] = {};

    const int srow = t >> 3;                            // 0..31
    const int scol = ((t & 7) ^ ((t >> 3) & 7)) * 4;    // pre-swizzled source (floats)
    float* lA[4]; float* lB[2];
#pragma unroll
    for (int r = 0; r < 4; ++r) lA[r] = &As[(r * 32 + w * 8) * 32];
#pragma unroll
    for (int r = 0; r < 2; ++r) lB[r] = &Bs[(r * 32 + w * 8) * 32];

    const int wm = w * 32;
    const int fr = lane & 15, fg = (lane >> 4) * 8;
    const int plo = (((fg >> 2) ^ (fr & 7))) * 4;
    const int phi = ((((fg >> 2) + 1) ^ (fr & 7))) * 4;

    for (int kt = 0; kt < 4; ++kt) {
        const int ko = kc + kt * 32;
#pragma unroll
        for (int r = 0; r < 4; ++r)
            gload16f(xs + (size_t)(m0 + r * 32 + srow) * 2048 + ko + scol, lA[r]);
#pragma unroll
        for (int r = 0; r < 2; ++r)
            gload16f(Wxt + (size_t)(r * 32 + srow) * 2048 + ko + scol, lB[r]);
        __syncthreads();
        short8 a[2], b[3];
#pragma unroll
        for (int i = 0; i < 2; ++i) {
            const float* base = &As[(wm + i * 16 + fr) * 32];
            a[i] = pack8(*(const float4*)&base[plo], *(const float4*)&base[phi]);
        }
#pragma unroll
        for (int j = 0; j < 3; ++j) {
            const float* base = &Bs[(j * 16 + fr) * 32];
            b[j] = pack8(*(const float4*)&base[plo], *(const float4*)&base[phi]);
        }
#pragma unroll
        for (int i = 0; i < 2; ++i)
#pragma unroll
            for (int j = 0; j < 3; ++j)
                acc[i][j] = __builtin_amdgcn_mfma_f32_16x16x32_bf16(a[i], b[j], acc[i][j], 0, 0, 0);
        __syncthreads();
    }
    const int cr = (lane >> 4) * 4, cc = lane & 15;
    float* pb = part + (size_t)kb * 4096 * 48;
#pragma unroll
    for (int i = 0; i < 2; ++i)
#pragma unroll
        for (int j = 0; j < 3; ++j)
#pragma unroll
            for (int r = 0; r < 4; ++r)
                pb[(size_t)(m0 + wm + i * 16 + cr + r) * 48 + j * 16 + cc] = acc[i][j][r];
}

// ---------- fused: reduce K-split partials -> bcd row, then pack scan operands ----------
__global__ __launch_bounds__(256) void kredprep(const float* __restrict__ part,
        const float* __restrict__ wdt, const float* __restrict__ bdt,
        const float* __restrict__ Dp, float* __restrict__ xs_io,
        const uint16_t* __restrict__ xzb, uint32_t* __restrict__ szw,
        float* __restrict__ bcd) {
    const int row = blockIdx.x;
    const int t = threadIdx.x;
    __shared__ float rawsh;
    if (t < 33) {
        float s = 0.f;
#pragma unroll
        for (int ks = 0; ks < KS2; ++ks)
            s += part[(size_t)ks * 4096 * 48 + (size_t)row * 48 + t];
        bcd[(size_t)row * BCD_LD + t] = s;
        if (t == 32) rawsh = s;
    }
    __syncthreads();
    const float raw = rawsh;
#pragma unroll
    for (int g = 0; g < 2; ++g) {
        const int dg = t * 8 + g * 4;
        const float4 w  = *(const float4*)&wdt[dg];
        const float4 b  = *(const float4*)&bdt[dg];
        const float4 Dv = *(const float4*)&Dp[dg];
        const float4 xv = *(const float4*)&xs_io[(size_t)row * 2048 + dg];
        const ushort4 zu = *(const ushort4*)&xzb[(size_t)row * 4096 + 2048 + dg];
        const float dt0 = softplus_f(raw * w.x + b.x);
        const float dt1 = softplus_f(raw * w.y + b.y);
        const float dt2 = softplus_f(raw * w.z + b.z);
        const float dt3 = softplus_f(raw * w.w + b.w);
        float4 pd;
        pd.x = __uint_as_float(pack2bf(dt0, dt0 * xv.x));
        pd.y = __uint_as_float(pack2bf(dt1, dt1 * xv.y));
        pd.z = __uint_as_float(pack2bf(dt2, dt2 * xv.z));
        pd.w = __uint_as_float(pack2bf(dt3, dt3 * xv.w));
        const float s0 = silu_f(bf2f(zu.x)), s1 = silu_f(bf2f(zu.y));
        const float s2 = silu_f(bf2f(zu.z)), s3 = silu_f(bf2f(zu.w));
        uint4 ps;
        ps.x = pack2bf(s0, xv.x * Dv.x * s0);
        ps.y = pack2bf(s1, xv.y * Dv.y * s1);
        ps.z = pack2bf(s2, xv.z * Dv.z * s2);
        ps.w = pack2bf(s3, xv.w * Dv.w * s3);
        *(float4*)&xs_io[(size_t)row * 2048 + dg] = pd;
        *(uint4*)&szw[(size_t)row * 2048 + dg] = ps;
    }
}

// ---------- scan phase 1: 2 ch/thread, bcd B in LDS, 4-deep global batching ----------
__global__ __launch_bounds__(256) void kscan1(const uint32_t* __restrict__ dtdx,
        const float* __restrict__ bcd, const float* __restrict__ Alog,
        float* __restrict__ hbuf, float* __restrict__ sumdt) {
    const int T = blockIdx.x * 256 + threadIdx.x;
    const int sub = T & 1;
    const int cp  = (T >> 1) & 2047;
    const int chunk = T >> 12;
    const int b = cp >> 10, d0 = (cp & 1023) * 2;
    const int row0 = b * SEQLEN + chunk * CHUNKLEN;    // same for whole block

    __shared__ float Bls[32][16];       // B part (cols 0..15) of the 32 chunk rows
    {
        const int r = threadIdx.x >> 3, c = (threadIdx.x & 7) * 2;
        const float2 v = *(const float2*)&bcd[(size_t)(row0 + r) * BCD_LD + c];
        Bls[r][c] = v.x; Bls[r][c + 1] = v.y;
    }
    __syncthreads();

    float Ae0[8], Ae1[8]; bool st = true;
#pragma unroll
    for (int i = 0; i < 8; ++i) {
        const float a0 = __expf(Alog[d0 * 16 + sub * 8 + i]);
        const float a1 = __expf(Alog[(d0 + 1) * 16 + sub * 8 + i]);
        Ae0[i] = -a0 * L2E; Ae1[i] = -a1 * L2E;
        st = st && (fabsf(a0 - (float)(sub * 8 + i + 1)) < 1e-3f)
                && (fabsf(a1 - (float)(sub * 8 + i + 1)) < 1e-3f);
    }
    float hA[8] = {}, hB[8] = {};
    float sdtA = 0.f, sdtB = 0.f;
    const uint32_t* pD = dtdx + (size_t)row0 * 2048 + d0;
    if (st) {
        for (int l0 = 0; l0 < CHUNKLEN; l0 += 4) {
            uint2 pk[4];
#pragma unroll
            for (int s = 0; s < 4; ++s) pk[s] = *(const uint2*)(pD + (size_t)s * 2048);
#pragma unroll
            for (int s = 0; s < 4; ++s) {
                const float4 B0 = *(const float4*)&Bls[l0 + s][sub * 8];
                const float4 B1 = *(const float4*)&Bls[l0 + s][sub * 8 + 4];
                const float dtA  = __uint_as_float(pk[s].x << 16);
                const float dtxA = __uint_as_float(pk[s].x & 0xffff0000u);
                const float dtB  = __uint_as_float(pk[s].y << 16);
                const float dtxB = __uint_as_float(pk[s].y & 0xffff0000u);
                sdtA += dtA; sdtB += dtB;
                const float e0A = __builtin_amdgcn_exp2f(dtA * (-L2E));
                const float e0B = __builtin_amdgcn_exp2f(dtB * (-L2E));
                const float e8A = (e0A*e0A)*(e0A*e0A)*(e0A*e0A)*(e0A*e0A);
                const float e8B = (e0B*e0B)*(e0B*e0B)*(e0B*e0B)*(e0B*e0B);
                float dA = sub ? e8A : 1.f, dB = sub ? e8B : 1.f;
                dA *= e0A; dB *= e0B; hA[0] = fmaf(dA, hA[0], dtxA * B0.x); hB[0] = fmaf(dB, hB[0], dtxB * B0.x);
                dA *= e0A; dB *= e0B; hA[1] = fmaf(dA, hA[1], dtxA * B0.y); hB[1] = fmaf(dB, hB[1], dtxB * B0.y);
                dA *= e0A; dB *= e0B; hA[2] = fmaf(dA, hA[2], dtxA * B0.z); hB[2] = fmaf(dB, hB[2], dtxB * B0.z);
                dA *= e0A; dB *= e0B; hA[3] = fmaf(dA, hA[3], dtxA * B0.w); hB[3] = fmaf(dB, hB[3], dtxB * B0.w);
                dA *= e0A; dB *= e0B; hA[4] = fmaf(dA, hA[4], dtxA * B1.x); hB[4] = fmaf(dB, hB[4], dtxB * B1.x);
                dA *= e0A; dB *= e0B; hA[5] = fmaf(dA, hA[5], dtxA * B1.y); hB[5] = fmaf(dB, hB[5], dtxB * B1.y);
                dA *= e0A; dB *= e0B; hA[6] = fmaf(dA, hA[6], dtxA * B1.z); hB[6] = fmaf(dB, hB[6], dtxB * B1.z);
                dA *= e0A; dB *= e0B; hA[7] = fmaf(dA, hA[7], dtxA * B1.w); hB[7] = fmaf(dB, hB[7], dtxB * B1.w);
            }
            pD += 4 * 2048;
        }
    } else {
        for (int l0 = 0; l0 < CHUNKLEN; l0 += 4) {
            uint2 pk[4];
#pragma unroll
            for (int s = 0; s < 4; ++s) pk[s] = *(const uint2*)(pD + (size_t)s * 2048);
#pragma unroll
            for (int s = 0; s < 4; ++s) {
                const float4 B0 = *(const float4*)&Bls[l0 + s][sub * 8];
                const float4 B1 = *(const float4*)&Bls[l0 + s][sub * 8 + 4];
                const float dtA  = __uint_as_float(pk[s].x << 16);
                const float dtxA = __uint_as_float(pk[s].x & 0xffff0000u);
                const float dtB  = __uint_as_float(pk[s].y << 16);
                const float dtxB = __uint_as_float(pk[s].y & 0xffff0000u);
                sdtA += dtA; sdtB += dtB;
                const float Bv[8] = {B0.x, B0.y, B0.z, B0.w, B1.x, B1.y, B1.z, B1.w};
#pragma unroll
                for (int i = 0; i < 8; ++i) {
                    hA[i] = fmaf(__builtin_amdgcn_exp2f(dtA * Ae0[i]), hA[i], dtxA * Bv[i]);
                    hB[i] = fmaf(__builtin_amdgcn_exp2f(dtB * Ae1[i]), hB[i], dtxB * Bv[i]);
                }
            }
            pD += 4 * 2048;
        }
    }
    const size_t cc0 = (size_t)(chunk * 4096 + b * 2048 + d0) * 16 + sub * 8;
    *(float4*)&hbuf[cc0]          = make_float4(hA[0], hA[1], hA[2], hA[3]);
    *(float4*)&hbuf[cc0 + 4]      = make_float4(hA[4], hA[5], hA[6], hA[7]);
    *(float4*)&hbuf[cc0 + 16]     = make_float4(hB[0], hB[1], hB[2], hB[3]);
    *(float4*)&hbuf[cc0 + 20]     = make_float4(hB[4], hB[5], hB[6], hB[7]);
    if (sub == 0)
        *(float2*)&sumdt[chunk * 4096 + b * 2048 + d0] = make_float2(sdtA, sdtB);
}

// ---------- scan phase 2: chunk combine (in-place carries), next-iter prefetch ----------
__global__ void kscan2(float* __restrict__ hbuf, const float* __restrict__ sumdt,
                       const float* __restrict__ Alog) {
    const int T = blockIdx.x * 256 + threadIdx.x;   // 65536
    const int n = T & 15, ch = T >> 4;
    const int d = ch & 2047;
    const float Ae = -__expf(Alog[d * 16 + n]) * L2E;
    float h = 0.f;
    size_t idx = (size_t)ch * 16 + n;
    float loc = hbuf[idx];
    float sd  = sumdt[ch];
    for (int c = 0; c < NCHUNK; ++c) {
        float locN = 0.f, sdN = 0.f;
        const size_t idxN = idx + (size_t)4096 * 16;
        if (c + 1 < NCHUNK) {                 // prefetch next chunk's inputs
            locN = hbuf[idxN];
            sdN  = sumdt[(size_t)(c + 1) * 4096 + ch];
        }
        hbuf[idx] = h;                         // carry (h at chunk start)
        h = __builtin_amdgcn_exp2f(Ae * sd) * h + loc;
        loc = locN; sd = sdN; idx = idxN;
    }
}

// ---------- scan phase 3: 2 ch/thread, bcd B+C in LDS, 4-deep batching ----------
__global__ __launch_bounds__(256) void kscan3(const uint32_t* __restrict__ dtdx,
        const float* __restrict__ bcd, const float* __restrict__ Alog,
        const uint32_t* __restrict__ szw, const float* __restrict__ hbuf,
        uint16_t* __restrict__ u) {
    const int T = blockIdx.x * 256 + threadIdx.x;
    const int sub = T & 1;
    const int cp  = (T >> 1) & 2047;
    const int chunk = T >> 12;
    const int b = cp >> 10, d0 = (cp & 1023) * 2;
    const int row0 = b * SEQLEN + chunk * CHUNKLEN;    // same for whole block

    __shared__ float BC[32][32];        // B (0..15) + C (16..31) of the 32 chunk rows
    {
        const int r = threadIdx.x >> 3, c = (threadIdx.x & 7) * 4;
        *(float4*)&BC[r][c] = *(const float4*)&bcd[(size_t)(row0 + r) * BCD_LD + c];
    }
    __syncthreads();

    float Ae0[8], Ae1[8]; bool st = true;
#pragma unroll
    for (int i = 0; i < 8; ++i) {
        const float a0 = __expf(Alog[d0 * 16 + sub * 8 + i]);
        const float a1 = __expf(Alog[(d0 + 1) * 16 + sub * 8 + i]);
        Ae0[i] = -a0 * L2E; Ae1[i] = -a1 * L2E;
        st = st && (fabsf(a0 - (float)(sub * 8 + i + 1)) < 1e-3f)
                && (fabsf(a1 - (float)(sub * 8 + i + 1)) < 1e-3f);
    }
    float hA[8], hB[8];
    {
        const size_t cc0 = (size_t)(chunk * 4096 + b * 2048 + d0) * 16 + sub * 8;
        const float4 a0 = *(const float4*)&hbuf[cc0];
        const float4 a1 = *(const float4*)&hbuf[cc0 + 4];
        const float4 b0 = *(const float4*)&hbuf[cc0 + 16];
        const float4 b1 = *(const float4*)&hbuf[cc0 + 20];
        hA[0]=a0.x; hA[1]=a0.y; hA[2]=a0.z; hA[3]=a0.w;
        hA[4]=a1.x; hA[5]=a1.y; hA[6]=a1.z; hA[7]=a1.w;
        hB[0]=b0.x; hB[1]=b0.y; hB[2]=b0.z; hB[3]=b0.w;
        hB[4]=b1.x; hB[5]=b1.y; hB[6]=b1.z; hB[7]=b1.w;
    }
    const uint32_t* pD = dtdx + (size_t)row0 * 2048 + d0;
    const uint32_t* pS = szw  + (size_t)row0 * 2048 + d0;   // only sub==0 reads
    uint16_t* pU = u + (size_t)row0 * D_INNER + d0;
    if (st) {
        for (int l0 = 0; l0 < CHUNKLEN; l0 += 4) {
            uint2 pk[4], qk[4];
#pragma unroll
            for (int s = 0; s < 4; ++s) {
                pk[s] = *(const uint2*)(pD + (size_t)s * 2048);
                if (sub == 0) qk[s] = *(const uint2*)(pS + (size_t)s * 2048);
            }
#pragma unroll
            for (int s = 0; s < 4; ++s) {
                const float4 B0 = *(const float4*)&BC[l0 + s][sub * 8];
                const float4 B1 = *(const float4*)&BC[l0 + s][sub * 8 + 4];
                const float4 C0 = *(const float4*)&BC[l0 + s][16 + sub * 8];
                const float4 C1 = *(const float4*)&BC[l0 + s][20 + sub * 8];
                const float dtA  = __uint_as_float(pk[s].x << 16);
                const float dtxA = __uint_as_float(pk[s].x & 0xffff0000u);
                const float dtB  = __uint_as_float(pk[s].y << 16);
                const float dtxB = __uint_as_float(pk[s].y & 0xffff0000u);
                const float e0A = __builtin_amdgcn_exp2f(dtA * (-L2E));
                const float e0B = __builtin_amdgcn_exp2f(dtB * (-L2E));
                const float e8A = (e0A*e0A)*(e0A*e0A)*(e0A*e0A)*(e0A*e0A);
                const float e8B = (e0B*e0B)*(e0B*e0B)*(e0B*e0B)*(e0B*e0B);
                float dA = sub ? e8A : 1.f, dB = sub ? e8B : 1.f;
                float yA, yB;
                dA *= e0A; dB *= e0B; hA[0] = fmaf(dA, hA[0], dtxA * B0.x); hB[0] = fmaf(dB, hB[0], dtxB * B0.x);
                dA *= e0A; dB *= e0B; hA[1] = fmaf(dA, hA[1], dtxA * B0.y); hB[1] = fmaf(dB, hB[1], dtxB * B0.y);
                dA *= e0A; dB *= e0B; hA[2] = fmaf(dA, hA[2], dtxA * B0.z); hB[2] = fmaf(dB, hB[2], dtxB * B0.z);
                dA *= e0A; dB *= e0B; hA[3] = fmaf(dA, hA[3], dtxA * B0.w); hB[3] = fmaf(dB, hB[3], dtxB * B0.w);
                dA *= e0A; dB *= e0B; hA[4] = fmaf(dA, hA[4], dtxA * B1.x); hB[4] = fmaf(dB, hB[4], dtxB * B1.x);
                dA *= e0A; dB *= e0B; hA[5] = fmaf(dA, hA[5], dtxA * B1.y); hB[5] = fmaf(dB, hB[5], dtxB * B1.y);
                dA *= e0A; dB *= e0B; hA[6] = fmaf(dA, hA[6], dtxA * B1.z); hB[6] = fmaf(dB, hB[6], dtxB * B1.z);
                dA *= e0A; dB *= e0B; hA[7] = fmaf(dA, hA[7], dtxA * B1.w); hB[7] = fmaf(dB, hB[7], dtxB * B1.w);
                yA = hA[0]*C0.x + hA[1]*C0.y + hA[2]*C0.z + hA[3]*C0.w
                   + hA[4]*C1.x + hA[5]*C1.y + hA[6]*C1.z + hA[7]*C1.w;
                yB = hB[0]*C0.x + hB[1]*C0.y + hB[2]*C0.z + hB[3]*C0.w
                   + hB[4]*C1.x + hB[5]*C1.y + hB[6]*C1.z + hB[7]*C1.w;
                yA += __shfl_xor(yA, 1);
                yB += __shfl_xor(yB, 1);
                if (sub == 0) {
                    const float szA = __uint_as_float(qk[s].x << 16);
                    const float w2A = __uint_as_float(qk[s].x & 0xffff0000u);
                    const float szB = __uint_as_float(qk[s].y << 16);
                    const float w2B = __uint_as_float(qk[s].y & 0xffff0000u);
                    *(uint32_t*)(pU + (size_t)s * D_INNER) =
                        pack2bf(fmaf(yA, szA, w2A), fmaf(yB, szB, w2B));
                }
            }
            pD += 4 * 2048; pS += 4 * 2048; pU += 4 * D_INNER;
        }
    } else {
        for (int l0 = 0; l0 < CHUNKLEN; l0 += 4) {
            uint2 pk[4], qk[4];
#pragma unroll
            for (int s = 0; s < 4; ++s) {
                pk[s] = *(const uint2*)(pD + (size_t)s * 2048);
                if (sub == 0) qk[s] = *(const uint2*)(pS + (size_t)s * 2048);
            }
#pragma unroll
            for (int s = 0; s < 4; ++s) {
                const float4 B0 = *(const float4*)&BC[l0 + s][sub * 8];
                const float4 B1 = *(const float4*)&BC[l0 + s][sub * 8 + 4];
                const float4 C0 = *(const float4*)&BC[l0 + s][16 + sub * 8];
                const float4 C1 = *(const float4*)&BC[l0 + s][20 + sub * 8];
                const float dtA  = __uint_as_float(pk[s].x << 16);
                const float dtxA = __uint_as_float(pk[s].x & 0xffff0000u);
                const float dtB  = __uint_as_float(pk[s].y << 16);
                const float dtxB = __uint_as_float(pk[s].y & 0xffff0000u);
                const float Bv[8] = {B0.x, B0.y, B0.z, B0.w, B1.x, B1.y, B1.z, B1.w};
                const float Cv[8] = {C0.x, C0.y, C0.z, C0.w, C1.x, C1.y, C1.z, C1.w};
                float yA = 0.f, yB = 0.f;
#pragma unroll
                for (int i = 0; i < 8; ++i) {
                    hA[i] = fmaf(__builtin_amdgcn_exp2f(dtA * Ae0[i]), hA[i], dtxA * Bv[i]);
                    hB[i] = fmaf(__builtin_amdgcn_exp2f(dtB * Ae1[i]), hB[i], dtxB * Bv[i]);
                    yA = fmaf(hA[i], Cv[i], yA);
                    yB = fmaf(hB[i], Cv[i], yB);
                }
                yA += __shfl_xor(yA, 1);
                yB += __shfl_xor(yB, 1);
                if (sub == 0) {
                    const float szA = __uint_as_float(qk[s].x << 16);
                    const float w2A = __uint_as_float(qk[s].x & 0xffff0000u);
                    const float szB = __uint_as_float(qk[s].y << 16);
                    const float w2B = __uint_as_float(qk[s].y & 0xffff0000u);
                    *(uint32_t*)(pU + (size_t)s * D_INNER) =
                        pack2bf(fmaf(yA, szA, w2A), fmaf(yB, szB, w2B));
                }
            }
            pD += 4 * 2048; pS += 4 * 2048; pU += 4 * D_INNER;
        }
    }
}

// ---------- causal depthwise conv (k=4) + bias + SiLU, 2 channels/thread ----------
__global__ void kconv(const uint16_t* __restrict__ xzb, const float* __restrict__ cw,
                      const float* __restrict__ cb, float* __restrict__ xs) {
    const int T = blockIdx.x * 256 + threadIdx.x;   // over NROWS*1024
    const int d0 = (T & 1023) * 2;
    const int row = T >> 10;
    const int l = row & (SEQLEN - 1), b = row >> 11;
    const float4 wA = *(const float4*)&cw[d0 * 4];
    const float4 wB = *(const float4*)&cw[d0 * 4 + 4];
    const float2 bias = *(const float2*)&cb[d0];
    float a0 = bias.x, a1 = bias.y;
    const size_t base = (size_t)b * SEQLEN;
    if (l >= 3) {
        uint32_t v;
        v = *(const uint32_t*)&xzb[(base + l - 3) * 4096 + d0];
        a0 += wA.x * bf2f((uint16_t)v); a1 += wB.x * bf2f((uint16_t)(v >> 16));
        v = *(const uint32_t*)&xzb[(base + l - 2) * 4096 + d0];
        a0 += wA.y * bf2f((uint16_t)v); a1 += wB.y * bf2f((uint16_t)(v >> 16));
        v = *(const uint32_t*)&xzb[(base + l - 1) * 4096 + d0];
        a0 += wA.z * bf2f((uint16_t)v); a1 += wB.z * bf2f((uint16_t)(v >> 16));
        v = *(const uint32_t*)&xzb[(base + l    ) * 4096 + d0];
        a0 += wA.w * bf2f((uint16_t)v); a1 += wB.w * bf2f((uint16_t)(v >> 16));
    } else {
        uint32_t v;
        if (l >= 2) {
            v = *(const uint32_t*)&xzb[(base + l - 2) * 4096 + d0];
            a0 += wA.y * bf2f((uint16_t)v); a1 += wB.y * bf2f((uint16_t)(v >> 16));
        }
        if (l >= 1) {
            v = *(const uint32_t*)&xzb[(base + l - 1) * 4096 + d0];
            a0 += wA.z * bf2f((uint16_t)v); a1 += wB.z * bf2f((uint16_t)(v >> 16));
        }
        v = *(const uint32_t*)&xzb[(base + l) * 4096 + d0];
        a0 += wA.w * bf2f((uint16_t)v); a1 += wB.w * bf2f((uint16_t)(v >> 16));
    }
    *(float2*)&xs[(size_t)row * 2048 + d0] = make_float2(silu_f(a0), silu_f(a1));
}

extern "C" void kernel_launch(void* const* d_in, const int* in_sizes, int n_in,
                              void* d_out, int out_size, void* d_ws, size_t ws_size,
                              hipStream_t stream) {
    const float* x      = (const float*)d_in[0];
    const float* W_in   = (const float*)d_in[1];
    const float* conv_w = (const float*)d_in[2];
    const float* conv_b = (const float*)d_in[3];
    const float* W_x    = (const float*)d_in[4];
    const float* w_dt   = (const float*)d_in[5];
    const float* b_dt   = (const float*)d_in[6];
    const float* A_log  = (const float*)d_in[7];
    const float* Dp     = (const float*)d_in[8];
    const float* W_out  = (const float*)d_in[9];
    float* out = (float*)d_out;

    char* p = (char*)d_ws;
    uint16_t* xb  = (uint16_t*)p;  p += (size_t)NROWS * D_MODEL * 2;      // 8 MB (dead after gemm1)
    uint16_t* Wb  = (uint16_t*)p;  p += (size_t)4096 * 1024 * 2;          // 8 MB (dead after gemm1)
    uint16_t* Wob = (uint16_t*)p;  p += (size_t)1024 * 2048 * 2;          // 4 MB  (W_out^T)
    uint16_t* xzb = (uint16_t*)p;  p += (size_t)NROWS * 4096 * 2;         // 32 MB (bf16 xz)
    float* xs     = (float*)p;     p += (size_t)NROWS * D_INNER * 4;      // 32 MB (f32 xs, then dtdx pack)
    float* bcd    = (float*)p;     p += (size_t)NROWS * BCD_LD * 4;       // 576 KB
    float* sumdt  = (float*)p;     p += (size_t)NCHUNK * 4096 * 4;        // 1 MB
    float* Wxt    = (float*)p;     p += (size_t)64 * 2048 * 4;            // 512 KB
    uint16_t* ub  = (uint16_t*)p;  p += (size_t)NROWS * D_INNER * 2;      // 16 MB
    uint32_t* szw = (uint32_t*)p;  p += (size_t)NROWS * D_INNER * 4;      // 32 MB (silu(z) pack)
    // overlays (regions dead during their use):
    float* hbuf   = (float*)xb;        // 16 MB = xb+Wb (dead after gemm1)
    float* part   = (float*)ub;        // 12.6 MB (ub written only by kscan3, later)
    uint32_t* dtdx = (uint32_t*)xs;    // packed (dt, dt*x), in-place over xs after kredprep

    // 1) fused input prep (cvt + 2 transposes + Wxt)
    kprep0<<<10752, 256, 0, stream>>>(x, xb, W_in, Wb, W_out, Wob, W_x, Wxt);
    // 2) xz = x @ W_in   (M=4096, N=4096, K=1024), bf16 out, 3-buf counted-vmcnt
    kgemm256<1024, 5><<<dim3(32, 16), 512, 0, stream>>>(xb, Wb, xzb, 4096);
    // 3) conv + silu (bf16 in, f32 out), 2 ch/thread
    kconv<<<NROWS * 1024 / 256, 256, 0, stream>>>(xzb, conv_w, conv_b, xs);
    // 4) bcd partials = xs @ W_x  (MFMA, K-split 16)
    kgemm2m<<<dim3(KS2, 32), 256, 0, stream>>>(xs, Wxt, part);
    // 5) fused reduce + scan-operand packing (dtdx in-place over xs, szw separate)
    kredprep<<<NROWS, 256, 0, stream>>>(part, w_dt, b_dt, Dp, xs, xzb, szw, bcd);
    // 6) selective scan (3 phases), 2 ch/thread, LDS-staged bcd, 4-deep batching
    kscan1<<<(4096 * NCHUNK) / 256, 256, 0, stream>>>(dtdx, bcd, A_log, hbuf, sumdt);
    kscan2<<<(4096 * 16) / 256, 256, 0, stream>>>(hbuf, sumdt, A_log);
    kscan3<<<(4096 * NCHUNK) / 256, 256, 0, stream>>>(dtdx, bcd, A_log, szw, hbuf, ub);
    // 7) out = u @ W_out (M=4096, N=1024, K=2048), 3-buf counted-vmcnt
    kgemm64<2048, 3><<<dim3(1024 / 128, 4096 / 64), 256, 0, stream>>>(ub, Wob, out, 1024);
}

// Round 12
// 212.577 us; speedup vs baseline: 2.5270x; 1.0065x over previous
//
#include <hip/hip_runtime.h>
#include <hip/hip_bf16.h>
#include <stdint.h>

#define D_MODEL 1024
#define D_STATE 16
#define D_CONV  4
#define D_INNER 2048
#define BATCH   2
#define SEQLEN  2048
#define NROWS   (BATCH*SEQLEN)     // 4096
#define BCD_LD  36                 // padded leading dim for bcd (33 used)
#define NCHUNK  64
#define CHUNKLEN (SEQLEN/NCHUNK)   // 32
#define KS2     16                 // K-splits for GEMM2 (chunk = 128)
#define L2E 1.44269504088896340f

typedef __attribute__((ext_vector_type(8))) short   short8;
typedef __attribute__((ext_vector_type(4))) float   f32x4;

__device__ __forceinline__ uint16_t f2bf(float f) {        // RNE f32->bf16
    uint32_t u = __float_as_uint(f);
    return (uint16_t)((u + 0x7FFFu + ((u >> 16) & 1u)) >> 16);
}
__device__ __forceinline__ float bf2f(uint16_t h) {
    return __uint_as_float(((uint32_t)h) << 16);
}
__device__ __forceinline__ uint32_t pack2bf(float lo, float hi) {
    return (uint32_t)f2bf(lo) | ((uint32_t)f2bf(hi) << 16);
}
__device__ __forceinline__ void gload16(const uint16_t* g, uint16_t* l) {
    __builtin_amdgcn_global_load_lds(
        (const __attribute__((address_space(1))) void*)g,
        (__attribute__((address_space(3))) void*)l, 16, 0, 0);
}
__device__ __forceinline__ void gload16f(const float* g, float* l) {
    __builtin_amdgcn_global_load_lds(
        (const __attribute__((address_space(1))) void*)g,
        (__attribute__((address_space(3))) void*)l, 16, 0, 0);
}
__device__ __forceinline__ float softplus_f(float v) {
    return fmaxf(v, 0.f) + __logf(1.f + __expf(-fabsf(v)));
}
__device__ __forceinline__ float silu_f(float v) {
    return v / (1.f + __expf(-v));
}
__device__ __forceinline__ short8 pack8(const float4 lo, const float4 hi) {
    short8 r;
    r[0] = (short)f2bf(lo.x); r[1] = (short)f2bf(lo.y);
    r[2] = (short)f2bf(lo.z); r[3] = (short)f2bf(lo.w);
    r[4] = (short)f2bf(hi.x); r[5] = (short)f2bf(hi.y);
    r[6] = (short)f2bf(hi.z); r[7] = (short)f2bf(hi.w);
    return r;
}

// ---------- fused input prep: kcvt | ktrans(W_in) | ktrans(W_out) | kwxt ----------
__global__ void kprep0(const float* __restrict__ x, uint16_t* __restrict__ xb,
                       const float* __restrict__ W_in, uint16_t* __restrict__ Wb,
                       const float* __restrict__ W_out, uint16_t* __restrict__ Wob,
                       const float* __restrict__ Wx, float* __restrict__ Wxt) {
    __shared__ float tile[32][33];
    const int blk = blockIdx.x;
    const int tid = threadIdx.x;
    if (blk < 4096) {                          // ---- cvt x -> bf16 (1M float4s)
        const int T = blk * 256 + tid;
        const float4 v = *(const float4*)&x[(size_t)T * 4];
        ushort4 o;
        o.x = f2bf(v.x); o.y = f2bf(v.y); o.z = f2bf(v.z); o.w = f2bf(v.w);
        *(ushort4*)&xb[(size_t)T * 4] = o;
    } else if (blk < 8192) {                   // ---- W_in [1024][4096] -> Wb [4096][1024]
        const int bb = blk - 4096;
        const int n0 = (bb & 127) * 32, k0 = (bb >> 7) * 32;
        const int tx = tid & 31, ty = tid >> 5;
#pragma unroll
        for (int i = 0; i < 4; ++i)
            tile[ty + i * 8][tx] = W_in[(size_t)(k0 + ty + i * 8) * 4096 + n0 + tx];
        __syncthreads();
#pragma unroll
        for (int i = 0; i < 4; ++i)
            Wb[(size_t)(n0 + ty + i * 8) * 1024 + k0 + tx] = f2bf(tile[tx][ty + i * 8]);
    } else if (blk < 10240) {                  // ---- W_out [2048][1024] -> Wob [1024][2048]
        const int bb = blk - 8192;
        const int n0 = (bb & 31) * 32, k0 = (bb >> 5) * 32;
        const int tx = tid & 31, ty = tid >> 5;
#pragma unroll
        for (int i = 0; i < 4; ++i)
            tile[ty + i * 8][tx] = W_out[(size_t)(k0 + ty + i * 8) * 1024 + n0 + tx];
        __syncthreads();
#pragma unroll
        for (int i = 0; i < 4; ++i)
            Wob[(size_t)(n0 + ty + i * 8) * 2048 + k0 + tx] = f2bf(tile[tx][ty + i * 8]);
    } else {                                   // ---- Wxt[64][2048] = W_x^T zero-padded
        const int T = (blk - 10240) * 256 + tid;
        const int j = T >> 11, k = T & 2047;
        Wxt[T] = (j < 33) ? Wx[(size_t)k * 33 + j] : 0.f;
    }
}

// ---------- GEMM1: 256x128 tile, 512 thr, 3-buf counted-vmcnt pipeline ----------
template<int KDIM, int GXL>
__global__ __launch_bounds__(512) void kgemm256(const uint16_t* __restrict__ A,
                                                const uint16_t* __restrict__ B,
                                                uint16_t* __restrict__ C, const int ldc) {
    __shared__ uint16_t As[3][256 * 32];   // 3 x 16 KB
    __shared__ uint16_t Bsh[3][128 * 32];  // 3 x 8 KB  (72 KB total)
    const int t = threadIdx.x;          // 0..511
    const int w = t >> 6, lane = t & 63;
    int wg = blockIdx.y * (1 << GXL) + blockIdx.x;
    wg = (wg & 7) * ((gridDim.x * gridDim.y) >> 3) + (wg >> 3);   // bijective XCD swizzle
    const int m0 = (wg >> GXL) * 256, n0 = (wg & ((1 << GXL) - 1)) * 128;
    const int wm = (w >> 1) * 64, wn = (w & 1) * 64;
    f32x4 acc[4][4] = {};

    const int srow = t >> 2;                              // 0..127
    const int scol = ((t & 3) ^ ((t >> 3) & 3)) * 8;      // pre-swizzled source slot
    const uint16_t* ga0 = A + (size_t)(m0 + srow) * KDIM + scol;
    const uint16_t* ga1 = A + (size_t)(m0 + 128 + srow) * KDIM + scol;
    const uint16_t* gb0 = B + (size_t)(n0 + srow) * KDIM + scol;

    const int fr = lane & 15, fg = (lane >> 4) * 8;
    const int psl = (((fg >> 3) ^ ((fr >> 1) & 3)) << 3);

    auto stage = [&](int buf, int ko) {
        gload16(ga0 + ko, &As[buf][w * 512]);
        gload16(ga1 + ko, &As[buf][4096 + w * 512]);
        gload16(gb0 + ko, &Bsh[buf][w * 512]);
    };

    constexpr int KT = KDIM / 32;
    stage(0, 0);
    stage(1, 32);                       // 6 loads in flight
    int cur = 0;
    for (int kt = 0; kt < KT; ++kt) {
        if (kt + 1 < KT) asm volatile("s_waitcnt vmcnt(3)" ::: "memory");
        else             asm volatile("s_waitcnt vmcnt(0)" ::: "memory");
        asm volatile("s_barrier" ::: "memory");      // all waves' tile-kt loads landed
        if (kt + 2 < KT) stage((kt + 2) % 3, (kt + 2) * 32);
        short8 a[4], b[4];
#pragma unroll
        for (int i = 0; i < 4; ++i) {
            a[i] = *(const short8*)&As[cur][(wm + i * 16 + fr) * 32 + psl];
            b[i] = *(const short8*)&Bsh[cur][(wn + i * 16 + fr) * 32 + psl];
        }
#pragma unroll
        for (int i = 0; i < 4; ++i)
#pragma unroll
            for (int j = 0; j < 4; ++j)
                acc[i][j] = __builtin_amdgcn_mfma_f32_16x16x32_bf16(a[i], b[j], acc[i][j], 0, 0, 0);
        cur = (cur + 1) % 3;
    }
    const int cr = (lane >> 4) * 4, cc = lane & 15;
#pragma unroll
    for (int i = 0; i < 4; ++i)
#pragma unroll
        for (int j = 0; j < 4; ++j)
#pragma unroll
            for (int r = 0; r < 4; ++r)
                C[(size_t)(m0 + wm + i * 16 + cr + r) * ldc + (n0 + wn + j * 16 + cc)] =
                    f2bf(acc[i][j][r]);
}

// ---------- GEMM3: 64x128 tile, 3-buf counted-vmcnt pipeline, f32 C ----------
template<int KDIM, int GXL>
__global__ __launch_bounds__(256) void kgemm64(const uint16_t* __restrict__ A,
                                               const uint16_t* __restrict__ B,
                                               float* __restrict__ C, const int ldc) {
    __shared__ uint16_t As[3][64 * 32];      // 3 x 4 KB
    __shared__ uint16_t Bsh[3][128 * 32];    // 3 x 8 KB  (36 KB total)
    const int t = threadIdx.x;
    const int w = t >> 6, lane = t & 63;
    int wg = blockIdx.y * (1 << GXL) + blockIdx.x;
    wg = (wg & 7) * ((gridDim.x * gridDim.y) >> 3) + (wg >> 3);
    const int m0 = (wg >> GXL) * 64, n0 = (wg & ((1 << GXL) - 1)) * 128;
    const int wm = (w >> 1) * 32, wn = (w & 1) * 64;
    f32x4 acc[2][4] = {};

    const int srow = t >> 2;
    const int scol = ((t & 3) ^ ((t >> 3) & 3)) * 8;
    const uint16_t* ga0 = A + (size_t)(m0 + srow) * KDIM + scol;
    const uint16_t* gb0 = B + (size_t)(n0 + srow) * KDIM + scol;
    const uint16_t* gb1 = B + (size_t)(n0 + 64 + srow) * KDIM + scol;

    const int fr = lane & 15, fg = (lane >> 4) * 8;
    const int psl = (((fg >> 3) ^ ((fr >> 1) & 3)) << 3);

    auto stage = [&](int buf, int ko) {
        gload16(ga0 + ko, &As[buf][w * 512]);
        gload16(gb0 + ko, &Bsh[buf][w * 512]);
        gload16(gb1 + ko, &Bsh[buf][2048 + w * 512]);
    };

    constexpr int KT = KDIM / 32;
    stage(0, 0);
    stage(1, 32);
    int cur = 0;
    for (int kt = 0; kt < KT; ++kt) {
        if (kt + 1 < KT) asm volatile("s_waitcnt vmcnt(3)" ::: "memory");
        else             asm volatile("s_waitcnt vmcnt(0)" ::: "memory");
        asm volatile("s_barrier" ::: "memory");
        if (kt + 2 < KT) stage((kt + 2) % 3, (kt + 2) * 32);
        short8 a[2], b[4];
#pragma unroll
        for (int i = 0; i < 2; ++i)
            a[i] = *(const short8*)&As[cur][(wm + i * 16 + fr) * 32 + psl];
#pragma unroll
        for (int j = 0; j < 4; ++j)
            b[j] = *(const short8*)&Bsh[cur][(wn + j * 16 + fr) * 32 + psl];
#pragma unroll
        for (int i = 0; i < 2; ++i)
#pragma unroll
            for (int j = 0; j < 4; ++j)
                acc[i][j] = __builtin_amdgcn_mfma_f32_16x16x32_bf16(a[i], b[j], acc[i][j], 0, 0, 0);
        cur = (cur + 1) % 3;
    }
    const int cr = (lane >> 4) * 4, cc = lane & 15;
#pragma unroll
    for (int i = 0; i < 2; ++i)
#pragma unroll
        for (int j = 0; j < 4; ++j)
#pragma unroll
            for (int r = 0; r < 4; ++r)
                C[(size_t)(m0 + wm + i * 16 + cr + r) * ldc + (n0 + wn + j * 16 + cc)] = acc[i][j][r];
}

// ---------- GEMM2 MFMA K-split: part[kb][4096][48] = xsb(chunk) @ Wxt^T ----------
// A now bf16 (direct short8 fragments); B stays f32-staged + pack8.
__global__ __launch_bounds__(256) void kgemm2m(const uint16_t* __restrict__ xsb,
        const float* __restrict__ Wxt, float* __restrict__ part) {
    __shared__ uint16_t As[128 * 32];   // 8 KB bf16
    __shared__ float Bs[64 * 32];       // 8 KB f32
    const int t = threadIdx.x;
    const int w = t >> 6, lane = t & 63;
    const int kb = blockIdx.x;              // 0..15
    const int m0 = blockIdx.y * 128;
    const int kc = kb * 128;
    f32x4 acc[2][3] = {};

    // A staging (bf16, kgemm256 pattern): rows 0..127 via 2 gload16
    const int srowA = t >> 2;                             // 0..63
    const int scolA = ((t & 3) ^ ((t >> 3) & 3)) * 8;     // elems
    const uint16_t* ga0 = xsb + (size_t)(m0 + srowA) * 2048 + scolA;
    const uint16_t* ga1 = xsb + (size_t)(m0 + 64 + srowA) * 2048 + scolA;
    uint16_t* lA0 = &As[w * 512];
    uint16_t* lA1 = &As[2048 + w * 512];

    // B staging (f32, 64 rows)
    const int srowB = t >> 3;                            // 0..31
    const int scolB = ((t & 7) ^ ((t >> 3) & 7)) * 4;    // floats
    float* lB[2];
#pragma unroll
    for (int r = 0; r < 2; ++r) lB[r] = &Bs[(r * 32 + w * 8) * 32];

    const int wm = w * 32;
    const int fr = lane & 15, fg = (lane >> 4) * 8;
    const int psl = (((fg >> 3) ^ ((fr >> 1) & 3)) << 3);   // bf16 A read slot
    const int plo = (((fg >> 2) ^ (fr & 7))) * 4;           // f32 B read slots
    const int phi = ((((fg >> 2) + 1) ^ (fr & 7))) * 4;

    for (int kt = 0; kt < 4; ++kt) {
        const int ko = kc + kt * 32;
        gload16(ga0 + ko, lA0);
        gload16(ga1 + ko, lA1);
#pragma unroll
        for (int r = 0; r < 2; ++r)
            gload16f(Wxt + (size_t)(r * 32 + srowB) * 2048 + ko + scolB, lB[r]);
        __syncthreads();
        short8 a[2], b[3];
#pragma unroll
        for (int i = 0; i < 2; ++i)
            a[i] = *(const short8*)&As[(wm + i * 16 + fr) * 32 + psl];
#pragma unroll
        for (int j = 0; j < 3; ++j) {
            const float* base = &Bs[(j * 16 + fr) * 32];
            b[j] = pack8(*(const float4*)&base[plo], *(const float4*)&base[phi]);
        }
#pragma unroll
        for (int i = 0; i < 2; ++i)
#pragma unroll
            for (int j = 0; j < 3; ++j)
                acc[i][j] = __builtin_amdgcn_mfma_f32_16x16x32_bf16(a[i], b[j], acc[i][j], 0, 0, 0);
        __syncthreads();
    }
    const int cr = (lane >> 4) * 4, cc = lane & 15;
    float* pb = part + (size_t)kb * 4096 * 48;
#pragma unroll
    for (int i = 0; i < 2; ++i)
#pragma unroll
        for (int j = 0; j < 3; ++j)
#pragma unroll
            for (int r = 0; r < 4; ++r)
                pb[(size_t)(m0 + wm + i * 16 + cr + r) * 48 + j * 16 + cc] = acc[i][j][r];
}

// ---------- fused: reduce partials -> bcd row; pack dtdx (over xzb row) + szw ----------
// one block per row. Reads of the xzb z-half complete before dtdx overwrites the row.
__global__ __launch_bounds__(256) void kredprep(const float* __restrict__ part,
        const float* __restrict__ wdt, const float* __restrict__ bdt,
        const float* __restrict__ Dp, const uint16_t* __restrict__ xsb,
        uint16_t* __restrict__ xzb_io, uint32_t* __restrict__ szw,
        float* __restrict__ bcd) {
    const int row = blockIdx.x;
    const int t = threadIdx.x;
    __shared__ float rawsh;
    if (t < 33) {
        float s = 0.f;
#pragma unroll
        for (int ks = 0; ks < KS2; ++ks)
            s += part[(size_t)ks * 4096 * 48 + (size_t)row * 48 + t];
        bcd[(size_t)row * BCD_LD + t] = s;
        if (t == 32) rawsh = s;
    }
    __syncthreads();
    const float raw = rawsh;
    ushort4 xu[2], zu[2];
#pragma unroll
    for (int g = 0; g < 2; ++g) {
        const int dg = t * 8 + g * 4;
        xu[g] = *(const ushort4*)&xsb[(size_t)row * 2048 + dg];
        zu[g] = *(const ushort4*)&xzb_io[(size_t)row * 4096 + 2048 + dg];
    }
    __syncthreads();          // all z reads done block-wide before row overwrite
    uint32_t* dtdx = (uint32_t*)xzb_io;
#pragma unroll
    for (int g = 0; g < 2; ++g) {
        const int dg = t * 8 + g * 4;
        const float4 w  = *(const float4*)&wdt[dg];
        const float4 b  = *(const float4*)&bdt[dg];
        const float4 Dv = *(const float4*)&Dp[dg];
        const float x0 = bf2f(xu[g].x), x1 = bf2f(xu[g].y);
        const float x2 = bf2f(xu[g].z), x3 = bf2f(xu[g].w);
        const float dt0 = softplus_f(raw * w.x + b.x);
        const float dt1 = softplus_f(raw * w.y + b.y);
        const float dt2 = softplus_f(raw * w.z + b.z);
        const float dt3 = softplus_f(raw * w.w + b.w);
        uint4 pd;
        pd.x = pack2bf(dt0, dt0 * x0);
        pd.y = pack2bf(dt1, dt1 * x1);
        pd.z = pack2bf(dt2, dt2 * x2);
        pd.w = pack2bf(dt3, dt3 * x3);
        const float s0 = silu_f(bf2f(zu[g].x)), s1 = silu_f(bf2f(zu[g].y));
        const float s2 = silu_f(bf2f(zu[g].z)), s3 = silu_f(bf2f(zu[g].w));
        uint4 ps;
        ps.x = pack2bf(s0, x0 * Dv.x * s0);
        ps.y = pack2bf(s1, x1 * Dv.y * s1);
        ps.z = pack2bf(s2, x2 * Dv.z * s2);
        ps.w = pack2bf(s3, x3 * Dv.w * s3);
        *(uint4*)&dtdx[(size_t)row * 2048 + dg] = pd;
        *(uint4*)&szw[(size_t)row * 2048 + dg] = ps;
    }
}

// ---------- scan phase 1: 2 ch/thread, bcd B in LDS, 4-deep global batching ----------
__global__ __launch_bounds__(256) void kscan1(const uint32_t* __restrict__ dtdx,
        const float* __restrict__ bcd, const float* __restrict__ Alog,
        float* __restrict__ hbuf, float* __restrict__ sumdt) {
    const int T = blockIdx.x * 256 + threadIdx.x;
    const int sub = T & 1;
    const int cp  = (T >> 1) & 2047;
    const int chunk = T >> 12;
    const int b = cp >> 10, d0 = (cp & 1023) * 2;
    const int row0 = b * SEQLEN + chunk * CHUNKLEN;    // same for whole block

    __shared__ float Bls[32][16];       // B part (cols 0..15) of the 32 chunk rows
    {
        const int r = threadIdx.x >> 3, c = (threadIdx.x & 7) * 2;
        const float2 v = *(const float2*)&bcd[(size_t)(row0 + r) * BCD_LD + c];
        Bls[r][c] = v.x; Bls[r][c + 1] = v.y;
    }
    __syncthreads();

    float Ae0[8], Ae1[8]; bool st = true;
#pragma unroll
    for (int i = 0; i < 8; ++i) {
        const float a0 = __expf(Alog[d0 * 16 + sub * 8 + i]);
        const float a1 = __expf(Alog[(d0 + 1) * 16 + sub * 8 + i]);
        Ae0[i] = -a0 * L2E; Ae1[i] = -a1 * L2E;
        st = st && (fabsf(a0 - (float)(sub * 8 + i + 1)) < 1e-3f)
                && (fabsf(a1 - (float)(sub * 8 + i + 1)) < 1e-3f);
    }
    float hA[8] = {}, hB[8] = {};
    float sdtA = 0.f, sdtB = 0.f;
    const uint32_t* pD = dtdx + (size_t)row0 * 2048 + d0;
    if (st) {
        for (int l0 = 0; l0 < CHUNKLEN; l0 += 4) {
            uint2 pk[4];
#pragma unroll
            for (int s = 0; s < 4; ++s) pk[s] = *(const uint2*)(pD + (size_t)s * 2048);
#pragma unroll
            for (int s = 0; s < 4; ++s) {
                const float4 B0 = *(const float4*)&Bls[l0 + s][sub * 8];
                const float4 B1 = *(const float4*)&Bls[l0 + s][sub * 8 + 4];
                const float dtA  = __uint_as_float(pk[s].x << 16);
                const float dtxA = __uint_as_float(pk[s].x & 0xffff0000u);
                const float dtB  = __uint_as_float(pk[s].y << 16);
                const float dtxB = __uint_as_float(pk[s].y & 0xffff0000u);
                sdtA += dtA; sdtB += dtB;
                const float e0A = __builtin_amdgcn_exp2f(dtA * (-L2E));
                const float e0B = __builtin_amdgcn_exp2f(dtB * (-L2E));
                const float e8A = (e0A*e0A)*(e0A*e0A)*(e0A*e0A)*(e0A*e0A);
                const float e8B = (e0B*e0B)*(e0B*e0B)*(e0B*e0B)*(e0B*e0B);
                float dA = sub ? e8A : 1.f, dB = sub ? e8B : 1.f;
                dA *= e0A; dB *= e0B; hA[0] = fmaf(dA, hA[0], dtxA * B0.x); hB[0] = fmaf(dB, hB[0], dtxB * B0.x);
                dA *= e0A; dB *= e0B; hA[1] = fmaf(dA, hA[1], dtxA * B0.y); hB[1] = fmaf(dB, hB[1], dtxB * B0.y);
                dA *= e0A; dB *= e0B; hA[2] = fmaf(dA, hA[2], dtxA * B0.z); hB[2] = fmaf(dB, hB[2], dtxB * B0.z);
                dA *= e0A; dB *= e0B; hA[3] = fmaf(dA, hA[3], dtxA * B0.w); hB[3] = fmaf(dB, hB[3], dtxB * B0.w);
                dA *= e0A; dB *= e0B; hA[4] = fmaf(dA, hA[4], dtxA * B1.x); hB[4] = fmaf(dB, hB[4], dtxB * B1.x);
                dA *= e0A; dB *= e0B; hA[5] = fmaf(dA, hA[5], dtxA * B1.y); hB[5] = fmaf(dB, hB[5], dtxB * B1.y);
                dA *= e0A; dB *= e0B; hA[6] = fmaf(dA, hA[6], dtxA * B1.z); hB[6] = fmaf(dB, hB[6], dtxB * B1.z);
                dA *= e0A; dB *= e0B; hA[7] = fmaf(dA, hA[7], dtxA * B1.w); hB[7] = fmaf(dB, hB[7], dtxB * B1.w);
            }
            pD += 4 * 2048;
        }
    } else {
        for (int l0 = 0; l0 < CHUNKLEN; l0 += 4) {
            uint2 pk[4];
#pragma unroll
            for (int s = 0; s < 4; ++s) pk[s] = *(const uint2*)(pD + (size_t)s * 2048);
#pragma unroll
            for (int s = 0; s < 4; ++s) {
                const float4 B0 = *(const float4*)&Bls[l0 + s][sub * 8];
                const float4 B1 = *(const float4*)&Bls[l0 + s][sub * 8 + 4];
                const float dtA  = __uint_as_float(pk[s].x << 16);
                const float dtxA = __uint_as_float(pk[s].x & 0xffff0000u);
                const float dtB  = __uint_as_float(pk[s].y << 16);
                const float dtxB = __uint_as_float(pk[s].y & 0xffff0000u);
                sdtA += dtA; sdtB += dtB;
                const float Bv[8] = {B0.x, B0.y, B0.z, B0.w, B1.x, B1.y, B1.z, B1.w};
#pragma unroll
                for (int i = 0; i < 8; ++i) {
                    hA[i] = fmaf(__builtin_amdgcn_exp2f(dtA * Ae0[i]), hA[i], dtxA * Bv[i]);
                    hB[i] = fmaf(__builtin_amdgcn_exp2f(dtB * Ae1[i]), hB[i], dtxB * Bv[i]);
                }
            }
            pD += 4 * 2048;
        }
    }
    const size_t cc0 = (size_t)(chunk * 4096 + b * 2048 + d0) * 16 + sub * 8;
    *(float4*)&hbuf[cc0]          = make_float4(hA[0], hA[1], hA[2], hA[3]);
    *(float4*)&hbuf[cc0 + 4]      = make_float4(hA[4], hA[5], hA[6], hA[7]);
    *(float4*)&hbuf[cc0 + 16]     = make_float4(hB[0], hB[1], hB[2], hB[3]);
    *(float4*)&hbuf[cc0 + 20]     = make_float4(hB[4], hB[5], hB[6], hB[7]);
    if (sub == 0)
        *(float2*)&sumdt[chunk * 4096 + b * 2048 + d0] = make_float2(sdtA, sdtB);
}

// ---------- scan phase 2: chunk combine (in-place carries), next-iter prefetch ----------
__global__ void kscan2(float* __restrict__ hbuf, const float* __restrict__ sumdt,
                       const float* __restrict__ Alog) {
    const int T = blockIdx.x * 256 + threadIdx.x;   // 65536
    const int n = T & 15, ch = T >> 4;
    const int d = ch & 2047;
    const float Ae = -__expf(Alog[d * 16 + n]) * L2E;
    float h = 0.f;
    size_t idx = (size_t)ch * 16 + n;
    float loc = hbuf[idx];
    float sd  = sumdt[ch];
    for (int c = 0; c < NCHUNK; ++c) {
        float locN = 0.f, sdN = 0.f;
        const size_t idxN = idx + (size_t)4096 * 16;
        if (c + 1 < NCHUNK) {
            locN = hbuf[idxN];
            sdN  = sumdt[(size_t)(c + 1) * 4096 + ch];
        }
        hbuf[idx] = h;
        h = __builtin_amdgcn_exp2f(Ae * sd) * h + loc;
        loc = locN; sd = sdN; idx = idxN;
    }
}

// ---------- scan phase 3: 2 ch/thread, bcd B+C in LDS, 4-deep batching ----------
__global__ __launch_bounds__(256) void kscan3(const uint32_t* __restrict__ dtdx,
        const float* __restrict__ bcd, const float* __restrict__ Alog,
        const uint32_t* __restrict__ szw, const float* __restrict__ hbuf,
        uint16_t* __restrict__ u) {
    const int T = blockIdx.x * 256 + threadIdx.x;
    const int sub = T & 1;
    const int cp  = (T >> 1) & 2047;
    const int chunk = T >> 12;
    const int b = cp >> 10, d0 = (cp & 1023) * 2;
    const int row0 = b * SEQLEN + chunk * CHUNKLEN;    // same for whole block

    __shared__ float BC[32][32];        // B (0..15) + C (16..31) of the 32 chunk rows
    {
        const int r = threadIdx.x >> 3, c = (threadIdx.x & 7) * 4;
        *(float4*)&BC[r][c] = *(const float4*)&bcd[(size_t)(row0 + r) * BCD_LD + c];
    }
    __syncthreads();

    float Ae0[8], Ae1[8]; bool st = true;
#pragma unroll
    for (int i = 0; i < 8; ++i) {
        const float a0 = __expf(Alog[d0 * 16 + sub * 8 + i]);
        const float a1 = __expf(Alog[(d0 + 1) * 16 + sub * 8 + i]);
        Ae0[i] = -a0 * L2E; Ae1[i] = -a1 * L2E;
        st = st && (fabsf(a0 - (float)(sub * 8 + i + 1)) < 1e-3f)
                && (fabsf(a1 - (float)(sub * 8 + i + 1)) < 1e-3f);
    }
    float hA[8], hB[8];
    {
        const size_t cc0 = (size_t)(chunk * 4096 + b * 2048 + d0) * 16 + sub * 8;
        const float4 a0 = *(const float4*)&hbuf[cc0];
        const float4 a1 = *(const float4*)&hbuf[cc0 + 4];
        const float4 b0 = *(const float4*)&hbuf[cc0 + 16];
        const float4 b1 = *(const float4*)&hbuf[cc0 + 20];
        hA[0]=a0.x; hA[1]=a0.y; hA[2]=a0.z; hA[3]=a0.w;
        hA[4]=a1.x; hA[5]=a1.y; hA[6]=a1.z; hA[7]=a1.w;
        hB[0]=b0.x; hB[1]=b0.y; hB[2]=b0.z; hB[3]=b0.w;
        hB[4]=b1.x; hB[5]=b1.y; hB[6]=b1.z; hB[7]=b1.w;
    }
    const uint32_t* pD = dtdx + (size_t)row0 * 2048 + d0;
    const uint32_t* pS = szw  + (size_t)row0 * 2048 + d0;   // only sub==0 reads
    uint16_t* pU = u + (size_t)row0 * D_INNER + d0;
    if (st) {
        for (int l0 = 0; l0 < CHUNKLEN; l0 += 4) {
            uint2 pk[4], qk[4];
#pragma unroll
            for (int s = 0; s < 4; ++s) {
                pk[s] = *(const uint2*)(pD + (size_t)s * 2048);
                if (sub == 0) qk[s] = *(const uint2*)(pS + (size_t)s * 2048);
            }
#pragma unroll
            for (int s = 0; s < 4; ++s) {
                const float4 B0 = *(const float4*)&BC[l0 + s][sub * 8];
                const float4 B1 = *(const float4*)&BC[l0 + s][sub * 8 + 4];
                const float4 C0 = *(const float4*)&BC[l0 + s][16 + sub * 8];
                const float4 C1 = *(const float4*)&BC[l0 + s][20 + sub * 8];
                const float dtA  = __uint_as_float(pk[s].x << 16);
                const float dtxA = __uint_as_float(pk[s].x & 0xffff0000u);
                const float dtB  = __uint_as_float(pk[s].y << 16);
                const float dtxB = __uint_as_float(pk[s].y & 0xffff0000u);
                const float e0A = __builtin_amdgcn_exp2f(dtA * (-L2E));
                const float e0B = __builtin_amdgcn_exp2f(dtB * (-L2E));
                const float e8A = (e0A*e0A)*(e0A*e0A)*(e0A*e0A)*(e0A*e0A);
                const float e8B = (e0B*e0B)*(e0B*e0B)*(e0B*e0B)*(e0B*e0B);
                float dA = sub ? e8A : 1.f, dB = sub ? e8B : 1.f;
                float yA, yB;
                dA *= e0A; dB *= e0B; hA[0] = fmaf(dA, hA[0], dtxA * B0.x); hB[0] = fmaf(dB, hB[0], dtxB * B0.x);
                dA *= e0A; dB *= e0B; hA[1] = fmaf(dA, hA[1], dtxA * B0.y); hB[1] = fmaf(dB, hB[1], dtxB * B0.y);
                dA *= e0A; dB *= e0B; hA[2] = fmaf(dA, hA[2], dtxA * B0.z); hB[2] = fmaf(dB, hB[2], dtxB * B0.z);
                dA *= e0A; dB *= e0B; hA[3] = fmaf(dA, hA[3], dtxA * B0.w); hB[3] = fmaf(dB, hB[3], dtxB * B0.w);
                dA *= e0A; dB *= e0B; hA[4] = fmaf(dA, hA[4], dtxA * B1.x); hB[4] = fmaf(dB, hB[4], dtxB * B1.x);
                dA *= e0A; dB *= e0B; hA[5] = fmaf(dA, hA[5], dtxA * B1.y); hB[5] = fmaf(dB, hB[5], dtxB * B1.y);
                dA *= e0A; dB *= e0B; hA[6] = fmaf(dA, hA[6], dtxA * B1.z); hB[6] = fmaf(dB, hB[6], dtxB * B1.z);
                dA *= e0A; dB *= e0B; hA[7] = fmaf(dA, hA[7], dtxA * B1.w); hB[7] = fmaf(dB, hB[7], dtxB * B1.w);
                yA = hA[0]*C0.x + hA[1]*C0.y + hA[2]*C0.z + hA[3]*C0.w
                   + hA[4]*C1.x + hA[5]*C1.y + hA[6]*C1.z + hA[7]*C1.w;
                yB = hB[0]*C0.x + hB[1]*C0.y + hB[2]*C0.z + hB[3]*C0.w
                   + hB[4]*C1.x + hB[5]*C1.y + hB[6]*C1.z + hB[7]*C1.w;
                yA += __shfl_xor(yA, 1);
                yB += __shfl_xor(yB, 1);
                if (sub == 0) {
                    const float szA = __uint_as_float(qk[s].x << 16);
                    const float w2A = __uint_as_float(qk[s].x & 0xffff0000u);
                    const float szB = __uint_as_float(qk[s].y << 16);
                    const float w2B = __uint_as_float(qk[s].y & 0xffff0000u);
                    *(uint32_t*)(pU + (size_t)s * D_INNER) =
                        pack2bf(fmaf(yA, szA, w2A), fmaf(yB, szB, w2B));
                }
            }
            pD += 4 * 2048; pS += 4 * 2048; pU += 4 * D_INNER;
        }
    } else {
        for (int l0 = 0; l0 < CHUNKLEN; l0 += 4) {
            uint2 pk[4], qk[4];
#pragma unroll
            for (int s = 0; s < 4; ++s) {
                pk[s] = *(const uint2*)(pD + (size_t)s * 2048);
                if (sub == 0) qk[s] = *(const uint2*)(pS + (size_t)s * 2048);
            }
#pragma unroll
            for (int s = 0; s < 4; ++s) {
                const float4 B0 = *(const float4*)&BC[l0 + s][sub * 8];
                const float4 B1 = *(const float4*)&BC[l0 + s][sub * 8 + 4];
                const float4 C0 = *(const float4*)&BC[l0 + s][16 + sub * 8];
                const float4 C1 = *(const float4*)&BC[l0 + s][20 + sub * 8];
                const float dtA  = __uint_as_float(pk[s].x << 16);
                const float dtxA = __uint_as_float(pk[s].x & 0xffff0000u);
                const float dtB  = __uint_as_float(pk[s].y << 16);
                const float dtxB = __uint_as_float(pk[s].y & 0xffff0000u);
                const float Bv[8] = {B0.x, B0.y, B0.z, B0.w, B1.x, B1.y, B1.z, B1.w};
                const float Cv[8] = {C0.x, C0.y, C0.z, C0.w, C1.x, C1.y, C1.z, C1.w};
                float yA = 0.f, yB = 0.f;
#pragma unroll
                for (int i = 0; i < 8; ++i) {
                    hA[i] = fmaf(__builtin_amdgcn_exp2f(dtA * Ae0[i]), hA[i], dtxA * Bv[i]);
                    hB[i] = fmaf(__builtin_amdgcn_exp2f(dtB * Ae1[i]), hB[i], dtxB * Bv[i]);
                    yA = fmaf(hA[i], Cv[i], yA);
                    yB = fmaf(hB[i], Cv[i], yB);
                }
                yA += __shfl_xor(yA, 1);
                yB += __shfl_xor(yB, 1);
                if (sub == 0) {
                    const float szA = __uint_as_float(qk[s].x << 16);
                    const float w2A = __uint_as_float(qk[s].x & 0xffff0000u);
                    const float szB = __uint_as_float(qk[s].y << 16);
                    const float w2B = __uint_as_float(qk[s].y & 0xffff0000u);
                    *(uint32_t*)(pU + (size_t)s * D_INNER) =
                        pack2bf(fmaf(yA, szA, w2A), fmaf(yB, szB, w2B));
                }
            }
            pD += 4 * 2048; pS += 4 * 2048; pU += 4 * D_INNER;
        }
    }
}

// ---------- causal depthwise conv (k=4) + bias + SiLU, 2 ch/thread, bf16 out ----------
__global__ void kconv(const uint16_t* __restrict__ xzb, const float* __restrict__ cw,
                      const float* __restrict__ cb, uint16_t* __restrict__ xsb) {
    const int T = blockIdx.x * 256 + threadIdx.x;   // over NROWS*1024
    const int d0 = (T & 1023) * 2;
    const int row = T >> 10;
    const int l = row & (SEQLEN - 1), b = row >> 11;
    const float4 wA = *(const float4*)&cw[d0 * 4];
    const float4 wB = *(const float4*)&cw[d0 * 4 + 4];
    const float2 bias = *(const float2*)&cb[d0];
    float a0 = bias.x, a1 = bias.y;
    const size_t base = (size_t)b * SEQLEN;
    if (l >= 3) {
        uint32_t v;
        v = *(const uint32_t*)&xzb[(base + l - 3) * 4096 + d0];
        a0 += wA.x * bf2f((uint16_t)v); a1 += wB.x * bf2f((uint16_t)(v >> 16));
        v = *(const uint32_t*)&xzb[(base + l - 2) * 4096 + d0];
        a0 += wA.y * bf2f((uint16_t)v); a1 += wB.y * bf2f((uint16_t)(v >> 16));
        v = *(const uint32_t*)&xzb[(base + l - 1) * 4096 + d0];
        a0 += wA.z * bf2f((uint16_t)v); a1 += wB.z * bf2f((uint16_t)(v >> 16));
        v = *(const uint32_t*)&xzb[(base + l    ) * 4096 + d0];
        a0 += wA.w * bf2f((uint16_t)v); a1 += wB.w * bf2f((uint16_t)(v >> 16));
    } else {
        uint32_t v;
        if (l >= 2) {
            v = *(const uint32_t*)&xzb[(base + l - 2) * 4096 + d0];
            a0 += wA.y * bf2f((uint16_t)v); a1 += wB.y * bf2f((uint16_t)(v >> 16));
        }
        if (l >= 1) {
            v = *(const uint32_t*)&xzb[(base + l - 1) * 4096 + d0];
            a0 += wA.z * bf2f((uint16_t)v); a1 += wB.z * bf2f((uint16_t)(v >> 16));
        }
        v = *(const uint32_t*)&xzb[(base + l) * 4096 + d0];
        a0 += wA.w * bf2f((uint16_t)v); a1 += wB.w * bf2f((uint16_t)(v >> 16));
    }
    *(uint32_t*)&xsb[(size_t)row * 2048 + d0] = pack2bf(silu_f(a0), silu_f(a1));
}

extern "C" void kernel_launch(void* const* d_in, const int* in_sizes, int n_in,
                              void* d_out, int out_size, void* d_ws, size_t ws_size,
                              hipStream_t stream) {
    const float* x      = (const float*)d_in[0];
    const float* W_in   = (const float*)d_in[1];
    const float* conv_w = (const float*)d_in[2];
    const float* conv_b = (const float*)d_in[3];
    const float* W_x    = (const float*)d_in[4];
    const float* w_dt   = (const float*)d_in[5];
    const float* b_dt   = (const float*)d_in[6];
    const float* A_log  = (const float*)d_in[7];
    const float* Dp     = (const float*)d_in[8];
    const float* W_out  = (const float*)d_in[9];
    float* out = (float*)d_out;

    char* p = (char*)d_ws;
    uint16_t* xb  = (uint16_t*)p;  p += (size_t)NROWS * D_MODEL * 2;      // 8 MB (dead after gemm1)
    uint16_t* Wb  = (uint16_t*)p;  p += (size_t)4096 * 1024 * 2;          // 8 MB (dead after gemm1)
    uint16_t* Wob = (uint16_t*)p;  p += (size_t)1024 * 2048 * 2;          // 4 MB  (W_out^T)
    uint16_t* xzb = (uint16_t*)p;  p += (size_t)NROWS * 4096 * 2;         // 32 MB (bf16 xz; later dtdx)
    uint16_t* xsb = (uint16_t*)p;  p += (size_t)NROWS * D_INNER * 2;      // 16 MB (bf16 xs)
    float* bcd    = (float*)p;     p += (size_t)NROWS * BCD_LD * 4;       // 576 KB
    float* sumdt  = (float*)p;     p += (size_t)NCHUNK * 4096 * 4;        // 1 MB
    float* Wxt    = (float*)p;     p += (size_t)64 * 2048 * 4;            // 512 KB
    uint16_t* ub  = (uint16_t*)p;  p += (size_t)NROWS * D_INNER * 2;      // 16 MB
    uint32_t* szw = (uint32_t*)p;  p += (size_t)NROWS * D_INNER * 4;      // 32 MB (silu(z) pack)
    // overlays (regions dead during their use):
    float* hbuf    = (float*)xb;        // 16 MB = xb+Wb (dead after gemm1)
    float* part    = (float*)ub;        // 12.6 MB (ub written only by kscan3, later)
    uint32_t* dtdx = (uint32_t*)xzb;    // packed (dt, dt*x), in-place over xzb rows

    // 1) fused input prep (cvt + 2 transposes + Wxt)
    kprep0<<<10752, 256, 0, stream>>>(x, xb, W_in, Wb, W_out, Wob, W_x, Wxt);
    // 2) xz = x @ W_in   (M=4096, N=4096, K=1024), bf16 out, 3-buf counted-vmcnt
    kgemm256<1024, 5><<<dim3(32, 16), 512, 0, stream>>>(xb, Wb, xzb, 4096);
    // 3) conv + silu (bf16 in, bf16 out), 2 ch/thread
    kconv<<<NROWS * 1024 / 256, 256, 0, stream>>>(xzb, conv_w, conv_b, xsb);
    // 4) bcd partials = xsb @ W_x  (MFMA, K-split 16, bf16 A)
    kgemm2m<<<dim3(KS2, 32), 256, 0, stream>>>(xsb, Wxt, part);
    // 5) fused reduce + scan-operand packing (dtdx over xzb rows, szw separate)
    kredprep<<<NROWS, 256, 0, stream>>>(part, w_dt, b_dt, Dp, xsb, xzb, szw, bcd);
    // 6) selective scan (3 phases), 2 ch/thread, LDS-staged bcd, 4-deep batching
    kscan1<<<(4096 * NCHUNK) / 256, 256, 0, stream>>>(dtdx, bcd, A_log, hbuf, sumdt);
    kscan2<<<(4096 * 16) / 256, 256, 0, stream>>>(hbuf, sumdt, A_log);
    kscan3<<<(4096 * NCHUNK) / 256, 256, 0, stream>>>(dtdx, bcd, A_log, szw, hbuf, ub);
    // 7) out = u @ W_out (M=4096, N=1024, K=2048), 3-buf counted-vmcnt
    kgemm64<2048, 3><<<dim3(1024 / 128, 4096 / 64), 256, 0, stream>>>(ub, Wob, out, 1024);
}